// Round 7
// baseline (2909.999 us; speedup 1.0000x reference)
//
#include <hip/hip_runtime.h>
#include <cmath>

// ============================ constants ============================
static constexpr int kAImg = 159375;   // anchors per image
static constexpr int kNCand = 7875;    // 2000+2000+2000+1875
static constexpr int kPostNms = 2000;
static constexpr int kMPad = 2048;     // padded roi count for MFMA GEMM
static constexpr float kISC = 1.0f / 4096.0f;

__constant__ int c_AOFF[4]   = {0, 120000, 150000, 157500};
__constant__ int c_ALVL[4]   = {120000, 30000, 7500, 1875};
__constant__ int c_CBASE[4]  = {0, 2000, 4000, 6000};
__constant__ int c_LW[4]     = {200, 100, 50, 25};
__constant__ int c_LH[4]     = {200, 100, 50, 25};
__constant__ int c_STRIDE[4] = {4, 8, 16, 32};

struct Cand     { float x1, y1, x2, y2; unsigned key; unsigned lvl; unsigned pad0, pad1; };
struct HeadCand { float x1, y1, x2, y2; float score; unsigned key; unsigned pad0, pad1; };
struct RoiParam { int lvl; float x1, y1, rw, rh; int pad0, pad1, pad2; };
struct AnchTab  { float v[4][3][4]; };

typedef unsigned short u16;
typedef __attribute__((ext_vector_type(8))) short short8;
typedef __attribute__((ext_vector_type(4))) float f32x4;
typedef _Float16 f16x8 __attribute__((ext_vector_type(8)));

// ============================ device helpers ============================
__device__ __forceinline__ unsigned keyOf(float f) {
  unsigned u = __float_as_uint(f);
  return (u & 0x80000000u) ? ~u : (u | 0x80000000u);
}

// fp32 -> (f16 hi, f16 lo*4096). value = hi + lo/4096, err ~ 2^-24 relative.
__device__ __forceinline__ void split_f16(float f, u16& hi, u16& lo) {
  union { _Float16 h; u16 u; } a, b;
  a.h = (_Float16)f;
  float r = (f - (float)a.h) * 4096.0f;
  b.h = (_Float16)r;
  hi = a.u; lo = b.u;
}

__device__ __forceinline__ unsigned long long shfl64(unsigned long long v, int src) {
  int lo = __shfl((int)(unsigned)(v & 0xffffffffull), src);
  int hi = __shfl((int)(unsigned)(v >> 32), src);
  return ((unsigned long long)(unsigned)hi << 32) | (unsigned)lo;
}

__device__ __forceinline__ float iou_pair(float4 a, float4 b) {
#pragma clang fp contract(off)
  float ix1 = fmaxf(a.x, b.x), iy1 = fmaxf(a.y, b.y);
  float ix2 = fminf(a.z, b.z), iy2 = fminf(a.w, b.w);
  float iw = fmaxf(ix2 - ix1, 0.f), ih = fmaxf(iy2 - iy1, 0.f);
  float inter = iw * ih;
  float a1 = (a.z - a.x) * (a.w - a.y);
  float a2 = (b.z - b.x) * (b.w - b.y);
  float uni = a1 + a2 - inter;
  return uni > 0.f ? inter / uni : 0.f;
}

__device__ __forceinline__ float4 decode_clip(float bx1, float by1, float bx2, float by2,
                                              float d0, float d1, float d2, float d3,
                                              float wx, float wy, float ww, float wh) {
#pragma clang fp contract(off)
  float w = bx2 - bx1, h = by2 - by1;
  float cx = bx1 + 0.5f * w, cy = by1 + 0.5f * h;
  float dx = d0 / wx, dy = d1 / wy;
  float dw = fminf(d2 / ww, 4.135166556742356f);
  float dh = fminf(d3 / wh, 4.135166556742356f);
  float pcx = dx * w + cx, pcy = dy * h + cy;
  float pw = expf(dw) * w, ph = expf(dh) * h;
  float x1 = pcx - 0.5f * pw, y1 = pcy - 0.5f * ph;
  float x2 = pcx + 0.5f * pw, y2 = pcy + 0.5f * ph;
  x1 = fminf(fmaxf(x1, 0.f), 800.f); y1 = fminf(fmaxf(y1, 0.f), 800.f);
  x2 = fminf(fmaxf(x2, 0.f), 800.f); y2 = fminf(fmaxf(y2, 0.f), 800.f);
  return make_float4(x1, y1, x2, y2);
}

// block-wide exclusive scan of a bool over 1024 threads (16 waves)
__device__ __forceinline__ unsigned block_scan_bool(bool p, unsigned* wbuf, unsigned& total) {
  unsigned long long m = __ballot(p);
  int lane = threadIdx.x & 63;
  int wid = threadIdx.x >> 6;
  unsigned exc = (unsigned)__popcll(m & ((lane == 0) ? 0ull : ((~0ull) >> (64 - lane))));
  if (lane == 0) wbuf[wid] = (unsigned)__popcll(m);
  __syncthreads();
  unsigned pre = 0, tot = 0;
#pragma unroll
  for (int w = 0; w < 16; w++) { unsigned c = wbuf[w]; if (w < wid) pre += c; tot += c; }
  total = tot;
  __syncthreads();
  return pre + exc;
}

// ============================ zero fill ============================
__global__ __launch_bounds__(256) void zero_u32_kernel(unsigned* __restrict__ p, int n32) {
  for (int i = blockIdx.x * 256 + threadIdx.x; i < n32; i += gridDim.x * 256) p[i] = 0u;
}

// ============================ NCHW -> padded HWC f16-split transpose ============================
template <int H, int W>
__global__ __launch_bounds__(256) void transpose_pad_kernel(
    const float* __restrict__ feat, u16* __restrict__ Fh, u16* __restrict__ Fl) {
  __shared__ float tile[128][65];
  int y = blockIdx.y;
  int x0 = blockIdx.x * 64;
  for (int e = threadIdx.x; e < 128 * 64; e += 256) {
    int ci = e >> 6, x = e & 63;
    float v = 0.f;
    if (x0 + x < W) v = feat[(size_t)ci * (H * W) + y * W + x0 + x];
    tile[ci][x] = v;
  }
  __syncthreads();
  for (int e = threadIdx.x; e < 64 * 128; e += 256) {
    int x = e >> 7, ci = e & 127;
    if (x0 + x >= W) continue;
    u16 hi, lo;
    split_f16(tile[ci][x], hi, lo);
    size_t out = ((size_t)(y + 1) * (W + 2) + (x0 + x + 1)) * 128 + ci;
    Fh[out] = hi; Fl[out] = lo;
  }
}

// ============================ conv weight repack: [co][ci][tap] -> [tap][co][ci] f16 split ============================
__global__ __launch_bounds__(256) void conv_w_repack_kernel(
    const float* __restrict__ w3, u16* __restrict__ Wh, u16* __restrict__ Wl) {
  int idx = blockIdx.x * 256 + threadIdx.x;
  if (idx >= 9 * 128 * 128) return;
  int tap = idx >> 14;
  int r = idx & 16383;
  int co = r >> 7, ci = r & 127;
  u16 hi, lo;
  split_f16(w3[co * 1152 + ci * 9 + tap], hi, lo);
  Wh[idx] = hi; Wl[idx] = lo;
}

// ============================ implicit-GEMM MFMA 3x3 conv (f16x3 dual-acc) ============================
template <int H, int W>
__global__ __launch_bounds__(256) void conv_mfma_kernel(
    const u16* __restrict__ Fh, const u16* __restrict__ Fl,
    const u16* __restrict__ Wh, const u16* __restrict__ Wl,
    const float* __restrict__ b3, float* __restrict__ tbuf) {
  __shared__ u16 sAh[128][40], sAl[128][40], sBh[128][40], sBl[128][40];
  int tid = threadIdx.x;
  int m0 = blockIdx.x * 128;
  int w = tid >> 6, lane = tid & 63;
  int wm = (w >> 1) * 64, wn = (w & 1) * 64;
  int quad = lane >> 4, lrow = lane & 15;
  f32x4 acc1[4][4], acc2[4][4];
#pragma unroll
  for (int i = 0; i < 4; i++)
#pragma unroll
    for (int j = 0; j < 4; j++) { acc1[i][j] = (f32x4)0.f; acc2[i][j] = (f32x4)0.f; }

  for (int tap = 0; tap < 9; tap++) {
    int ky = tap / 3, kx = tap - (tap / 3) * 3;
    for (int c = 0; c < 4; c++) {
      for (int e = tid; e < 512; e += 256) {
        int row = e >> 2, seg = (e & 3) * 8;
        int m = m0 + row;
        int y = m / W, x = m - y * W;
        size_t pidx = ((size_t)(y + ky) * (W + 2) + x + kx) * 128 + c * 32 + seg;
        *(short8*)&sAh[row][seg] = *(const short8*)&Fh[pidx];
        *(short8*)&sAl[row][seg] = *(const short8*)&Fl[pidx];
        size_t bidx = ((size_t)tap * 128 + row) * 128 + c * 32 + seg;
        *(short8*)&sBh[row][seg] = *(const short8*)&Wh[bidx];
        *(short8*)&sBl[row][seg] = *(const short8*)&Wl[bidx];
      }
      __syncthreads();
      int kb = quad * 8;
      f16x8 afh[4], afl[4], bfh[4], bfl[4];
#pragma unroll
      for (int t = 0; t < 4; t++) {
        afh[t] = *(const f16x8*)&sAh[wm + t * 16 + lrow][kb];
        afl[t] = *(const f16x8*)&sAl[wm + t * 16 + lrow][kb];
        bfh[t] = *(const f16x8*)&sBh[wn + t * 16 + lrow][kb];
        bfl[t] = *(const f16x8*)&sBl[wn + t * 16 + lrow][kb];
      }
#pragma unroll
      for (int mt = 0; mt < 4; mt++)
#pragma unroll
        for (int nt = 0; nt < 4; nt++) {
          acc1[mt][nt] = __builtin_amdgcn_mfma_f32_16x16x32_f16(afh[mt], bfh[nt], acc1[mt][nt], 0, 0, 0);
          acc2[mt][nt] = __builtin_amdgcn_mfma_f32_16x16x32_f16(afh[mt], bfl[nt], acc2[mt][nt], 0, 0, 0);
          acc2[mt][nt] = __builtin_amdgcn_mfma_f32_16x16x32_f16(afl[mt], bfh[nt], acc2[mt][nt], 0, 0, 0);
        }
      __syncthreads();
    }
  }
#pragma unroll
  for (int nt = 0; nt < 4; nt++) {
    int col = wn + nt * 16 + lrow;
    float bias = b3[col];
#pragma unroll
    for (int mt = 0; mt < 4; mt++) {
#pragma unroll
      for (int reg = 0; reg < 4; reg++) {
        int row = m0 + wm + mt * 16 + quad * 4 + reg;
        float v = acc1[mt][nt][reg] + kISC * acc2[mt][nt][reg] + bias;
        tbuf[(size_t)row * 128 + col] = fmaxf(v, 0.f);
      }
    }
  }
}

// ============================ 1x1 heads from t (HWC fp32) ============================
__global__ __launch_bounds__(256) void head_1x1_kernel(
    const float* __restrict__ tbuf,
    const float* __restrict__ wc, const float* __restrict__ bcs,
    const float* __restrict__ wb, const float* __restrict__ bbx,
    unsigned* __restrict__ keys, float* __restrict__ deltas, int aoff, int HW) {
  __shared__ float wl[15][128];
  __shared__ float bl[15];
  for (int e = threadIdx.x; e < 15 * 128; e += 256) {
    int oc = e >> 7, k = e & 127;
    wl[oc][k] = (oc < 3) ? wc[oc * 128 + k] : wb[(oc - 3) * 128 + k];
  }
  if (threadIdx.x < 15)
    bl[threadIdx.x] = (threadIdx.x < 3) ? bcs[threadIdx.x] : bbx[threadIdx.x - 3];
  __syncthreads();
  int m = blockIdx.x * 256 + threadIdx.x;
  if (m >= HW) return;
  const float* trow = tbuf + (size_t)m * 128;
  float dot[15];
#pragma unroll
  for (int o = 0; o < 15; o++) dot[o] = 0.f;
  for (int k = 0; k < 128; k += 4) {
    float4 v = *(const float4*)&trow[k];
#pragma unroll
    for (int o = 0; o < 15; o++) {
      dot[o] = fmaf(wl[o][k], v.x, dot[o]);
      dot[o] = fmaf(wl[o][k + 1], v.y, dot[o]);
      dot[o] = fmaf(wl[o][k + 2], v.z, dot[o]);
      dot[o] = fmaf(wl[o][k + 3], v.w, dot[o]);
    }
  }
#pragma unroll
  for (int oc = 0; oc < 15; oc++) {
    float s = dot[oc] + bl[oc];
    if (oc < 3) {
      keys[aoff + m * 3 + oc] = keyOf(s);
    } else {
      int bc = oc - 3, a = bc >> 2, comp = bc & 3;
      deltas[(size_t)(aoff + m * 3 + a) * 4 + comp] = s;
    }
  }
}

// ============================ radix select per (image,level 0..2) ============================
__global__ __launch_bounds__(1024) void radix_select_kernel(
    const unsigned* __restrict__ keys, unsigned* __restrict__ tkT, unsigned* __restrict__ tkNeed) {
  int job = blockIdx.x;
  int b = job / 3, l = job - b * 3;
  const unsigned* kb = keys + (size_t)b * kAImg + c_AOFF[l];
  int n = c_ALVL[l];
  __shared__ unsigned hist[256];
  __shared__ unsigned s_sel, s_remk;
  unsigned prefix = 0, pmask = 0, remk = 2000;
  for (int shift = 24; shift >= 0; shift -= 8) {
    if (threadIdx.x < 256) hist[threadIdx.x] = 0;
    __syncthreads();
    for (int i = threadIdx.x; i < n; i += 1024) {
      unsigned key = kb[i];
      if ((key & pmask) == prefix) atomicAdd(&hist[(key >> shift) & 255u], 1u);
    }
    __syncthreads();
    if (threadIdx.x == 0) {
      unsigned cum = 0; int sel = 0;
      for (int d = 255; d >= 0; d--) {
        unsigned c = hist[d];
        if (cum + c >= remk) { sel = d; break; }
        cum += c;
      }
      s_sel = (unsigned)sel; s_remk = remk - cum;
    }
    __syncthreads();
    prefix |= (s_sel << shift);
    pmask |= (255u << shift);
    remk = s_remk;
    __syncthreads();
  }
  if (threadIdx.x == 0) { tkT[b * 4 + l] = prefix; tkNeed[b * 4 + l] = remk; }
}

// ============================ candidate build ============================
__global__ __launch_bounds__(1024) void cand_build_kernel(
    const unsigned* __restrict__ keys, const float* __restrict__ deltas,
    const unsigned* __restrict__ tkT, const unsigned* __restrict__ tkNeed,
    Cand* __restrict__ cand, AnchTab tab) {
  int b = blockIdx.x >> 2, l = blockIdx.x & 3;
  int n = c_ALVL[l];
  int W = c_LW[l];
  int stride = c_STRIDE[l];
  const unsigned* kb = keys + (size_t)b * kAImg + c_AOFF[l];
  const float* db = deltas + ((size_t)b * kAImg + c_AOFF[l]) * 4;
  Cand* cb = cand + (size_t)b * kNCand + c_CBASE[l];
  bool selAll = (l == 3);
  unsigned T = selAll ? 0u : tkT[b * 4 + l];
  unsigned need = selAll ? 0u : tkNeed[b * 4 + l];
  __shared__ unsigned wbuf[16];
  __shared__ unsigned s_runeq, s_runout;
  if (threadIdx.x == 0) { s_runeq = 0; s_runout = 0; }
  __syncthreads();
  for (int c0 = 0; c0 < n; c0 += 1024) {
    int i = c0 + (int)threadIdx.x;
    bool act = i < n;
    unsigned key = act ? kb[i] : 0u;
    bool isEq = (!selAll) && act && (key == T);
    unsigned eqTot;
    unsigned eqExc = block_scan_bool(isEq, wbuf, eqTot);
    unsigned runeq = s_runeq;
    unsigned runout = s_runout;
    bool isSel = act && (selAll || key > T || (isEq && (runeq + eqExc) < need));
    unsigned selTot;
    unsigned selExc = block_scan_bool(isSel, wbuf, selTot);
    if (isSel) {
      int slot = (int)(runout + selExc);
      int pos = i / 3, a = i - pos * 3;
      int yy = pos / W, xx = pos - yy * W;
      float sx = (float)(xx * stride), sy = (float)(yy * stride);
      float ax1 = tab.v[l][a][0] + sx;
      float ay1 = tab.v[l][a][1] + sy;
      float ax2 = tab.v[l][a][2] + sx;
      float ay2 = tab.v[l][a][3] + sy;
      float d0 = db[(size_t)i * 4 + 0], d1 = db[(size_t)i * 4 + 1];
      float d2 = db[(size_t)i * 4 + 2], d3 = db[(size_t)i * 4 + 3];
      float4 bx = decode_clip(ax1, ay1, ax2, ay2, d0, d1, d2, d3, 1.f, 1.f, 1.f, 1.f);
      bool ok = (bx.z - bx.x >= 0.001f) && (bx.w - bx.y >= 0.001f);
      Cand cd;
      cd.x1 = bx.x; cd.y1 = bx.y; cd.x2 = bx.z; cd.y2 = bx.w;
      cd.key = ok ? key : 0u; cd.lvl = (unsigned)l; cd.pad0 = 0; cd.pad1 = 0;
      cb[slot] = cd;
    }
    __syncthreads();
    if (threadIdx.x == 0) { s_runeq = runeq + eqTot; s_runout = runout + selTot; }
    __syncthreads();
  }
}

// ============================ single-block bitonic sort (desc key, asc slot) ============================
template <int NPAD>
__global__ __launch_bounds__(1024) void sort_desc_kernel(
    const unsigned* __restrict__ keyBase, int strideWords, int nFixed,
    const unsigned* __restrict__ nPtr, unsigned* __restrict__ sortedSlot,
    unsigned* __restrict__ validCnt, int imgStrideKeyWords, int imgStrideSlot) {
  __shared__ unsigned sk[NPAD];
  __shared__ unsigned short sslot[NPAD];
  __shared__ unsigned s_cnt;
  int b = blockIdx.x;
  const unsigned* kbase = keyBase + (size_t)b * imgStrideKeyWords;
  unsigned* oslot = sortedSlot + (size_t)b * imgStrideSlot;
  unsigned* ocnt = validCnt + b;
  int n = nFixed;
  if (nPtr) { int m = (int)nPtr[b]; n = n < m ? n : m; }
  for (int i = threadIdx.x; i < NPAD; i += 1024) {
    sk[i] = (i < n) ? kbase[(size_t)i * strideWords] : 0u;
    sslot[i] = (unsigned short)i;
  }
  if (threadIdx.x == 0) s_cnt = 0;
  __syncthreads();
  for (int k2 = 2; k2 <= NPAD; k2 <<= 1) {
    for (int j = k2 >> 1; j > 0; j >>= 1) {
      for (int i = threadIdx.x; i < NPAD; i += 1024) {
        int ixj = i ^ j;
        if (ixj > i) {
          unsigned ka = sk[i], kb2 = sk[ixj];
          unsigned short sa = sslot[i], sb = sslot[ixj];
          bool aGreater = (ka > kb2) || (ka == kb2 && sa < sb);
          bool up = ((i & k2) == 0);
          bool doSwap = up ? (!aGreater) : aGreater;
          if (doSwap) { sk[i] = kb2; sk[ixj] = ka; sslot[i] = sb; sslot[ixj] = sa; }
        }
      }
      __syncthreads();
    }
  }
  unsigned local = 0;
  for (int i = threadIdx.x; i < NPAD; i += 1024) {
    oslot[i] = (unsigned)sslot[i];
    if (sk[i] > 0u) local++;
  }
  atomicAdd(&s_cnt, local);
  __syncthreads();
  if (threadIdx.x == 0) *ocnt = s_cnt;
}

// ============================ sorted gather (RPN): raw boxes per sorted pos ============================
__global__ __launch_bounds__(256) void rpn_sort_gather(
    const Cand* __restrict__ cand, const unsigned* __restrict__ ss,
    const unsigned* __restrict__ validCnt, float4* __restrict__ boxRaw) {
  int b = blockIdx.y;
  int pos = blockIdx.x * 256 + threadIdx.x;
  int valid = (int)validCnt[b];
  float4 raw = make_float4(0.f, 0.f, 0.f, 0.f);
  if (pos < valid) {
    Cand c = cand[(size_t)b * kNCand + ss[(size_t)b * 8192 + pos]];
    raw = make_float4(c.x1, c.y1, c.x2, c.y2);
  }
  boxRaw[(size_t)b * 8192 + pos] = raw;
}

// ============================ per-level stable compaction (sorted order, offset boxes) ============================
__global__ __launch_bounds__(1024) void lvl_compact_kernel(
    const Cand* __restrict__ cand, const unsigned* __restrict__ ss,
    const unsigned* __restrict__ validCnt, float4* __restrict__ boxLvl,
    unsigned* __restrict__ lvlList, unsigned* __restrict__ lvlCnt) {
  int b = blockIdx.x;
  int valid = (int)validCnt[b];
  __shared__ unsigned wbuf[16];
  __shared__ unsigned s_run;
  for (int l = 0; l < 4; l++) {
    if (threadIdx.x == 0) s_run = 0;
    __syncthreads();
    for (int c0 = 0; c0 < 8192; c0 += 1024) {
      int pos = c0 + (int)threadIdx.x;
      bool act = pos < valid;
      unsigned lv = 99u;
      float4 off4 = make_float4(0.f, 0.f, 0.f, 0.f);
      if (act) {
#pragma clang fp contract(off)
        Cand c = cand[(size_t)b * kNCand + ss[(size_t)b * 8192 + pos]];
        lv = c.lvl;
        float off = 801.0f * (float)c.lvl;
        off4 = make_float4(c.x1 + off, c.y1 + off, c.x2 + off, c.y2 + off);
      }
      bool isl = act && (lv == (unsigned)l);
      unsigned tot;
      unsigned exc = block_scan_bool(isl, wbuf, tot);
      unsigned run = s_run;
      if (isl) {
        unsigned slot = run + exc;
        lvlList[((size_t)b * 4 + l) * 2048 + slot] = (unsigned)pos;
        boxLvl[((size_t)b * 4 + l) * 2048 + slot] = off4;
      }
      __syncthreads();
      if (threadIdx.x == 0) s_run = run + tot;
      __syncthreads();
    }
    if (threadIdx.x == 0) lvlCnt[b * 4 + l] = s_run;
    __syncthreads();
  }
}

// ============================ sorted gather (head): boxes + scores ============================
__global__ __launch_bounds__(256) void head_sort_gather(
    const HeadCand* __restrict__ hc, const unsigned* __restrict__ hsorted,
    const unsigned* __restrict__ hvalid, float4* __restrict__ hbox, float* __restrict__ hsc) {
  int pos = blockIdx.x * 256 + threadIdx.x;
  int valid = (int)*hvalid;
  float4 v = make_float4(0.f, 0.f, 0.f, 0.f);
  float s = 0.f;
  if (pos < valid) {
    HeadCand c = hc[hsorted[pos]];
    v = make_float4(c.x1, c.y1, c.x2, c.y2);
    s = c.score;
  }
  hbox[pos] = v;
  hsc[pos] = s;
}

// ============================ NMS suppression-mask build ============================
__global__ __launch_bounds__(64) void nms_mask_kernel(
    const float4* __restrict__ boxesOff, const unsigned* __restrict__ validCnt,
    unsigned long long* __restrict__ mask, int rowStrideWords,
    int imgBoxStride, long long imgMaskStride, float th) {
  int b = blockIdx.z;
  const float4* bx = boxesOff + (size_t)b * imgBoxStride;
  unsigned long long* mrow = mask + (size_t)b * imgMaskStride;
  int valid = (int)validCnt[b];
  int i = blockIdx.x * 64 + threadIdx.x;
  int j0 = blockIdx.y * 64;
  __shared__ float4 sb[64];
  sb[threadIdx.x] = bx[j0 + threadIdx.x];
  __syncthreads();
  float4 a = bx[i];
  unsigned long long bits = 0;
  for (int t = 0; t < 64; t++) {
    int j = j0 + t;
    if (j > i && j < valid && iou_pair(a, sb[t]) > th) bits |= (1ull << t);
  }
  mrow[(size_t)i * rowStrideWords + (j0 >> 6)] = bits;
}

// ============================ tile-parallel greedy NMS reduce ============================
// One block = one wave (64 threads) per job. Mask rows: 32 u64 words (<=2048 cands).
// Serial chain is per-TILE (64 cands), not per-candidate; decisions bit-identical
// to the forward suppression scan (== iterative argmax NMS for fixed sorted scores).
template <int KMAX>
__global__ __launch_bounds__(64) void nms_reduce_tile_kernel(
    const unsigned long long* __restrict__ mask, const unsigned* __restrict__ validCnt,
    unsigned* __restrict__ keptIdx, unsigned* __restrict__ keptCnt,
    long long jobMaskStride) {
  __shared__ unsigned long long lds[2][64][33];  // pad 33 to spread LDS banks
  int job = blockIdx.x;
  const unsigned long long* mrow = mask + (size_t)job * jobMaskStride;
  int valid = (int)validCnt[job];
  unsigned* kout = keptIdx + (size_t)job * KMAX;
  int lane = threadIdx.x;
  unsigned long long removed = 0ull;  // lane<32 holds word[lane]
  int kept = 0;
  int ntiles = (valid + 63) >> 6;     // <= 32

  unsigned long long pf[32];
  auto issue = [&](int k) {
    int base = k * 64;
#pragma unroll
    for (int i = 0; i < 32; i++) {
      int idx = i * 64 + lane;
      int r = idx >> 5, w = idx & 31;
      pf[i] = (base + r < valid) ? mrow[(size_t)(base + r) * 32 + w] : 0ull;
    }
  };
  auto commit = [&](int buf) {
#pragma unroll
    for (int i = 0; i < 32; i++) {
      int idx = i * 64 + lane;
      int r = idx >> 5, w = idx & 31;
      lds[buf][r][w] = pf[i];
    }
  };

  if (ntiles > 0) { issue(0); commit(0); }
  bool full = false;
  for (int k = 0; k < ntiles && !full; k++) {
    int buf = k & 1;
    if (k + 1 < ntiles) issue(k + 1);           // loads in flight over decision loop
    int base = k * 64;
    unsigned long long tb = lds[buf][lane][k];  // own row's in-tile word
    unsigned long long globalbits = shfl64(removed, k);
    int nt = valid - base; if (nt > 64) nt = 64;
    unsigned long long keptm = 0ull, supp = globalbits;
    for (int t = 0; t < nt; t++) {
      if (!((supp >> t) & 1ull)) {
        keptm |= (1ull << t);
        supp |= shfl64(tb, t);
        if (lane == 0) kout[kept] = (unsigned)(base + t);
        kept++;
        if (kept >= KMAX) { full = true; break; }
      }
    }
    // OR kept rows into the running removed mask (for future tiles)
    unsigned long long km = keptm;
    while (km) {
      int t = __builtin_ctzll(km);
      km &= km - 1;
      if (lane < 32) removed |= lds[buf][t][lane];
    }
    if (k + 1 < ntiles && !full) commit((k + 1) & 1);
  }
  if (lane == 0) keptCnt[job] = (unsigned)kept;
}

// ============================ scatter per-level kept -> global-pos flags ============================
__global__ __launch_bounds__(256) void flag_scatter_kernel(
    const unsigned* __restrict__ keptLoc, const unsigned* __restrict__ lvlKeptCnt,
    const unsigned* __restrict__ lvlList, unsigned char* __restrict__ kflag) {
  int job = blockIdx.y;
  int k = blockIdx.x * 256 + threadIdx.x;
  if (k >= (int)lvlKeptCnt[job]) return;
  unsigned local = keptLoc[(size_t)job * 2048 + k];
  unsigned pos = lvlList[(size_t)job * 2048 + local];
  int b = job >> 2;
  kflag[(size_t)b * 8192 + pos] = 1;
}

// ============================ merge kept flags: first 2000 in global sorted order ============================
__global__ __launch_bounds__(1024) void merge_kept_kernel(
    const unsigned char* __restrict__ kflag, const unsigned* __restrict__ validCnt,
    unsigned* __restrict__ keptIdx, unsigned* __restrict__ Mc) {
  int b = blockIdx.x;
  int valid = (int)validCnt[b];
  __shared__ unsigned wbuf[16];
  __shared__ unsigned s_run;
  if (threadIdx.x == 0) s_run = 0;
  __syncthreads();
  for (int c0 = 0; c0 < 8192; c0 += 1024) {
    int i = c0 + (int)threadIdx.x;
    bool k = (i < valid) && kflag[(size_t)b * 8192 + i];
    unsigned tot;
    unsigned exc = block_scan_bool(k, wbuf, tot);
    unsigned run = s_run;
    if (k) {
      unsigned slot = run + exc;
      if (slot < kPostNms) keptIdx[(size_t)b * kPostNms + slot] = (unsigned)i;
    }
    __syncthreads();
    if (threadIdx.x == 0) s_run = run + tot;
    __syncthreads();
  }
  if (threadIdx.x == 0) {
    unsigned r = s_run;
    Mc[b] = r < kPostNms ? r : kPostNms;
  }
}

// ============================ kept-index gathers ============================
__global__ __launch_bounds__(256) void rpn_roi_gather(
    const unsigned* __restrict__ keptIdx, const unsigned* __restrict__ Mc,
    const float4* __restrict__ boxRaw, float* __restrict__ rois) {
  int b = blockIdx.y;
  int k = blockIdx.x * 256 + threadIdx.x;
  if (k >= (int)Mc[b]) return;
  unsigned i = keptIdx[(size_t)b * kPostNms + k];
  float4 v = boxRaw[(size_t)b * 8192 + i];
  float* r = rois + ((size_t)b * kPostNms + k) * 4;
  r[0] = v.x; r[1] = v.y; r[2] = v.z; r[3] = v.w;
}

__global__ __launch_bounds__(128) void head_det_gather(
    const unsigned* __restrict__ keptIdx, const unsigned* __restrict__ cnt,
    const float4* __restrict__ hbox, const float* __restrict__ hsc,
    float* __restrict__ detBox, float* __restrict__ detSc) {
  int k = threadIdx.x;
  if (k >= (int)*cnt || k >= 100) return;
  unsigned i = keptIdx[k];
  float4 v = hbox[i];
  detBox[k * 4 + 0] = v.x; detBox[k * 4 + 1] = v.y;
  detBox[k * 4 + 2] = v.z; detBox[k * 4 + 3] = v.w;
  detSc[k] = hsc[i];
}

// ============================ ROI params ============================
__global__ __launch_bounds__(256) void roi_params_kernel(
    const float* __restrict__ rois, const unsigned* __restrict__ Mc, RoiParam* __restrict__ par) {
  int b = blockIdx.y;
  int i = blockIdx.x * 256 + threadIdx.x;
  if (i >= (int)Mc[b]) return;
  const float* r = rois + ((size_t)b * kPostNms + i) * 4;
  float x1 = r[0], y1 = r[1], x2 = r[2], y2 = r[3];
  float area = (x2 - x1) * (y2 - y1);
  float tgt = floorf(4.0f + log2f(sqrtf(fmaxf(area, 0.f)) / 224.0f + 1e-6f));
  tgt = fminf(fmaxf(tgt, 2.f), 5.f);
  int l = (int)tgt - 2;
  const float scales[4] = {0.25f, 0.125f, 0.0625f, 0.03125f};
  float sc = scales[l];
  RoiParam p;
  p.lvl = l;
  p.x1 = x1 * sc; p.y1 = y1 * sc;
  p.rw = fmaxf(x2 * sc - p.x1, 1.0f);
  p.rh = fmaxf(y2 * sc - p.y1, 1.0f);
  p.pad0 = p.pad1 = p.pad2 = 0;
  par[(size_t)b * kPostNms + i] = p;
}

// ============================ pooled pad (zero rows >= Mc) ============================
__global__ __launch_bounds__(256) void pad_pooled_kernel(
    u16* __restrict__ hi, u16* __restrict__ lo, const unsigned* __restrict__ Mc, int b) {
  int start = (int)Mc[b] * 6272;
  const int total = kMPad * 6272;
  for (int i = start + (int)(blockIdx.x * 256 + threadIdx.x); i < total; i += 512 * 256) {
    hi[i] = 0; lo[i] = 0;
  }
}

// ============================ multi-scale ROI align (writes split-f16) ============================
__global__ __launch_bounds__(256) void roi_align_kernel(
    const float* __restrict__ f0, const float* __restrict__ f1,
    const float* __restrict__ f2, const float* __restrict__ f3,
    const RoiParam* __restrict__ par, const unsigned* __restrict__ Mc,
    u16* __restrict__ pooledHi, u16* __restrict__ pooledLo, int b) {
  int idx = blockIdx.x * 256 + threadIdx.x;
  int roi = idx / 6272;
  if (roi >= (int)Mc[b]) return;
  int rem = idx - roi * 6272;
  int c = rem / 49, bin = rem - c * 49;
  int py = bin / 7, px = bin - py * 7;
  RoiParam p = par[roi];
  int H = c_LH[p.lvl], W = c_LW[p.lvl];
  const float* f = (p.lvl == 0 ? f0 : p.lvl == 1 ? f1 : p.lvl == 2 ? f2 : f3);
  f += ((size_t)b * 128 + c) * (size_t)(H * W);
  float Hf = (float)H, Wf = (float)W;
  float rh7 = p.rh / 7.0f, rw7 = p.rw / 7.0f;
  float sum = 0.f;
#pragma unroll
  for (int sy = 0; sy < 2; sy++) {
    float offy = (float)py + ((float)sy + 0.5f) * 0.5f;
    float Y = p.y1 + offy * rh7;
    float yc = fminf(fmaxf(Y, 0.f), Hf - 1.f);
    float y0f = floorf(yc);
    int y0 = (int)y0f;
    int y1 = min(y0 + 1, H - 1);
    float ly = yc - y0f, hy = 1.f - ly;
#pragma unroll
    for (int sx = 0; sx < 2; sx++) {
      float offx = (float)px + ((float)sx + 0.5f) * 0.5f;
      float X = p.x1 + offx * rw7;
      bool valid = (Y > -1.f) && (Y < Hf) && (X > -1.f) && (X < Wf);
      float xc = fminf(fmaxf(X, 0.f), Wf - 1.f);
      float x0f = floorf(xc);
      int x0 = (int)x0f;
      int x1i = min(x0 + 1, W - 1);
      float lx = xc - x0f, hx = 1.f - lx;
      float v = hy * hx * f[y0 * W + x0] + hy * lx * f[y0 * W + x1i] +
                ly * hx * f[y1 * W + x0] + ly * lx * f[y1 * W + x1i];
      sum += valid ? v : 0.f;
    }
  }
  float v = sum * 0.25f;
  u16 hi, lo;
  split_f16(v, hi, lo);
  pooledHi[idx] = hi;
  pooledLo[idx] = lo;
}

// ============================ weight split conversion ============================
__global__ __launch_bounds__(256) void convert_split_kernel(
    const float* __restrict__ src, u16* __restrict__ hi, u16* __restrict__ lo, int n) {
  for (int i = blockIdx.x * 256 + threadIdx.x; i < n; i += gridDim.x * 256) {
    u16 h, l;
    split_f16(src[i], h, l);
    hi[i] = h; lo[i] = l;
  }
}

// ============================ f16x3 dual-acc split-K MFMA GEMM ============================
__global__ __launch_bounds__(256) void gemm_f16x3_kernel(
    const u16* __restrict__ Ah, const u16* __restrict__ Al,
    const u16* __restrict__ Bh, const u16* __restrict__ Bl,
    float* __restrict__ Cpart, int K, int kChunks) {
  __shared__ u16 sAh[128][40], sAl[128][40], sBh[128][40], sBl[128][40];
  int tid = threadIdx.x;
  int m0 = blockIdx.y * 128, n0 = blockIdx.x * 128;
  int kBase = blockIdx.z * kChunks * 32;
  int w = tid >> 6, lane = tid & 63;
  int wm = (w >> 1) * 64, wn = (w & 1) * 64;
  int quad = lane >> 4, lrow = lane & 15;
  f32x4 acc1[4][4], acc2[4][4];
#pragma unroll
  for (int i = 0; i < 4; i++)
#pragma unroll
    for (int j = 0; j < 4; j++) { acc1[i][j] = (f32x4)0.f; acc2[i][j] = (f32x4)0.f; }

  for (int c = 0; c < kChunks; c++) {
    int k0 = kBase + c * 32;
    for (int e = tid; e < 512; e += 256) {
      int row = e >> 2, kk = (e & 3) * 8;
      size_t ga = (size_t)(m0 + row) * K + k0 + kk;
      size_t gb = (size_t)(n0 + row) * K + k0 + kk;
      *(short8*)&sAh[row][kk] = *(const short8*)&Ah[ga];
      *(short8*)&sAl[row][kk] = *(const short8*)&Al[ga];
      *(short8*)&sBh[row][kk] = *(const short8*)&Bh[gb];
      *(short8*)&sBl[row][kk] = *(const short8*)&Bl[gb];
    }
    __syncthreads();
    int kb = quad * 8;
    f16x8 afh[4], afl[4], bfh[4], bfl[4];
#pragma unroll
    for (int t = 0; t < 4; t++) {
      afh[t] = *(const f16x8*)&sAh[wm + t * 16 + lrow][kb];
      afl[t] = *(const f16x8*)&sAl[wm + t * 16 + lrow][kb];
      bfh[t] = *(const f16x8*)&sBh[wn + t * 16 + lrow][kb];
      bfl[t] = *(const f16x8*)&sBl[wn + t * 16 + lrow][kb];
    }
#pragma unroll
    for (int mt = 0; mt < 4; mt++)
#pragma unroll
      for (int nt = 0; nt < 4; nt++) {
        acc1[mt][nt] = __builtin_amdgcn_mfma_f32_16x16x32_f16(afh[mt], bfh[nt], acc1[mt][nt], 0, 0, 0);
        acc2[mt][nt] = __builtin_amdgcn_mfma_f32_16x16x32_f16(afh[mt], bfl[nt], acc2[mt][nt], 0, 0, 0);
        acc2[mt][nt] = __builtin_amdgcn_mfma_f32_16x16x32_f16(afl[mt], bfh[nt], acc2[mt][nt], 0, 0, 0);
      }
    __syncthreads();
  }
  float* out = Cpart + (size_t)blockIdx.z * (kMPad * 1024);
#pragma unroll
  for (int mt = 0; mt < 4; mt++)
#pragma unroll
    for (int nt = 0; nt < 4; nt++) {
      int col = n0 + wn + nt * 16 + lrow;
#pragma unroll
      for (int reg = 0; reg < 4; reg++) {
        int row = m0 + wm + mt * 16 + quad * 4 + reg;
        out[(size_t)row * 1024 + col] = acc1[mt][nt][reg] + kISC * acc2[mt][nt][reg];
      }
    }
}

// ============================ combine partials: bias+relu -> split-f16 ============================
__global__ __launch_bounds__(256) void combine_relu_split_kernel(
    const float* __restrict__ part, const float* __restrict__ bias,
    u16* __restrict__ hi, u16* __restrict__ lo) {
  int idx = blockIdx.x * 256 + threadIdx.x;
  int n = idx & 1023;
  float v = fmaxf(part[idx] + part[idx + kMPad * 1024] + bias[n], 0.f);
  u16 h, l;
  split_f16(v, h, l);
  hi[idx] = h; lo[idx] = l;
}

// ============================ combine partials: bias+relu -> f32 ============================
__global__ __launch_bounds__(256) void combine_relu_f32_kernel(
    const float* __restrict__ part, const float* __restrict__ bias,
    float* __restrict__ out) {
  int idx = blockIdx.x * 256 + threadIdx.x;
  int n = idx & 1023;
  out[idx] = fmaxf(part[idx] + part[idx + kMPad * 1024] + bias[n], 0.f);
}

// ============================ head linear (cls 2 + bbox 8 per roi) ============================
__global__ __launch_bounds__(64) void head_linear_kernel(
    const float* __restrict__ H2, const float* __restrict__ cw, const float* __restrict__ cb2,
    const float* __restrict__ bw, const float* __restrict__ bb2,
    const unsigned* __restrict__ Mc, float* __restrict__ out10) {
  int r = blockIdx.x;
  if (r >= (int)*Mc) return;
  __shared__ float x[1024];
  const float* h = H2 + (size_t)r * 1024;
  for (int i = threadIdx.x; i < 1024; i += 64) x[i] = h[i];
  __syncthreads();
  int t = threadIdx.x;
  if (t < 10) {
    const float* w = (t < 2) ? (cw + t * 1024) : (bw + (t - 2) * 1024);
    float bias = (t < 2) ? cb2[t] : bb2[t - 2];
    float dot = 0.f;
    for (int k = 0; k < 1024; k++) dot = fmaf(w[k], x[k], dot);
    out10[r * 10 + t] = dot + bias;
  }
}

// ============================ head decode ============================
__global__ __launch_bounds__(256) void head_decode_kernel(
    const float* __restrict__ out10, const float* __restrict__ rois,
    const unsigned* __restrict__ Mc, HeadCand* __restrict__ hc, int b) {
#pragma clang fp contract(off)
  int r = blockIdx.x * 256 + threadIdx.x;
  if (r >= (int)Mc[b]) return;
  const float* h = out10 + (size_t)r * 10;
  float l0 = h[0], l1 = h[1];
  float mx = fmaxf(l0, l1);
  float e0 = expf(l0 - mx), e1 = expf(l1 - mx);
  float sfg = e1 / (e0 + e1);
  const float* rr = rois + ((size_t)b * kPostNms + r) * 4;
  float4 bx = decode_clip(rr[0], rr[1], rr[2], rr[3], h[6], h[7], h[8], h[9],
                          10.f, 10.f, 5.f, 5.f);
  bool keep = (sfg > 0.05f) && (bx.z - bx.x >= 0.01f) && (bx.w - bx.y >= 0.01f);
  HeadCand c;
  c.x1 = bx.x; c.y1 = bx.y; c.x2 = bx.z; c.y2 = bx.w;
  c.score = sfg;
  c.key = keep ? keyOf(sfg) : 0u;
  c.pad0 = c.pad1 = 0;
  hc[r] = c;
}

// ============================ final output ============================
__global__ __launch_bounds__(256) void output_kernel(
    const float* __restrict__ detBox, const float* __restrict__ detSc,
    const unsigned* __restrict__ detCnt, float* __restrict__ out) {
  int t = threadIdx.x;
  if (t >= 200) return;
  int b = t / 100, q = t - b * 100;
  int cnt = (int)detCnt[b];
  float bx0 = 0.f, bx1 = 0.f, bx2 = 0.f, bx3 = 0.f, sc = 0.f, lb = 0.f;
  if (q < cnt) {
    const float* d = detBox + ((size_t)b * 100 + q) * 4;
    bx0 = d[0]; bx1 = d[1]; bx2 = d[2]; bx3 = d[3];
    sc = detSc[b * 100 + q];
    lb = 1.0f;
  }
  float* ob = out + ((size_t)b * 100 + q) * 4;
  ob[0] = bx0; ob[1] = bx1; ob[2] = bx2; ob[3] = bx3;
  out[800 + t] = sc;
  out[1000 + t] = lb;
}

// ============================ host launcher ============================
extern "C" void kernel_launch(void* const* d_in, const int* in_sizes, int n_in,
                              void* d_out, int out_size, void* d_ws, size_t ws_size,
                              hipStream_t stream) {
  (void)in_sizes; (void)n_in; (void)out_size; (void)ws_size;
  const float* feats[4] = {(const float*)d_in[0], (const float*)d_in[1],
                           (const float*)d_in[2], (const float*)d_in[3]};
  const float* w3 = (const float*)d_in[4];
  const float* b3 = (const float*)d_in[5];
  const float* wc = (const float*)d_in[6];
  const float* bcs = (const float*)d_in[7];
  const float* wb = (const float*)d_in[8];
  const float* bbx = (const float*)d_in[9];
  const float* fc6w = (const float*)d_in[10];
  const float* fc6b = (const float*)d_in[11];
  const float* fc7w = (const float*)d_in[12];
  const float* fc7b = (const float*)d_in[13];
  const float* clsw = (const float*)d_in[14];
  const float* clsb = (const float*)d_in[15];
  const float* bboxw = (const float*)d_in[16];
  const float* bboxb = (const float*)d_in[17];

  unsigned char* base = (unsigned char*)d_ws;
  size_t off = 0;
  auto alloc = [&](size_t bytes) -> void* {
    void* p = base + off;
    off += (bytes + 255) & ~(size_t)255;
    return p;
  };
  unsigned* keys = (unsigned*)alloc((size_t)2 * kAImg * 4);
  float* deltas = (float*)alloc((size_t)2 * kAImg * 16);
  unsigned* tkT = (unsigned*)alloc(32);
  unsigned* tkNeed = (unsigned*)alloc(32);
  Cand* cand = (Cand*)alloc((size_t)2 * kNCand * sizeof(Cand));
  unsigned* sortedSlot = (unsigned*)alloc((size_t)2 * 8192 * 4);
  unsigned* validCnt = (unsigned*)alloc(8);
  float4* boxRaw = (float4*)alloc((size_t)2 * 8192 * 16);
  float4* boxLvl = (float4*)alloc((size_t)8 * 2048 * 16);
  unsigned* lvlList = (unsigned*)alloc((size_t)8 * 2048 * 4);
  unsigned* lvlCnt = (unsigned*)alloc(32);
  unsigned long long* lvlMask = (unsigned long long*)alloc((size_t)8 * 2048 * 32 * 8);
  unsigned* keptLoc = (unsigned*)alloc((size_t)8 * 2048 * 4);
  unsigned* lvlKeptCnt = (unsigned*)alloc(32);
  unsigned char* kflag = (unsigned char*)alloc((size_t)2 * 8192);
  unsigned* keptIdx = (unsigned*)alloc((size_t)2 * kPostNms * 4);
  float* rois = (float*)alloc((size_t)2 * kPostNms * 16);
  unsigned* Mc = (unsigned*)alloc(8);
  RoiParam* roiPar = (RoiParam*)alloc((size_t)2 * kPostNms * sizeof(RoiParam));
  // conv pipeline buffers (reused per image/level)
  u16* padHi = (u16*)alloc((size_t)204 * 202 * 128 * 2);
  u16* padLo = (u16*)alloc((size_t)204 * 202 * 128 * 2);
  u16* wTapHi = (u16*)alloc((size_t)9 * 128 * 128 * 2);
  u16* wTapLo = (u16*)alloc((size_t)9 * 128 * 128 * 2);
  float* tbuf = (float*)alloc((size_t)313 * 128 * 128 * 4);
  u16* pooledHi = (u16*)alloc((size_t)kMPad * 6272 * 2);
  u16* pooledLo = (u16*)alloc((size_t)kMPad * 6272 * 2);
  u16* fc6wHi = (u16*)alloc((size_t)1024 * 6272 * 2);
  u16* fc6wLo = (u16*)alloc((size_t)1024 * 6272 * 2);
  u16* fc7wHi = (u16*)alloc((size_t)1024 * 1024 * 2);
  u16* fc7wLo = (u16*)alloc((size_t)1024 * 1024 * 2);
  float* part = (float*)alloc((size_t)2 * kMPad * 1024 * 4);
  u16* H1hi = (u16*)alloc((size_t)kMPad * 1024 * 2);
  u16* H1lo = (u16*)alloc((size_t)kMPad * 1024 * 2);
  float* H2buf = (float*)alloc((size_t)kMPad * 1024 * 4);
  float* out10 = (float*)alloc((size_t)kPostNms * 10 * 4);
  HeadCand* hc = (HeadCand*)alloc((size_t)kPostNms * sizeof(HeadCand));
  unsigned* hsorted = (unsigned*)alloc((size_t)2048 * 4);
  unsigned* hvalid = (unsigned*)alloc(4);
  float4* hbox = (float4*)alloc((size_t)2048 * 16);
  float* hsc = (float*)alloc((size_t)2048 * 4);
  unsigned long long* hMask = (unsigned long long*)alloc((size_t)2048 * 32 * 8);
  unsigned* hkept = (unsigned*)alloc((size_t)128 * 4);
  float* detBox = (float*)alloc((size_t)2 * 100 * 4 * 4);
  float* detSc = (float*)alloc((size_t)2 * 100 * 4);
  unsigned* detCnt = (unsigned*)alloc(8);

  // anchor base table, double precision, round-half-even (matches np.round)
  AnchTab tab;
  {
    const double aspects[3] = {0.5, 1.0, 2.0};
    const int sizes[4] = {32, 64, 128, 256};
    for (int l = 0; l < 4; l++)
      for (int a = 0; a < 3; a++) {
        double hr = sqrt(aspects[a]);
        double wr = 1.0 / hr;
        double wsz = wr * sizes[l], hsz = hr * sizes[l];
        tab.v[l][a][0] = (float)rint(-wsz / 2.0);
        tab.v[l][a][1] = (float)rint(-hsz / 2.0);
        tab.v[l][a][2] = (float)rint(wsz / 2.0);
        tab.v[l][a][3] = (float)rint(hsz / 2.0);
      }
  }

  const int LH[4] = {200, 100, 50, 25}, LW[4] = {200, 100, 50, 25};
  const int AOFF[4] = {0, 120000, 150000, 157500};

  // weight conversions (same work every call; graph-capture safe)
  convert_split_kernel<<<4096, 256, 0, stream>>>(fc6w, fc6wHi, fc6wLo, 1024 * 6272);
  convert_split_kernel<<<1024, 256, 0, stream>>>(fc7w, fc7wHi, fc7wLo, 1024 * 1024);
  conv_w_repack_kernel<<<(9 * 128 * 128 + 255) / 256, 256, 0, stream>>>(w3, wTapHi, wTapLo);

  // RPN conv pipeline (MFMA implicit GEMM) per image per level
  for (int b = 0; b < 2; b++) {
    for (int l = 0; l < 4; l++) {
      int H = LH[l], W = LW[l];
      int HW = H * W;
      int mtiles = (HW + 127) / 128;
      int n32 = (H + 4) * (W + 2) * 128 / 2;
      zero_u32_kernel<<<512, 256, 0, stream>>>((unsigned*)padHi, n32);
      zero_u32_kernel<<<512, 256, 0, stream>>>((unsigned*)padLo, n32);
      const float* fsrc = feats[l] + (size_t)b * 128 * HW;
      dim3 tgrid((W + 63) / 64, H);
      switch (l) {
        case 0:
          transpose_pad_kernel<200, 200><<<tgrid, 256, 0, stream>>>(fsrc, padHi, padLo);
          conv_mfma_kernel<200, 200><<<mtiles, 256, 0, stream>>>(padHi, padLo, wTapHi, wTapLo, b3, tbuf);
          break;
        case 1:
          transpose_pad_kernel<100, 100><<<tgrid, 256, 0, stream>>>(fsrc, padHi, padLo);
          conv_mfma_kernel<100, 100><<<mtiles, 256, 0, stream>>>(padHi, padLo, wTapHi, wTapLo, b3, tbuf);
          break;
        case 2:
          transpose_pad_kernel<50, 50><<<tgrid, 256, 0, stream>>>(fsrc, padHi, padLo);
          conv_mfma_kernel<50, 50><<<mtiles, 256, 0, stream>>>(padHi, padLo, wTapHi, wTapLo, b3, tbuf);
          break;
        default:
          transpose_pad_kernel<25, 25><<<tgrid, 256, 0, stream>>>(fsrc, padHi, padLo);
          conv_mfma_kernel<25, 25><<<mtiles, 256, 0, stream>>>(padHi, padLo, wTapHi, wTapLo, b3, tbuf);
          break;
      }
      head_1x1_kernel<<<(HW + 255) / 256, 256, 0, stream>>>(
          tbuf, wc, bcs, wb, bbx, keys + (size_t)b * kAImg,
          deltas + (size_t)b * kAImg * 4, AOFF[l], HW);
    }
  }

  radix_select_kernel<<<6, 1024, 0, stream>>>(keys, tkT, tkNeed);
  cand_build_kernel<<<8, 1024, 0, stream>>>(keys, deltas, tkT, tkNeed, cand, tab);
  sort_desc_kernel<8192><<<2, 1024, 0, stream>>>(
      ((const unsigned*)cand) + 4, 8, kNCand, nullptr, sortedSlot, validCnt, kNCand * 8, 8192);
  rpn_sort_gather<<<dim3(32, 2), 256, 0, stream>>>(cand, sortedSlot, validCnt, boxRaw);
  lvl_compact_kernel<<<2, 1024, 0, stream>>>(cand, sortedSlot, validCnt, boxLvl, lvlList, lvlCnt);
  // per-(image,level) masks: 8 jobs, 2048 boxes, 32 words/row
  nms_mask_kernel<<<dim3(32, 32, 8), 64, 0, stream>>>(
      boxLvl, lvlCnt, lvlMask, 32, 2048, (long long)2048 * 32, 0.7f);
  nms_reduce_tile_kernel<2048><<<8, 64, 0, stream>>>(
      lvlMask, lvlCnt, keptLoc, lvlKeptCnt, (long long)2048 * 32);
  zero_u32_kernel<<<16, 256, 0, stream>>>((unsigned*)kflag, 4096);
  flag_scatter_kernel<<<dim3(8, 8), 256, 0, stream>>>(keptLoc, lvlKeptCnt, lvlList, kflag);
  merge_kept_kernel<<<2, 1024, 0, stream>>>(kflag, validCnt, keptIdx, Mc);
  rpn_roi_gather<<<dim3(8, 2), 256, 0, stream>>>(keptIdx, Mc, boxRaw, rois);
  roi_params_kernel<<<dim3(8, 2), 256, 0, stream>>>(rois, Mc, roiPar);

  for (int b = 0; b < 2; b++) {
    pad_pooled_kernel<<<512, 256, 0, stream>>>(pooledHi, pooledLo, Mc, b);
    roi_align_kernel<<<49000, 256, 0, stream>>>(
        feats[0], feats[1], feats[2], feats[3], roiPar + (size_t)b * kPostNms, Mc,
        pooledHi, pooledLo, b);
    // fc6: M=2048, N=1024, K=6272 (split 2 x 98 chunks of 32)
    gemm_f16x3_kernel<<<dim3(8, 16, 2), 256, 0, stream>>>(
        pooledHi, pooledLo, fc6wHi, fc6wLo, part, 6272, 98);
    combine_relu_split_kernel<<<8192, 256, 0, stream>>>(part, fc6b, H1hi, H1lo);
    // fc7: M=2048, N=1024, K=1024 (split 2 x 16 chunks of 32)
    gemm_f16x3_kernel<<<dim3(8, 16, 2), 256, 0, stream>>>(
        H1hi, H1lo, fc7wHi, fc7wLo, part, 1024, 16);
    combine_relu_f32_kernel<<<8192, 256, 0, stream>>>(part, fc7b, H2buf);
    head_linear_kernel<<<2000, 64, 0, stream>>>(H2buf, clsw, clsb, bboxw, bboxb, Mc + b, out10);
    head_decode_kernel<<<8, 256, 0, stream>>>(out10, rois, Mc, hc, b);
    sort_desc_kernel<2048><<<1, 1024, 0, stream>>>(
        ((const unsigned*)hc) + 5, 8, 2000, Mc + b, hsorted, hvalid, 0, 0);
    head_sort_gather<<<8, 256, 0, stream>>>(hc, hsorted, hvalid, hbox, hsc);
    nms_mask_kernel<<<dim3(32, 32, 1), 64, 0, stream>>>(
        hbox, hvalid, hMask, 32, 0, 0, 0.5f);
    nms_reduce_tile_kernel<100><<<1, 64, 0, stream>>>(
        hMask, hvalid, hkept, detCnt + b, 0);
    head_det_gather<<<1, 128, 0, stream>>>(
        hkept, detCnt + b, hbox, hsc, detBox + (size_t)b * 400, detSc + (size_t)b * 100);
  }
  output_kernel<<<1, 256, 0, stream>>>(detBox, detSc, detCnt, (float*)d_out);
}

// Round 8
// 2579.223 us; speedup vs baseline: 1.1282x; 1.1282x over previous
//
#include <hip/hip_runtime.h>
#include <cmath>

// ============================ constants ============================
static constexpr int kAImg = 159375;   // anchors per image
static constexpr int kNCand = 7875;    // 2000+2000+2000+1875
static constexpr int kPostNms = 2000;
static constexpr int kMPad = 2048;     // padded roi count for MFMA GEMM
static constexpr float kISC = 1.0f / 4096.0f;

__constant__ int c_AOFF[4]   = {0, 120000, 150000, 157500};
__constant__ int c_ALVL[4]   = {120000, 30000, 7500, 1875};
__constant__ int c_CBASE[4]  = {0, 2000, 4000, 6000};
__constant__ int c_LW[4]     = {200, 100, 50, 25};
__constant__ int c_LH[4]     = {200, 100, 50, 25};
__constant__ int c_STRIDE[4] = {4, 8, 16, 32};

struct Cand     { float x1, y1, x2, y2; unsigned key; unsigned lvl; unsigned pad0, pad1; };
struct HeadCand { float x1, y1, x2, y2; float score; unsigned key; unsigned pad0, pad1; };
struct RoiParam { int lvl; float x1, y1, rw, rh; int pad0, pad1, pad2; };
struct AnchTab  { float v[4][3][4]; };

typedef unsigned short u16;
typedef __attribute__((ext_vector_type(8))) short short8;
typedef __attribute__((ext_vector_type(4))) float f32x4;
typedef _Float16 f16x8 __attribute__((ext_vector_type(8)));

// ============================ device helpers ============================
__device__ __forceinline__ unsigned keyOf(float f) {
  unsigned u = __float_as_uint(f);
  return (u & 0x80000000u) ? ~u : (u | 0x80000000u);
}

// fp32 -> (f16 hi, f16 lo*4096). value = hi + lo/4096, err ~ 2^-24 relative.
__device__ __forceinline__ void split_f16(float f, u16& hi, u16& lo) {
  union { _Float16 h; u16 u; } a, b;
  a.h = (_Float16)f;
  float r = (f - (float)a.h) * 4096.0f;
  b.h = (_Float16)r;
  hi = a.u; lo = b.u;
}

__device__ __forceinline__ unsigned long long shfl64(unsigned long long v, int src) {
  int lo = __shfl((int)(unsigned)(v & 0xffffffffull), src);
  int hi = __shfl((int)(unsigned)(v >> 32), src);
  return ((unsigned long long)(unsigned)hi << 32) | (unsigned)lo;
}

__device__ __forceinline__ float iou_pair(float4 a, float4 b) {
#pragma clang fp contract(off)
  float ix1 = fmaxf(a.x, b.x), iy1 = fmaxf(a.y, b.y);
  float ix2 = fminf(a.z, b.z), iy2 = fminf(a.w, b.w);
  float iw = fmaxf(ix2 - ix1, 0.f), ih = fmaxf(iy2 - iy1, 0.f);
  float inter = iw * ih;
  float a1 = (a.z - a.x) * (a.w - a.y);
  float a2 = (b.z - b.x) * (b.w - b.y);
  float uni = a1 + a2 - inter;
  return uni > 0.f ? inter / uni : 0.f;
}

__device__ __forceinline__ float4 decode_clip(float bx1, float by1, float bx2, float by2,
                                              float d0, float d1, float d2, float d3,
                                              float wx, float wy, float ww, float wh) {
#pragma clang fp contract(off)
  float w = bx2 - bx1, h = by2 - by1;
  float cx = bx1 + 0.5f * w, cy = by1 + 0.5f * h;
  float dx = d0 / wx, dy = d1 / wy;
  float dw = fminf(d2 / ww, 4.135166556742356f);
  float dh = fminf(d3 / wh, 4.135166556742356f);
  float pcx = dx * w + cx, pcy = dy * h + cy;
  float pw = expf(dw) * w, ph = expf(dh) * h;
  float x1 = pcx - 0.5f * pw, y1 = pcy - 0.5f * ph;
  float x2 = pcx + 0.5f * pw, y2 = pcy + 0.5f * ph;
  x1 = fminf(fmaxf(x1, 0.f), 800.f); y1 = fminf(fmaxf(y1, 0.f), 800.f);
  x2 = fminf(fmaxf(x2, 0.f), 800.f); y2 = fminf(fmaxf(y2, 0.f), 800.f);
  return make_float4(x1, y1, x2, y2);
}

// block-wide exclusive scan of a bool over 1024 threads (16 waves)
__device__ __forceinline__ unsigned block_scan_bool(bool p, unsigned* wbuf, unsigned& total) {
  unsigned long long m = __ballot(p);
  int lane = threadIdx.x & 63;
  int wid = threadIdx.x >> 6;
  unsigned exc = (unsigned)__popcll(m & ((lane == 0) ? 0ull : ((~0ull) >> (64 - lane))));
  if (lane == 0) wbuf[wid] = (unsigned)__popcll(m);
  __syncthreads();
  unsigned pre = 0, tot = 0;
#pragma unroll
  for (int w = 0; w < 16; w++) { unsigned c = wbuf[w]; if (w < wid) pre += c; tot += c; }
  total = tot;
  __syncthreads();
  return pre + exc;
}

// ============================ zero fill ============================
__global__ __launch_bounds__(256) void zero_u32_kernel(unsigned* __restrict__ p, int n32) {
  for (int i = blockIdx.x * 256 + threadIdx.x; i < n32; i += gridDim.x * 256) p[i] = 0u;
}

// ============================ NCHW -> padded HWC f16-split transpose ============================
template <int H, int W>
__global__ __launch_bounds__(256) void transpose_pad_kernel(
    const float* __restrict__ feat, u16* __restrict__ Fh, u16* __restrict__ Fl) {
  __shared__ float tile[128][65];
  int y = blockIdx.y;
  int x0 = blockIdx.x * 64;
  for (int e = threadIdx.x; e < 128 * 64; e += 256) {
    int ci = e >> 6, x = e & 63;
    float v = 0.f;
    if (x0 + x < W) v = feat[(size_t)ci * (H * W) + y * W + x0 + x];
    tile[ci][x] = v;
  }
  __syncthreads();
  for (int e = threadIdx.x; e < 64 * 128; e += 256) {
    int x = e >> 7, ci = e & 127;
    if (x0 + x >= W) continue;
    u16 hi, lo;
    split_f16(tile[ci][x], hi, lo);
    size_t out = ((size_t)(y + 1) * (W + 2) + (x0 + x + 1)) * 128 + ci;
    Fh[out] = hi; Fl[out] = lo;
  }
}

// ============================ conv weight repack: [co][ci][tap] -> [tap][co][ci] f16 split ============================
__global__ __launch_bounds__(256) void conv_w_repack_kernel(
    const float* __restrict__ w3, u16* __restrict__ Wh, u16* __restrict__ Wl) {
  int idx = blockIdx.x * 256 + threadIdx.x;
  if (idx >= 9 * 128 * 128) return;
  int tap = idx >> 14;
  int r = idx & 16383;
  int co = r >> 7, ci = r & 127;
  u16 hi, lo;
  split_f16(w3[co * 1152 + ci * 9 + tap], hi, lo);
  Wh[idx] = hi; Wl[idx] = lo;
}

// ============================ implicit-GEMM MFMA 3x3 conv (f16x3 dual-acc) ============================
template <int H, int W>
__global__ __launch_bounds__(256) void conv_mfma_kernel(
    const u16* __restrict__ Fh, const u16* __restrict__ Fl,
    const u16* __restrict__ Wh, const u16* __restrict__ Wl,
    const float* __restrict__ b3, float* __restrict__ tbuf) {
  __shared__ u16 sAh[128][40], sAl[128][40], sBh[128][40], sBl[128][40];
  int tid = threadIdx.x;
  int m0 = blockIdx.x * 128;
  int w = tid >> 6, lane = tid & 63;
  int wm = (w >> 1) * 64, wn = (w & 1) * 64;
  int quad = lane >> 4, lrow = lane & 15;
  f32x4 acc1[4][4], acc2[4][4];
#pragma unroll
  for (int i = 0; i < 4; i++)
#pragma unroll
    for (int j = 0; j < 4; j++) { acc1[i][j] = (f32x4)0.f; acc2[i][j] = (f32x4)0.f; }

  for (int tap = 0; tap < 9; tap++) {
    int ky = tap / 3, kx = tap - (tap / 3) * 3;
    for (int c = 0; c < 4; c++) {
      for (int e = tid; e < 512; e += 256) {
        int row = e >> 2, seg = (e & 3) * 8;
        int m = m0 + row;
        int y = m / W, x = m - y * W;
        size_t pidx = ((size_t)(y + ky) * (W + 2) + x + kx) * 128 + c * 32 + seg;
        *(short8*)&sAh[row][seg] = *(const short8*)&Fh[pidx];
        *(short8*)&sAl[row][seg] = *(const short8*)&Fl[pidx];
        size_t bidx = ((size_t)tap * 128 + row) * 128 + c * 32 + seg;
        *(short8*)&sBh[row][seg] = *(const short8*)&Wh[bidx];
        *(short8*)&sBl[row][seg] = *(const short8*)&Wl[bidx];
      }
      __syncthreads();
      int kb = quad * 8;
      f16x8 afh[4], afl[4], bfh[4], bfl[4];
#pragma unroll
      for (int t = 0; t < 4; t++) {
        afh[t] = *(const f16x8*)&sAh[wm + t * 16 + lrow][kb];
        afl[t] = *(const f16x8*)&sAl[wm + t * 16 + lrow][kb];
        bfh[t] = *(const f16x8*)&sBh[wn + t * 16 + lrow][kb];
        bfl[t] = *(const f16x8*)&sBl[wn + t * 16 + lrow][kb];
      }
#pragma unroll
      for (int mt = 0; mt < 4; mt++)
#pragma unroll
        for (int nt = 0; nt < 4; nt++) {
          acc1[mt][nt] = __builtin_amdgcn_mfma_f32_16x16x32_f16(afh[mt], bfh[nt], acc1[mt][nt], 0, 0, 0);
          acc2[mt][nt] = __builtin_amdgcn_mfma_f32_16x16x32_f16(afh[mt], bfl[nt], acc2[mt][nt], 0, 0, 0);
          acc2[mt][nt] = __builtin_amdgcn_mfma_f32_16x16x32_f16(afl[mt], bfh[nt], acc2[mt][nt], 0, 0, 0);
        }
      __syncthreads();
    }
  }
#pragma unroll
  for (int nt = 0; nt < 4; nt++) {
    int col = wn + nt * 16 + lrow;
    float bias = b3[col];
#pragma unroll
    for (int mt = 0; mt < 4; mt++) {
#pragma unroll
      for (int reg = 0; reg < 4; reg++) {
        int row = m0 + wm + mt * 16 + quad * 4 + reg;
        float v = acc1[mt][nt][reg] + kISC * acc2[mt][nt][reg] + bias;
        tbuf[(size_t)row * 128 + col] = fmaxf(v, 0.f);
      }
    }
  }
}

// ============================ 1x1 heads from t (HWC fp32) ============================
__global__ __launch_bounds__(256) void head_1x1_kernel(
    const float* __restrict__ tbuf,
    const float* __restrict__ wc, const float* __restrict__ bcs,
    const float* __restrict__ wb, const float* __restrict__ bbx,
    unsigned* __restrict__ keys, float* __restrict__ deltas, int aoff, int HW) {
  __shared__ float wl[15][128];
  __shared__ float bl[15];
  for (int e = threadIdx.x; e < 15 * 128; e += 256) {
    int oc = e >> 7, k = e & 127;
    wl[oc][k] = (oc < 3) ? wc[oc * 128 + k] : wb[(oc - 3) * 128 + k];
  }
  if (threadIdx.x < 15)
    bl[threadIdx.x] = (threadIdx.x < 3) ? bcs[threadIdx.x] : bbx[threadIdx.x - 3];
  __syncthreads();
  int m = blockIdx.x * 256 + threadIdx.x;
  if (m >= HW) return;
  const float* trow = tbuf + (size_t)m * 128;
  float dot[15];
#pragma unroll
  for (int o = 0; o < 15; o++) dot[o] = 0.f;
  for (int k = 0; k < 128; k += 4) {
    float4 v = *(const float4*)&trow[k];
#pragma unroll
    for (int o = 0; o < 15; o++) {
      dot[o] = fmaf(wl[o][k], v.x, dot[o]);
      dot[o] = fmaf(wl[o][k + 1], v.y, dot[o]);
      dot[o] = fmaf(wl[o][k + 2], v.z, dot[o]);
      dot[o] = fmaf(wl[o][k + 3], v.w, dot[o]);
    }
  }
#pragma unroll
  for (int oc = 0; oc < 15; oc++) {
    float s = dot[oc] + bl[oc];
    if (oc < 3) {
      keys[aoff + m * 3 + oc] = keyOf(s);
    } else {
      int bc = oc - 3, a = bc >> 2, comp = bc & 3;
      deltas[(size_t)(aoff + m * 3 + a) * 4 + comp] = s;
    }
  }
}

// ============================ radix select per (image,level 0..2) ============================
__global__ __launch_bounds__(1024) void radix_select_kernel(
    const unsigned* __restrict__ keys, unsigned* __restrict__ tkT, unsigned* __restrict__ tkNeed) {
  int job = blockIdx.x;
  int b = job / 3, l = job - b * 3;
  const unsigned* kb = keys + (size_t)b * kAImg + c_AOFF[l];
  int n = c_ALVL[l];
  __shared__ unsigned hist[256];
  __shared__ unsigned s_sel, s_remk;
  unsigned prefix = 0, pmask = 0, remk = 2000;
  for (int shift = 24; shift >= 0; shift -= 8) {
    if (threadIdx.x < 256) hist[threadIdx.x] = 0;
    __syncthreads();
    for (int i = threadIdx.x; i < n; i += 1024) {
      unsigned key = kb[i];
      if ((key & pmask) == prefix) atomicAdd(&hist[(key >> shift) & 255u], 1u);
    }
    __syncthreads();
    if (threadIdx.x == 0) {
      unsigned cum = 0; int sel = 0;
      for (int d = 255; d >= 0; d--) {
        unsigned c = hist[d];
        if (cum + c >= remk) { sel = d; break; }
        cum += c;
      }
      s_sel = (unsigned)sel; s_remk = remk - cum;
    }
    __syncthreads();
    prefix |= (s_sel << shift);
    pmask |= (255u << shift);
    remk = s_remk;
    __syncthreads();
  }
  if (threadIdx.x == 0) { tkT[b * 4 + l] = prefix; tkNeed[b * 4 + l] = remk; }
}

// ============================ candidate build ============================
__global__ __launch_bounds__(1024) void cand_build_kernel(
    const unsigned* __restrict__ keys, const float* __restrict__ deltas,
    const unsigned* __restrict__ tkT, const unsigned* __restrict__ tkNeed,
    Cand* __restrict__ cand, AnchTab tab) {
  int b = blockIdx.x >> 2, l = blockIdx.x & 3;
  int n = c_ALVL[l];
  int W = c_LW[l];
  int stride = c_STRIDE[l];
  const unsigned* kb = keys + (size_t)b * kAImg + c_AOFF[l];
  const float* db = deltas + ((size_t)b * kAImg + c_AOFF[l]) * 4;
  Cand* cb = cand + (size_t)b * kNCand + c_CBASE[l];
  bool selAll = (l == 3);
  unsigned T = selAll ? 0u : tkT[b * 4 + l];
  unsigned need = selAll ? 0u : tkNeed[b * 4 + l];
  __shared__ unsigned wbuf[16];
  __shared__ unsigned s_runeq, s_runout;
  if (threadIdx.x == 0) { s_runeq = 0; s_runout = 0; }
  __syncthreads();
  for (int c0 = 0; c0 < n; c0 += 1024) {
    int i = c0 + (int)threadIdx.x;
    bool act = i < n;
    unsigned key = act ? kb[i] : 0u;
    bool isEq = (!selAll) && act && (key == T);
    unsigned eqTot;
    unsigned eqExc = block_scan_bool(isEq, wbuf, eqTot);
    unsigned runeq = s_runeq;
    unsigned runout = s_runout;
    bool isSel = act && (selAll || key > T || (isEq && (runeq + eqExc) < need));
    unsigned selTot;
    unsigned selExc = block_scan_bool(isSel, wbuf, selTot);
    if (isSel) {
      int slot = (int)(runout + selExc);
      int pos = i / 3, a = i - pos * 3;
      int yy = pos / W, xx = pos - yy * W;
      float sx = (float)(xx * stride), sy = (float)(yy * stride);
      float ax1 = tab.v[l][a][0] + sx;
      float ay1 = tab.v[l][a][1] + sy;
      float ax2 = tab.v[l][a][2] + sx;
      float ay2 = tab.v[l][a][3] + sy;
      float d0 = db[(size_t)i * 4 + 0], d1 = db[(size_t)i * 4 + 1];
      float d2 = db[(size_t)i * 4 + 2], d3 = db[(size_t)i * 4 + 3];
      float4 bx = decode_clip(ax1, ay1, ax2, ay2, d0, d1, d2, d3, 1.f, 1.f, 1.f, 1.f);
      bool ok = (bx.z - bx.x >= 0.001f) && (bx.w - bx.y >= 0.001f);
      Cand cd;
      cd.x1 = bx.x; cd.y1 = bx.y; cd.x2 = bx.z; cd.y2 = bx.w;
      cd.key = ok ? key : 0u; cd.lvl = (unsigned)l; cd.pad0 = 0; cd.pad1 = 0;
      cb[slot] = cd;
    }
    __syncthreads();
    if (threadIdx.x == 0) { s_runeq = runeq + eqTot; s_runout = runout + selTot; }
    __syncthreads();
  }
}

// ============================ single-block bitonic sort (desc key, asc slot) ============================
template <int NPAD>
__global__ __launch_bounds__(1024) void sort_desc_kernel(
    const unsigned* __restrict__ keyBase, int strideWords, int nFixed,
    const unsigned* __restrict__ nPtr, unsigned* __restrict__ sortedSlot,
    unsigned* __restrict__ validCnt, int imgStrideKeyWords, int imgStrideSlot) {
  __shared__ unsigned sk[NPAD];
  __shared__ unsigned short sslot[NPAD];
  __shared__ unsigned s_cnt;
  int b = blockIdx.x;
  const unsigned* kbase = keyBase + (size_t)b * imgStrideKeyWords;
  unsigned* oslot = sortedSlot + (size_t)b * imgStrideSlot;
  unsigned* ocnt = validCnt + b;
  int n = nFixed;
  if (nPtr) { int m = (int)nPtr[b]; n = n < m ? n : m; }
  for (int i = threadIdx.x; i < NPAD; i += 1024) {
    sk[i] = (i < n) ? kbase[(size_t)i * strideWords] : 0u;
    sslot[i] = (unsigned short)i;
  }
  if (threadIdx.x == 0) s_cnt = 0;
  __syncthreads();
  for (int k2 = 2; k2 <= NPAD; k2 <<= 1) {
    for (int j = k2 >> 1; j > 0; j >>= 1) {
      for (int i = threadIdx.x; i < NPAD; i += 1024) {
        int ixj = i ^ j;
        if (ixj > i) {
          unsigned ka = sk[i], kb2 = sk[ixj];
          unsigned short sa = sslot[i], sb = sslot[ixj];
          bool aGreater = (ka > kb2) || (ka == kb2 && sa < sb);
          bool up = ((i & k2) == 0);
          bool doSwap = up ? (!aGreater) : aGreater;
          if (doSwap) { sk[i] = kb2; sk[ixj] = ka; sslot[i] = sb; sslot[ixj] = sa; }
        }
      }
      __syncthreads();
    }
  }
  unsigned local = 0;
  for (int i = threadIdx.x; i < NPAD; i += 1024) {
    oslot[i] = (unsigned)sslot[i];
    if (sk[i] > 0u) local++;
  }
  atomicAdd(&s_cnt, local);
  __syncthreads();
  if (threadIdx.x == 0) *ocnt = s_cnt;
}

// ============================ sorted gather (RPN): raw boxes per sorted pos ============================
__global__ __launch_bounds__(256) void rpn_sort_gather(
    const Cand* __restrict__ cand, const unsigned* __restrict__ ss,
    const unsigned* __restrict__ validCnt, float4* __restrict__ boxRaw) {
  int b = blockIdx.y;
  int pos = blockIdx.x * 256 + threadIdx.x;
  int valid = (int)validCnt[b];
  float4 raw = make_float4(0.f, 0.f, 0.f, 0.f);
  if (pos < valid) {
    Cand c = cand[(size_t)b * kNCand + ss[(size_t)b * 8192 + pos]];
    raw = make_float4(c.x1, c.y1, c.x2, c.y2);
  }
  boxRaw[(size_t)b * 8192 + pos] = raw;
}

// ============================ per-level stable compaction (sorted order, offset boxes) ============================
__global__ __launch_bounds__(1024) void lvl_compact_kernel(
    const Cand* __restrict__ cand, const unsigned* __restrict__ ss,
    const unsigned* __restrict__ validCnt, float4* __restrict__ boxLvl,
    unsigned* __restrict__ lvlList, unsigned* __restrict__ lvlCnt) {
  int b = blockIdx.x;
  int valid = (int)validCnt[b];
  __shared__ unsigned wbuf[16];
  __shared__ unsigned s_run;
  for (int l = 0; l < 4; l++) {
    if (threadIdx.x == 0) s_run = 0;
    __syncthreads();
    for (int c0 = 0; c0 < 8192; c0 += 1024) {
      int pos = c0 + (int)threadIdx.x;
      bool act = pos < valid;
      unsigned lv = 99u;
      float4 off4 = make_float4(0.f, 0.f, 0.f, 0.f);
      if (act) {
#pragma clang fp contract(off)
        Cand c = cand[(size_t)b * kNCand + ss[(size_t)b * 8192 + pos]];
        lv = c.lvl;
        float off = 801.0f * (float)c.lvl;
        off4 = make_float4(c.x1 + off, c.y1 + off, c.x2 + off, c.y2 + off);
      }
      bool isl = act && (lv == (unsigned)l);
      unsigned tot;
      unsigned exc = block_scan_bool(isl, wbuf, tot);
      unsigned run = s_run;
      if (isl) {
        unsigned slot = run + exc;
        lvlList[((size_t)b * 4 + l) * 2048 + slot] = (unsigned)pos;
        boxLvl[((size_t)b * 4 + l) * 2048 + slot] = off4;
      }
      __syncthreads();
      if (threadIdx.x == 0) s_run = run + tot;
      __syncthreads();
    }
    if (threadIdx.x == 0) lvlCnt[b * 4 + l] = s_run;
    __syncthreads();
  }
}

// ============================ sorted gather (head): boxes + scores ============================
__global__ __launch_bounds__(256) void head_sort_gather(
    const HeadCand* __restrict__ hc, const unsigned* __restrict__ hsorted,
    const unsigned* __restrict__ hvalid, float4* __restrict__ hbox, float* __restrict__ hsc) {
  int pos = blockIdx.x * 256 + threadIdx.x;
  int valid = (int)*hvalid;
  float4 v = make_float4(0.f, 0.f, 0.f, 0.f);
  float s = 0.f;
  if (pos < valid) {
    HeadCand c = hc[hsorted[pos]];
    v = make_float4(c.x1, c.y1, c.x2, c.y2);
    s = c.score;
  }
  hbox[pos] = v;
  hsc[pos] = s;
}

// ============================ NMS suppression-mask build (rows) ============================
__global__ __launch_bounds__(64) void nms_mask_kernel(
    const float4* __restrict__ boxesOff, const unsigned* __restrict__ validCnt,
    unsigned long long* __restrict__ mask, int rowStrideWords,
    int imgBoxStride, long long imgMaskStride, float th) {
  int b = blockIdx.z;
  const float4* bx = boxesOff + (size_t)b * imgBoxStride;
  unsigned long long* mrow = mask + (size_t)b * imgMaskStride;
  int valid = (int)validCnt[b];
  int i = blockIdx.x * 64 + threadIdx.x;
  int j0 = blockIdx.y * 64;
  __shared__ float4 sb[64];
  sb[threadIdx.x] = bx[j0 + threadIdx.x];
  __syncthreads();
  float4 a = bx[i];
  unsigned long long bits = 0;
  for (int t = 0; t < 64; t++) {
    int j = j0 + t;
    if (j > i && j < valid && iou_pair(a, sb[t]) > th) bits |= (1ull << t);
  }
  mrow[(size_t)i * rowStrideWords + (j0 >> 6)] = bits;
}

// ============================ in-tile column masks (who suppresses me, i<j same tile) ============================
__global__ __launch_bounds__(64) void nms_col_kernel(
    const float4* __restrict__ boxes, const unsigned* __restrict__ validCnt,
    unsigned long long* __restrict__ colw, int jobBoxStride, int jobColStride, float th) {
  int job = blockIdx.y;
  int base = blockIdx.x * 64;
  const float4* bx = boxes + (size_t)job * jobBoxStride;
  int valid = (int)validCnt[job];
  int lane = threadIdx.x;
  __shared__ float4 sb[64];
  sb[lane] = bx[base + lane];
  __syncthreads();
  float4 a = sb[lane];
  unsigned long long bits = 0;
  if (base + lane < valid) {
    for (int t = 0; t < lane; t++) {
      if (iou_pair(sb[t], a) > th) bits |= (1ull << t);
    }
  }
  colw[(size_t)job * jobColStride + base + lane] = bits;
}

// ============================ ballot-frontier greedy NMS reduce ============================
// One wave per job, <=2048 candidates (32 tiles of 64). Per tile: confirmation-
// frontier iteration using only __ballot (exact greedy fixpoint), then a pure-
// register OR of kept rows (prefetched in pf) into the running removed mask.
template <int KMAX>
__global__ __launch_bounds__(64) void nms_reduce_frontier_kernel(
    const unsigned long long* __restrict__ mask,   // rows [job][2048][32]
    const unsigned long long* __restrict__ colw,   // cols [job][2048]
    const unsigned* __restrict__ validCnt,
    unsigned* __restrict__ keptIdx, unsigned* __restrict__ keptCnt,
    long long jobMaskStride, int jobColStride) {
  int job = blockIdx.x;
  const unsigned long long* mrow = mask + (size_t)job * jobMaskStride;
  const unsigned long long* mcol = colw + (size_t)job * jobColStride;
  int valid = (int)validCnt[job];
  unsigned* kout = keptIdx + (size_t)job * KMAX;
  int lane = threadIdx.x;
  int half = lane >> 5, w = lane & 31;
  unsigned long long removed = 0ull;   // lanes 0..31 hold removed word[lane]
  int keptTotal = 0;
  int ntiles = (valid + 63) >> 6;

  unsigned long long pf[32];
  unsigned long long colNext = 0ull;
  auto issue = [&](int k) {
    int base = k * 64;
#pragma unroll
    for (int i = 0; i < 32; i++) {
      int r = base + 2 * i + half;
      pf[i] = (r < valid) ? mrow[(size_t)r * 32 + w] : 0ull;
    }
    colNext = (base + lane < valid) ? mcol[base + lane] : 0ull;
  };
  if (ntiles > 0) issue(0);

  for (int k = 0; k < ntiles; k++) {
    int base = k * 64;
    int nt = valid - base; if (nt > 64) nt = 64;
    unsigned long long col = colNext;
    unsigned long long Wrm = shfl64(removed, k);   // removed word k (k<32)
    bool dead = (lane >= nt) || (((Wrm >> lane) & 1ull) != 0ull);
    bool kept = false;
    unsigned long long Kb = 0ull, Db = __ballot(dead);
    while (~(Kb | Db) != 0ull) {
      if (!kept && !dead) {
        if (col & Kb) dead = true;
        else if ((col & ~Db) == 0ull) kept = true;
      }
      Kb = __ballot(kept);
      Db = __ballot(dead);
    }
    int tk = __popcll(Kb);
    bool full = false;
    if (keptTotal + tk > KMAX) {
      int drop = keptTotal + tk - KMAX;
      unsigned long long kk = Kb;
      for (int d = 0; d < drop; d++) kk &= ~(1ull << (63 - __builtin_clzll(kk)));
      Kb = kk; tk = KMAX - keptTotal; full = true;
    }
    if (lane == 0) {
      unsigned long long km = Kb;
      int kc = keptTotal;
      while (km) { int t = __builtin_ctzll(km); km &= km - 1; kout[kc++] = (unsigned)(base + t); }
    }
    keptTotal += tk;
    if (full) break;
    // register-only OR of kept rows into removed
    unsigned long long acc = 0ull;
    unsigned long long kb = Kb >> half;
#pragma unroll
    for (int i = 0; i < 32; i++) {
      if ((kb >> (2 * i)) & 1ull) acc |= pf[i];
    }
    unsigned long long accOther = shfl64(acc, (lane + 32) & 63);
    if (lane < 32) removed |= acc | accOther;
    if (k + 1 < ntiles) issue(k + 1);
  }
  if (lane == 0) keptCnt[job] = (unsigned)keptTotal;
}

// ============================ scatter per-level kept -> global-pos flags ============================
__global__ __launch_bounds__(256) void flag_scatter_kernel(
    const unsigned* __restrict__ keptLoc, const unsigned* __restrict__ lvlKeptCnt,
    const unsigned* __restrict__ lvlList, unsigned char* __restrict__ kflag) {
  int job = blockIdx.y;
  int k = blockIdx.x * 256 + threadIdx.x;
  if (k >= (int)lvlKeptCnt[job]) return;
  unsigned local = keptLoc[(size_t)job * 2048 + k];
  unsigned pos = lvlList[(size_t)job * 2048 + local];
  int b = job >> 2;
  kflag[(size_t)b * 8192 + pos] = 1;
}

// ============================ merge kept flags: first 2000 in global sorted order ============================
__global__ __launch_bounds__(1024) void merge_kept_kernel(
    const unsigned char* __restrict__ kflag, const unsigned* __restrict__ validCnt,
    unsigned* __restrict__ keptIdx, unsigned* __restrict__ Mc) {
  int b = blockIdx.x;
  int valid = (int)validCnt[b];
  __shared__ unsigned wbuf[16];
  __shared__ unsigned s_run;
  if (threadIdx.x == 0) s_run = 0;
  __syncthreads();
  for (int c0 = 0; c0 < 8192; c0 += 1024) {
    int i = c0 + (int)threadIdx.x;
    bool k = (i < valid) && kflag[(size_t)b * 8192 + i];
    unsigned tot;
    unsigned exc = block_scan_bool(k, wbuf, tot);
    unsigned run = s_run;
    if (k) {
      unsigned slot = run + exc;
      if (slot < kPostNms) keptIdx[(size_t)b * kPostNms + slot] = (unsigned)i;
    }
    __syncthreads();
    if (threadIdx.x == 0) s_run = run + tot;
    __syncthreads();
  }
  if (threadIdx.x == 0) {
    unsigned r = s_run;
    Mc[b] = r < kPostNms ? r : kPostNms;
  }
}

// ============================ kept-index gathers ============================
__global__ __launch_bounds__(256) void rpn_roi_gather(
    const unsigned* __restrict__ keptIdx, const unsigned* __restrict__ Mc,
    const float4* __restrict__ boxRaw, float* __restrict__ rois) {
  int b = blockIdx.y;
  int k = blockIdx.x * 256 + threadIdx.x;
  if (k >= (int)Mc[b]) return;
  unsigned i = keptIdx[(size_t)b * kPostNms + k];
  float4 v = boxRaw[(size_t)b * 8192 + i];
  float* r = rois + ((size_t)b * kPostNms + k) * 4;
  r[0] = v.x; r[1] = v.y; r[2] = v.z; r[3] = v.w;
}

__global__ __launch_bounds__(128) void head_det_gather(
    const unsigned* __restrict__ keptIdx, const unsigned* __restrict__ cnt,
    const float4* __restrict__ hbox, const float* __restrict__ hsc,
    float* __restrict__ detBox, float* __restrict__ detSc) {
  int k = threadIdx.x;
  if (k >= (int)*cnt || k >= 100) return;
  unsigned i = keptIdx[k];
  float4 v = hbox[i];
  detBox[k * 4 + 0] = v.x; detBox[k * 4 + 1] = v.y;
  detBox[k * 4 + 2] = v.z; detBox[k * 4 + 3] = v.w;
  detSc[k] = hsc[i];
}

// ============================ ROI params ============================
__global__ __launch_bounds__(256) void roi_params_kernel(
    const float* __restrict__ rois, const unsigned* __restrict__ Mc, RoiParam* __restrict__ par) {
  int b = blockIdx.y;
  int i = blockIdx.x * 256 + threadIdx.x;
  if (i >= (int)Mc[b]) return;
  const float* r = rois + ((size_t)b * kPostNms + i) * 4;
  float x1 = r[0], y1 = r[1], x2 = r[2], y2 = r[3];
  float area = (x2 - x1) * (y2 - y1);
  float tgt = floorf(4.0f + log2f(sqrtf(fmaxf(area, 0.f)) / 224.0f + 1e-6f));
  tgt = fminf(fmaxf(tgt, 2.f), 5.f);
  int l = (int)tgt - 2;
  const float scales[4] = {0.25f, 0.125f, 0.0625f, 0.03125f};
  float sc = scales[l];
  RoiParam p;
  p.lvl = l;
  p.x1 = x1 * sc; p.y1 = y1 * sc;
  p.rw = fmaxf(x2 * sc - p.x1, 1.0f);
  p.rh = fmaxf(y2 * sc - p.y1, 1.0f);
  p.pad0 = p.pad1 = p.pad2 = 0;
  par[(size_t)b * kPostNms + i] = p;
}

// ============================ pooled pad (zero rows >= Mc) ============================
__global__ __launch_bounds__(256) void pad_pooled_kernel(
    u16* __restrict__ hi, u16* __restrict__ lo, const unsigned* __restrict__ Mc, int b) {
  int start = (int)Mc[b] * 6272;
  const int total = kMPad * 6272;
  for (int i = start + (int)(blockIdx.x * 256 + threadIdx.x); i < total; i += 512 * 256) {
    hi[i] = 0; lo[i] = 0;
  }
}

// ============================ multi-scale ROI align (writes split-f16) ============================
__global__ __launch_bounds__(256) void roi_align_kernel(
    const float* __restrict__ f0, const float* __restrict__ f1,
    const float* __restrict__ f2, const float* __restrict__ f3,
    const RoiParam* __restrict__ par, const unsigned* __restrict__ Mc,
    u16* __restrict__ pooledHi, u16* __restrict__ pooledLo, int b) {
  int idx = blockIdx.x * 256 + threadIdx.x;
  int roi = idx / 6272;
  if (roi >= (int)Mc[b]) return;
  int rem = idx - roi * 6272;
  int c = rem / 49, bin = rem - c * 49;
  int py = bin / 7, px = bin - py * 7;
  RoiParam p = par[roi];
  int H = c_LH[p.lvl], W = c_LW[p.lvl];
  const float* f = (p.lvl == 0 ? f0 : p.lvl == 1 ? f1 : p.lvl == 2 ? f2 : f3);
  f += ((size_t)b * 128 + c) * (size_t)(H * W);
  float Hf = (float)H, Wf = (float)W;
  float rh7 = p.rh / 7.0f, rw7 = p.rw / 7.0f;
  float sum = 0.f;
#pragma unroll
  for (int sy = 0; sy < 2; sy++) {
    float offy = (float)py + ((float)sy + 0.5f) * 0.5f;
    float Y = p.y1 + offy * rh7;
    float yc = fminf(fmaxf(Y, 0.f), Hf - 1.f);
    float y0f = floorf(yc);
    int y0 = (int)y0f;
    int y1 = min(y0 + 1, H - 1);
    float ly = yc - y0f, hy = 1.f - ly;
#pragma unroll
    for (int sx = 0; sx < 2; sx++) {
      float offx = (float)px + ((float)sx + 0.5f) * 0.5f;
      float X = p.x1 + offx * rw7;
      bool valid = (Y > -1.f) && (Y < Hf) && (X > -1.f) && (X < Wf);
      float xc = fminf(fmaxf(X, 0.f), Wf - 1.f);
      float x0f = floorf(xc);
      int x0 = (int)x0f;
      int x1i = min(x0 + 1, W - 1);
      float lx = xc - x0f, hx = 1.f - lx;
      float v = hy * hx * f[y0 * W + x0] + hy * lx * f[y0 * W + x1i] +
                ly * hx * f[y1 * W + x0] + ly * lx * f[y1 * W + x1i];
      sum += valid ? v : 0.f;
    }
  }
  float v = sum * 0.25f;
  u16 hi, lo;
  split_f16(v, hi, lo);
  pooledHi[idx] = hi;
  pooledLo[idx] = lo;
}

// ============================ weight split conversion ============================
__global__ __launch_bounds__(256) void convert_split_kernel(
    const float* __restrict__ src, u16* __restrict__ hi, u16* __restrict__ lo, int n) {
  for (int i = blockIdx.x * 256 + threadIdx.x; i < n; i += gridDim.x * 256) {
    u16 h, l;
    split_f16(src[i], h, l);
    hi[i] = h; lo[i] = l;
  }
}

// ============================ f16x3 dual-acc split-K MFMA GEMM ============================
__global__ __launch_bounds__(256) void gemm_f16x3_kernel(
    const u16* __restrict__ Ah, const u16* __restrict__ Al,
    const u16* __restrict__ Bh, const u16* __restrict__ Bl,
    float* __restrict__ Cpart, int K, int kChunks) {
  __shared__ u16 sAh[128][40], sAl[128][40], sBh[128][40], sBl[128][40];
  int tid = threadIdx.x;
  int m0 = blockIdx.y * 128, n0 = blockIdx.x * 128;
  int kBase = blockIdx.z * kChunks * 32;
  int w = tid >> 6, lane = tid & 63;
  int wm = (w >> 1) * 64, wn = (w & 1) * 64;
  int quad = lane >> 4, lrow = lane & 15;
  f32x4 acc1[4][4], acc2[4][4];
#pragma unroll
  for (int i = 0; i < 4; i++)
#pragma unroll
    for (int j = 0; j < 4; j++) { acc1[i][j] = (f32x4)0.f; acc2[i][j] = (f32x4)0.f; }

  for (int c = 0; c < kChunks; c++) {
    int k0 = kBase + c * 32;
    for (int e = tid; e < 512; e += 256) {
      int row = e >> 2, kk = (e & 3) * 8;
      size_t ga = (size_t)(m0 + row) * K + k0 + kk;
      size_t gb = (size_t)(n0 + row) * K + k0 + kk;
      *(short8*)&sAh[row][kk] = *(const short8*)&Ah[ga];
      *(short8*)&sAl[row][kk] = *(const short8*)&Al[ga];
      *(short8*)&sBh[row][kk] = *(const short8*)&Bh[gb];
      *(short8*)&sBl[row][kk] = *(const short8*)&Bl[gb];
    }
    __syncthreads();
    int kb = quad * 8;
    f16x8 afh[4], afl[4], bfh[4], bfl[4];
#pragma unroll
    for (int t = 0; t < 4; t++) {
      afh[t] = *(const f16x8*)&sAh[wm + t * 16 + lrow][kb];
      afl[t] = *(const f16x8*)&sAl[wm + t * 16 + lrow][kb];
      bfh[t] = *(const f16x8*)&sBh[wn + t * 16 + lrow][kb];
      bfl[t] = *(const f16x8*)&sBl[wn + t * 16 + lrow][kb];
    }
#pragma unroll
    for (int mt = 0; mt < 4; mt++)
#pragma unroll
      for (int nt = 0; nt < 4; nt++) {
        acc1[mt][nt] = __builtin_amdgcn_mfma_f32_16x16x32_f16(afh[mt], bfh[nt], acc1[mt][nt], 0, 0, 0);
        acc2[mt][nt] = __builtin_amdgcn_mfma_f32_16x16x32_f16(afh[mt], bfl[nt], acc2[mt][nt], 0, 0, 0);
        acc2[mt][nt] = __builtin_amdgcn_mfma_f32_16x16x32_f16(afl[mt], bfh[nt], acc2[mt][nt], 0, 0, 0);
      }
    __syncthreads();
  }
  float* out = Cpart + (size_t)blockIdx.z * (kMPad * 1024);
#pragma unroll
  for (int mt = 0; mt < 4; mt++)
#pragma unroll
    for (int nt = 0; nt < 4; nt++) {
      int col = n0 + wn + nt * 16 + lrow;
#pragma unroll
      for (int reg = 0; reg < 4; reg++) {
        int row = m0 + wm + mt * 16 + quad * 4 + reg;
        out[(size_t)row * 1024 + col] = acc1[mt][nt][reg] + kISC * acc2[mt][nt][reg];
      }
    }
}

// ============================ combine partials: bias+relu -> split-f16 ============================
__global__ __launch_bounds__(256) void combine_relu_split_kernel(
    const float* __restrict__ part, const float* __restrict__ bias,
    u16* __restrict__ hi, u16* __restrict__ lo) {
  int idx = blockIdx.x * 256 + threadIdx.x;
  int n = idx & 1023;
  float v = fmaxf(part[idx] + part[idx + kMPad * 1024] + bias[n], 0.f);
  u16 h, l;
  split_f16(v, h, l);
  hi[idx] = h; lo[idx] = l;
}

// ============================ combine partials: bias+relu -> f32 ============================
__global__ __launch_bounds__(256) void combine_relu_f32_kernel(
    const float* __restrict__ part, const float* __restrict__ bias,
    float* __restrict__ out) {
  int idx = blockIdx.x * 256 + threadIdx.x;
  int n = idx & 1023;
  out[idx] = fmaxf(part[idx] + part[idx + kMPad * 1024] + bias[n], 0.f);
}

// ============================ head linear (cls 2 + bbox 8 per roi) ============================
__global__ __launch_bounds__(64) void head_linear_kernel(
    const float* __restrict__ H2, const float* __restrict__ cw, const float* __restrict__ cb2,
    const float* __restrict__ bw, const float* __restrict__ bb2,
    const unsigned* __restrict__ Mc, float* __restrict__ out10) {
  int r = blockIdx.x;
  if (r >= (int)*Mc) return;
  __shared__ float x[1024];
  const float* h = H2 + (size_t)r * 1024;
  for (int i = threadIdx.x; i < 1024; i += 64) x[i] = h[i];
  __syncthreads();
  int t = threadIdx.x;
  if (t < 10) {
    const float* w = (t < 2) ? (cw + t * 1024) : (bw + (t - 2) * 1024);
    float bias = (t < 2) ? cb2[t] : bb2[t - 2];
    float dot = 0.f;
    for (int k = 0; k < 1024; k++) dot = fmaf(w[k], x[k], dot);
    out10[r * 10 + t] = dot + bias;
  }
}

// ============================ head decode ============================
__global__ __launch_bounds__(256) void head_decode_kernel(
    const float* __restrict__ out10, const float* __restrict__ rois,
    const unsigned* __restrict__ Mc, HeadCand* __restrict__ hc, int b) {
#pragma clang fp contract(off)
  int r = blockIdx.x * 256 + threadIdx.x;
  if (r >= (int)Mc[b]) return;
  const float* h = out10 + (size_t)r * 10;
  float l0 = h[0], l1 = h[1];
  float mx = fmaxf(l0, l1);
  float e0 = expf(l0 - mx), e1 = expf(l1 - mx);
  float sfg = e1 / (e0 + e1);
  const float* rr = rois + ((size_t)b * kPostNms + r) * 4;
  float4 bx = decode_clip(rr[0], rr[1], rr[2], rr[3], h[6], h[7], h[8], h[9],
                          10.f, 10.f, 5.f, 5.f);
  bool keep = (sfg > 0.05f) && (bx.z - bx.x >= 0.01f) && (bx.w - bx.y >= 0.01f);
  HeadCand c;
  c.x1 = bx.x; c.y1 = bx.y; c.x2 = bx.z; c.y2 = bx.w;
  c.score = sfg;
  c.key = keep ? keyOf(sfg) : 0u;
  c.pad0 = c.pad1 = 0;
  hc[r] = c;
}

// ============================ final output ============================
__global__ __launch_bounds__(256) void output_kernel(
    const float* __restrict__ detBox, const float* __restrict__ detSc,
    const unsigned* __restrict__ detCnt, float* __restrict__ out) {
  int t = threadIdx.x;
  if (t >= 200) return;
  int b = t / 100, q = t - b * 100;
  int cnt = (int)detCnt[b];
  float bx0 = 0.f, bx1 = 0.f, bx2 = 0.f, bx3 = 0.f, sc = 0.f, lb = 0.f;
  if (q < cnt) {
    const float* d = detBox + ((size_t)b * 100 + q) * 4;
    bx0 = d[0]; bx1 = d[1]; bx2 = d[2]; bx3 = d[3];
    sc = detSc[b * 100 + q];
    lb = 1.0f;
  }
  float* ob = out + ((size_t)b * 100 + q) * 4;
  ob[0] = bx0; ob[1] = bx1; ob[2] = bx2; ob[3] = bx3;
  out[800 + t] = sc;
  out[1000 + t] = lb;
}

// ============================ host launcher ============================
extern "C" void kernel_launch(void* const* d_in, const int* in_sizes, int n_in,
                              void* d_out, int out_size, void* d_ws, size_t ws_size,
                              hipStream_t stream) {
  (void)in_sizes; (void)n_in; (void)out_size; (void)ws_size;
  const float* feats[4] = {(const float*)d_in[0], (const float*)d_in[1],
                           (const float*)d_in[2], (const float*)d_in[3]};
  const float* w3 = (const float*)d_in[4];
  const float* b3 = (const float*)d_in[5];
  const float* wc = (const float*)d_in[6];
  const float* bcs = (const float*)d_in[7];
  const float* wb = (const float*)d_in[8];
  const float* bbx = (const float*)d_in[9];
  const float* fc6w = (const float*)d_in[10];
  const float* fc6b = (const float*)d_in[11];
  const float* fc7w = (const float*)d_in[12];
  const float* fc7b = (const float*)d_in[13];
  const float* clsw = (const float*)d_in[14];
  const float* clsb = (const float*)d_in[15];
  const float* bboxw = (const float*)d_in[16];
  const float* bboxb = (const float*)d_in[17];

  unsigned char* base = (unsigned char*)d_ws;
  size_t off = 0;
  auto alloc = [&](size_t bytes) -> void* {
    void* p = base + off;
    off += (bytes + 255) & ~(size_t)255;
    return p;
  };
  unsigned* keys = (unsigned*)alloc((size_t)2 * kAImg * 4);
  float* deltas = (float*)alloc((size_t)2 * kAImg * 16);
  unsigned* tkT = (unsigned*)alloc(32);
  unsigned* tkNeed = (unsigned*)alloc(32);
  Cand* cand = (Cand*)alloc((size_t)2 * kNCand * sizeof(Cand));
  unsigned* sortedSlot = (unsigned*)alloc((size_t)2 * 8192 * 4);
  unsigned* validCnt = (unsigned*)alloc(8);
  float4* boxRaw = (float4*)alloc((size_t)2 * 8192 * 16);
  float4* boxLvl = (float4*)alloc((size_t)8 * 2048 * 16);
  unsigned* lvlList = (unsigned*)alloc((size_t)8 * 2048 * 4);
  unsigned* lvlCnt = (unsigned*)alloc(32);
  unsigned long long* lvlMask = (unsigned long long*)alloc((size_t)8 * 2048 * 32 * 8);
  unsigned long long* lvlCol = (unsigned long long*)alloc((size_t)8 * 2048 * 8);
  unsigned* keptLoc = (unsigned*)alloc((size_t)8 * 2048 * 4);
  unsigned* lvlKeptCnt = (unsigned*)alloc(32);
  unsigned char* kflag = (unsigned char*)alloc((size_t)2 * 8192);
  unsigned* keptIdx = (unsigned*)alloc((size_t)2 * kPostNms * 4);
  float* rois = (float*)alloc((size_t)2 * kPostNms * 16);
  unsigned* Mc = (unsigned*)alloc(8);
  RoiParam* roiPar = (RoiParam*)alloc((size_t)2 * kPostNms * sizeof(RoiParam));
  // conv pipeline buffers (reused per image/level)
  u16* padHi = (u16*)alloc((size_t)204 * 202 * 128 * 2);
  u16* padLo = (u16*)alloc((size_t)204 * 202 * 128 * 2);
  u16* wTapHi = (u16*)alloc((size_t)9 * 128 * 128 * 2);
  u16* wTapLo = (u16*)alloc((size_t)9 * 128 * 128 * 2);
  float* tbuf = (float*)alloc((size_t)313 * 128 * 128 * 4);
  u16* pooledHi = (u16*)alloc((size_t)kMPad * 6272 * 2);
  u16* pooledLo = (u16*)alloc((size_t)kMPad * 6272 * 2);
  u16* fc6wHi = (u16*)alloc((size_t)1024 * 6272 * 2);
  u16* fc6wLo = (u16*)alloc((size_t)1024 * 6272 * 2);
  u16* fc7wHi = (u16*)alloc((size_t)1024 * 1024 * 2);
  u16* fc7wLo = (u16*)alloc((size_t)1024 * 1024 * 2);
  float* part = (float*)alloc((size_t)2 * kMPad * 1024 * 4);
  u16* H1hi = (u16*)alloc((size_t)kMPad * 1024 * 2);
  u16* H1lo = (u16*)alloc((size_t)kMPad * 1024 * 2);
  float* H2buf = (float*)alloc((size_t)kMPad * 1024 * 4);
  float* out10 = (float*)alloc((size_t)kPostNms * 10 * 4);
  HeadCand* hc = (HeadCand*)alloc((size_t)kPostNms * sizeof(HeadCand));
  unsigned* hsorted = (unsigned*)alloc((size_t)2048 * 4);
  unsigned* hvalid = (unsigned*)alloc(4);
  float4* hbox = (float4*)alloc((size_t)2048 * 16);
  float* hsc = (float*)alloc((size_t)2048 * 4);
  unsigned long long* hMask = (unsigned long long*)alloc((size_t)2048 * 32 * 8);
  unsigned long long* hCol = (unsigned long long*)alloc((size_t)2048 * 8);
  unsigned* hkept = (unsigned*)alloc((size_t)128 * 4);
  float* detBox = (float*)alloc((size_t)2 * 100 * 4 * 4);
  float* detSc = (float*)alloc((size_t)2 * 100 * 4);
  unsigned* detCnt = (unsigned*)alloc(8);

  // anchor base table, double precision, round-half-even (matches np.round)
  AnchTab tab;
  {
    const double aspects[3] = {0.5, 1.0, 2.0};
    const int sizes[4] = {32, 64, 128, 256};
    for (int l = 0; l < 4; l++)
      for (int a = 0; a < 3; a++) {
        double hr = sqrt(aspects[a]);
        double wr = 1.0 / hr;
        double wsz = wr * sizes[l], hsz = hr * sizes[l];
        tab.v[l][a][0] = (float)rint(-wsz / 2.0);
        tab.v[l][a][1] = (float)rint(-hsz / 2.0);
        tab.v[l][a][2] = (float)rint(wsz / 2.0);
        tab.v[l][a][3] = (float)rint(hsz / 2.0);
      }
  }

  const int LH[4] = {200, 100, 50, 25}, LW[4] = {200, 100, 50, 25};
  const int AOFF[4] = {0, 120000, 150000, 157500};

  // weight conversions (same work every call; graph-capture safe)
  convert_split_kernel<<<4096, 256, 0, stream>>>(fc6w, fc6wHi, fc6wLo, 1024 * 6272);
  convert_split_kernel<<<1024, 256, 0, stream>>>(fc7w, fc7wHi, fc7wLo, 1024 * 1024);
  conv_w_repack_kernel<<<(9 * 128 * 128 + 255) / 256, 256, 0, stream>>>(w3, wTapHi, wTapLo);

  // RPN conv pipeline (MFMA implicit GEMM) per image per level
  for (int b = 0; b < 2; b++) {
    for (int l = 0; l < 4; l++) {
      int H = LH[l], W = LW[l];
      int HW = H * W;
      int mtiles = (HW + 127) / 128;
      int n32 = (H + 4) * (W + 2) * 128 / 2;
      zero_u32_kernel<<<512, 256, 0, stream>>>((unsigned*)padHi, n32);
      zero_u32_kernel<<<512, 256, 0, stream>>>((unsigned*)padLo, n32);
      const float* fsrc = feats[l] + (size_t)b * 128 * HW;
      dim3 tgrid((W + 63) / 64, H);
      switch (l) {
        case 0:
          transpose_pad_kernel<200, 200><<<tgrid, 256, 0, stream>>>(fsrc, padHi, padLo);
          conv_mfma_kernel<200, 200><<<mtiles, 256, 0, stream>>>(padHi, padLo, wTapHi, wTapLo, b3, tbuf);
          break;
        case 1:
          transpose_pad_kernel<100, 100><<<tgrid, 256, 0, stream>>>(fsrc, padHi, padLo);
          conv_mfma_kernel<100, 100><<<mtiles, 256, 0, stream>>>(padHi, padLo, wTapHi, wTapLo, b3, tbuf);
          break;
        case 2:
          transpose_pad_kernel<50, 50><<<tgrid, 256, 0, stream>>>(fsrc, padHi, padLo);
          conv_mfma_kernel<50, 50><<<mtiles, 256, 0, stream>>>(padHi, padLo, wTapHi, wTapLo, b3, tbuf);
          break;
        default:
          transpose_pad_kernel<25, 25><<<tgrid, 256, 0, stream>>>(fsrc, padHi, padLo);
          conv_mfma_kernel<25, 25><<<mtiles, 256, 0, stream>>>(padHi, padLo, wTapHi, wTapLo, b3, tbuf);
          break;
      }
      head_1x1_kernel<<<(HW + 255) / 256, 256, 0, stream>>>(
          tbuf, wc, bcs, wb, bbx, keys + (size_t)b * kAImg,
          deltas + (size_t)b * kAImg * 4, AOFF[l], HW);
    }
  }

  radix_select_kernel<<<6, 1024, 0, stream>>>(keys, tkT, tkNeed);
  cand_build_kernel<<<8, 1024, 0, stream>>>(keys, deltas, tkT, tkNeed, cand, tab);
  sort_desc_kernel<8192><<<2, 1024, 0, stream>>>(
      ((const unsigned*)cand) + 4, 8, kNCand, nullptr, sortedSlot, validCnt, kNCand * 8, 8192);
  rpn_sort_gather<<<dim3(32, 2), 256, 0, stream>>>(cand, sortedSlot, validCnt, boxRaw);
  lvl_compact_kernel<<<2, 1024, 0, stream>>>(cand, sortedSlot, validCnt, boxLvl, lvlList, lvlCnt);
  // per-(image,level) masks: 8 jobs, 2048 boxes, 32 words/row + in-tile columns
  nms_mask_kernel<<<dim3(32, 32, 8), 64, 0, stream>>>(
      boxLvl, lvlCnt, lvlMask, 32, 2048, (long long)2048 * 32, 0.7f);
  nms_col_kernel<<<dim3(32, 8), 64, 0, stream>>>(
      boxLvl, lvlCnt, lvlCol, 2048, 2048, 0.7f);
  nms_reduce_frontier_kernel<2048><<<8, 64, 0, stream>>>(
      lvlMask, lvlCol, lvlCnt, keptLoc, lvlKeptCnt, (long long)2048 * 32, 2048);
  zero_u32_kernel<<<16, 256, 0, stream>>>((unsigned*)kflag, 4096);
  flag_scatter_kernel<<<dim3(8, 8), 256, 0, stream>>>(keptLoc, lvlKeptCnt, lvlList, kflag);
  merge_kept_kernel<<<2, 1024, 0, stream>>>(kflag, validCnt, keptIdx, Mc);
  rpn_roi_gather<<<dim3(8, 2), 256, 0, stream>>>(keptIdx, Mc, boxRaw, rois);
  roi_params_kernel<<<dim3(8, 2), 256, 0, stream>>>(rois, Mc, roiPar);

  for (int b = 0; b < 2; b++) {
    pad_pooled_kernel<<<512, 256, 0, stream>>>(pooledHi, pooledLo, Mc, b);
    roi_align_kernel<<<49000, 256, 0, stream>>>(
        feats[0], feats[1], feats[2], feats[3], roiPar + (size_t)b * kPostNms, Mc,
        pooledHi, pooledLo, b);
    // fc6: M=2048, N=1024, K=6272 (split 2 x 98 chunks of 32)
    gemm_f16x3_kernel<<<dim3(8, 16, 2), 256, 0, stream>>>(
        pooledHi, pooledLo, fc6wHi, fc6wLo, part, 6272, 98);
    combine_relu_split_kernel<<<8192, 256, 0, stream>>>(part, fc6b, H1hi, H1lo);
    // fc7: M=2048, N=1024, K=1024 (split 2 x 16 chunks of 32)
    gemm_f16x3_kernel<<<dim3(8, 16, 2), 256, 0, stream>>>(
        H1hi, H1lo, fc7wHi, fc7wLo, part, 1024, 16);
    combine_relu_f32_kernel<<<8192, 256, 0, stream>>>(part, fc7b, H2buf);
    head_linear_kernel<<<2000, 64, 0, stream>>>(H2buf, clsw, clsb, bboxw, bboxb, Mc + b, out10);
    head_decode_kernel<<<8, 256, 0, stream>>>(out10, rois, Mc, hc, b);
    sort_desc_kernel<2048><<<1, 1024, 0, stream>>>(
        ((const unsigned*)hc) + 5, 8, 2000, Mc + b, hsorted, hvalid, 0, 0);
    head_sort_gather<<<8, 256, 0, stream>>>(hc, hsorted, hvalid, hbox, hsc);
    nms_mask_kernel<<<dim3(32, 32, 1), 64, 0, stream>>>(
        hbox, hvalid, hMask, 32, 0, 0, 0.5f);
    nms_col_kernel<<<dim3(32, 1), 64, 0, stream>>>(
        hbox, hvalid, hCol, 0, 0, 0.5f);
    nms_reduce_frontier_kernel<100><<<1, 64, 0, stream>>>(
        hMask, hCol, hvalid, hkept, detCnt + b, (long long)2048 * 32, 0);
    head_det_gather<<<1, 128, 0, stream>>>(
        hkept, detCnt + b, hbox, hsc, detBox + (size_t)b * 400, detSc + (size_t)b * 100);
  }
  output_kernel<<<1, 256, 0, stream>>>(detBox, detSc, detCnt, (float*)d_out);
}

// Round 9
// 2360.053 us; speedup vs baseline: 1.2330x; 1.0929x over previous
//
#include <hip/hip_runtime.h>
#include <cmath>

// ============================ constants ============================
static constexpr int kAImg = 159375;   // anchors per image
static constexpr int kNCand = 7875;    // 2000+2000+2000+1875
static constexpr int kPostNms = 2000;
static constexpr int kMPad = 2048;     // padded roi count for MFMA GEMM
static constexpr float kISC = 1.0f / 4096.0f;

__constant__ int c_AOFF[4]   = {0, 120000, 150000, 157500};
__constant__ int c_ALVL[4]   = {120000, 30000, 7500, 1875};
__constant__ int c_CBASE[4]  = {0, 2000, 4000, 6000};
__constant__ int c_LW[4]     = {200, 100, 50, 25};
__constant__ int c_LH[4]     = {200, 100, 50, 25};
__constant__ int c_STRIDE[4] = {4, 8, 16, 32};
// chunk bases per job (1024-elem chunks): lvl chunks {118,30,8,2}, 158/image
__constant__ int c_JCHUNK[9] = {0, 118, 148, 156, 158, 276, 306, 314, 316};

struct Cand     { float x1, y1, x2, y2; unsigned key; unsigned lvl; unsigned pad0, pad1; };
struct HeadCand { float x1, y1, x2, y2; float score; unsigned key; unsigned pad0, pad1; };
struct RoiParam { int lvl; float x1, y1, rw, rh; int pad0, pad1, pad2; };
struct AnchTab  { float v[4][3][4]; };

typedef unsigned short u16;
typedef __attribute__((ext_vector_type(8))) short short8;
typedef __attribute__((ext_vector_type(4))) float f32x4;
typedef _Float16 f16x8 __attribute__((ext_vector_type(8)));

// ============================ device helpers ============================
__device__ __forceinline__ unsigned keyOf(float f) {
  unsigned u = __float_as_uint(f);
  return (u & 0x80000000u) ? ~u : (u | 0x80000000u);
}

// fp32 -> (f16 hi, f16 lo*4096). value = hi + lo/4096, err ~ 2^-24 relative.
__device__ __forceinline__ void split_f16(float f, u16& hi, u16& lo) {
  union { _Float16 h; u16 u; } a, b;
  a.h = (_Float16)f;
  float r = (f - (float)a.h) * 4096.0f;
  b.h = (_Float16)r;
  hi = a.u; lo = b.u;
}

__device__ __forceinline__ unsigned long long shfl64(unsigned long long v, int src) {
  int lo = __shfl((int)(unsigned)(v & 0xffffffffull), src);
  int hi = __shfl((int)(unsigned)(v >> 32), src);
  return ((unsigned long long)(unsigned)hi << 32) | (unsigned)lo;
}

__device__ __forceinline__ float iou_pair(float4 a, float4 b) {
#pragma clang fp contract(off)
  float ix1 = fmaxf(a.x, b.x), iy1 = fmaxf(a.y, b.y);
  float ix2 = fminf(a.z, b.z), iy2 = fminf(a.w, b.w);
  float iw = fmaxf(ix2 - ix1, 0.f), ih = fmaxf(iy2 - iy1, 0.f);
  float inter = iw * ih;
  float a1 = (a.z - a.x) * (a.w - a.y);
  float a2 = (b.z - b.x) * (b.w - b.y);
  float uni = a1 + a2 - inter;
  return uni > 0.f ? inter / uni : 0.f;
}

__device__ __forceinline__ float4 decode_clip(float bx1, float by1, float bx2, float by2,
                                              float d0, float d1, float d2, float d3,
                                              float wx, float wy, float ww, float wh) {
#pragma clang fp contract(off)
  float w = bx2 - bx1, h = by2 - by1;
  float cx = bx1 + 0.5f * w, cy = by1 + 0.5f * h;
  float dx = d0 / wx, dy = d1 / wy;
  float dw = fminf(d2 / ww, 4.135166556742356f);
  float dh = fminf(d3 / wh, 4.135166556742356f);
  float pcx = dx * w + cx, pcy = dy * h + cy;
  float pw = expf(dw) * w, ph = expf(dh) * h;
  float x1 = pcx - 0.5f * pw, y1 = pcy - 0.5f * ph;
  float x2 = pcx + 0.5f * pw, y2 = pcy + 0.5f * ph;
  x1 = fminf(fmaxf(x1, 0.f), 800.f); y1 = fminf(fmaxf(y1, 0.f), 800.f);
  x2 = fminf(fmaxf(x2, 0.f), 800.f); y2 = fminf(fmaxf(y2, 0.f), 800.f);
  return make_float4(x1, y1, x2, y2);
}

// block-wide exclusive scan of a bool over 1024 threads (16 waves)
__device__ __forceinline__ unsigned block_scan_bool(bool p, unsigned* wbuf, unsigned& total) {
  unsigned long long m = __ballot(p);
  int lane = threadIdx.x & 63;
  int wid = threadIdx.x >> 6;
  unsigned exc = (unsigned)__popcll(m & ((lane == 0) ? 0ull : ((~0ull) >> (64 - lane))));
  if (lane == 0) wbuf[wid] = (unsigned)__popcll(m);
  __syncthreads();
  unsigned pre = 0, tot = 0;
#pragma unroll
  for (int w = 0; w < 16; w++) { unsigned c = wbuf[w]; if (w < wid) pre += c; tot += c; }
  total = tot;
  __syncthreads();
  return pre + exc;
}

// ============================ zero fill ============================
__global__ __launch_bounds__(256) void zero_u32_kernel(unsigned* __restrict__ p, int n32) {
  for (int i = blockIdx.x * 256 + threadIdx.x; i < n32; i += gridDim.x * 256) p[i] = 0u;
}

// ============================ NCHW -> padded HWC f16-split transpose ============================
template <int H, int W>
__global__ __launch_bounds__(256) void transpose_pad_kernel(
    const float* __restrict__ feat, u16* __restrict__ Fh, u16* __restrict__ Fl) {
  __shared__ float tile[128][65];
  int y = blockIdx.y;
  int x0 = blockIdx.x * 64;
  for (int e = threadIdx.x; e < 128 * 64; e += 256) {
    int ci = e >> 6, x = e & 63;
    float v = 0.f;
    if (x0 + x < W) v = feat[(size_t)ci * (H * W) + y * W + x0 + x];
    tile[ci][x] = v;
  }
  __syncthreads();
  for (int e = threadIdx.x; e < 64 * 128; e += 256) {
    int x = e >> 7, ci = e & 127;
    if (x0 + x >= W) continue;
    u16 hi, lo;
    split_f16(tile[ci][x], hi, lo);
    size_t out = ((size_t)(y + 1) * (W + 2) + (x0 + x + 1)) * 128 + ci;
    Fh[out] = hi; Fl[out] = lo;
  }
}

// ============================ conv weight repack ============================
__global__ __launch_bounds__(256) void conv_w_repack_kernel(
    const float* __restrict__ w3, u16* __restrict__ Wh, u16* __restrict__ Wl) {
  int idx = blockIdx.x * 256 + threadIdx.x;
  if (idx >= 9 * 128 * 128) return;
  int tap = idx >> 14;
  int r = idx & 16383;
  int co = r >> 7, ci = r & 127;
  u16 hi, lo;
  split_f16(w3[co * 1152 + ci * 9 + tap], hi, lo);
  Wh[idx] = hi; Wl[idx] = lo;
}

// ============================ implicit-GEMM MFMA 3x3 conv (f16x3 dual-acc) ============================
template <int H, int W>
__global__ __launch_bounds__(256) void conv_mfma_kernel(
    const u16* __restrict__ Fh, const u16* __restrict__ Fl,
    const u16* __restrict__ Wh, const u16* __restrict__ Wl,
    const float* __restrict__ b3, float* __restrict__ tbuf) {
  __shared__ u16 sAh[128][40], sAl[128][40], sBh[128][40], sBl[128][40];
  int tid = threadIdx.x;
  int m0 = blockIdx.x * 128;
  int w = tid >> 6, lane = tid & 63;
  int wm = (w >> 1) * 64, wn = (w & 1) * 64;
  int quad = lane >> 4, lrow = lane & 15;
  f32x4 acc1[4][4], acc2[4][4];
#pragma unroll
  for (int i = 0; i < 4; i++)
#pragma unroll
    for (int j = 0; j < 4; j++) { acc1[i][j] = (f32x4)0.f; acc2[i][j] = (f32x4)0.f; }

  for (int tap = 0; tap < 9; tap++) {
    int ky = tap / 3, kx = tap - (tap / 3) * 3;
    for (int c = 0; c < 4; c++) {
      for (int e = tid; e < 512; e += 256) {
        int row = e >> 2, seg = (e & 3) * 8;
        int m = m0 + row;
        int y = m / W, x = m - y * W;
        size_t pidx = ((size_t)(y + ky) * (W + 2) + x + kx) * 128 + c * 32 + seg;
        *(short8*)&sAh[row][seg] = *(const short8*)&Fh[pidx];
        *(short8*)&sAl[row][seg] = *(const short8*)&Fl[pidx];
        size_t bidx = ((size_t)tap * 128 + row) * 128 + c * 32 + seg;
        *(short8*)&sBh[row][seg] = *(const short8*)&Wh[bidx];
        *(short8*)&sBl[row][seg] = *(const short8*)&Wl[bidx];
      }
      __syncthreads();
      int kb = quad * 8;
      f16x8 afh[4], afl[4], bfh[4], bfl[4];
#pragma unroll
      for (int t = 0; t < 4; t++) {
        afh[t] = *(const f16x8*)&sAh[wm + t * 16 + lrow][kb];
        afl[t] = *(const f16x8*)&sAl[wm + t * 16 + lrow][kb];
        bfh[t] = *(const f16x8*)&sBh[wn + t * 16 + lrow][kb];
        bfl[t] = *(const f16x8*)&sBl[wn + t * 16 + lrow][kb];
      }
#pragma unroll
      for (int mt = 0; mt < 4; mt++)
#pragma unroll
        for (int nt = 0; nt < 4; nt++) {
          acc1[mt][nt] = __builtin_amdgcn_mfma_f32_16x16x32_f16(afh[mt], bfh[nt], acc1[mt][nt], 0, 0, 0);
          acc2[mt][nt] = __builtin_amdgcn_mfma_f32_16x16x32_f16(afh[mt], bfl[nt], acc2[mt][nt], 0, 0, 0);
          acc2[mt][nt] = __builtin_amdgcn_mfma_f32_16x16x32_f16(afl[mt], bfh[nt], acc2[mt][nt], 0, 0, 0);
        }
      __syncthreads();
    }
  }
#pragma unroll
  for (int nt = 0; nt < 4; nt++) {
    int col = wn + nt * 16 + lrow;
    float bias = b3[col];
#pragma unroll
    for (int mt = 0; mt < 4; mt++) {
#pragma unroll
      for (int reg = 0; reg < 4; reg++) {
        int row = m0 + wm + mt * 16 + quad * 4 + reg;
        float v = acc1[mt][nt][reg] + kISC * acc2[mt][nt][reg] + bias;
        tbuf[(size_t)row * 128 + col] = fmaxf(v, 0.f);
      }
    }
  }
}

// ============================ 1x1 heads from t (HWC fp32) ============================
__global__ __launch_bounds__(256) void head_1x1_kernel(
    const float* __restrict__ tbuf,
    const float* __restrict__ wc, const float* __restrict__ bcs,
    const float* __restrict__ wb, const float* __restrict__ bbx,
    unsigned* __restrict__ keys, float* __restrict__ deltas, int aoff, int HW) {
  __shared__ float wl[15][128];
  __shared__ float bl[15];
  for (int e = threadIdx.x; e < 15 * 128; e += 256) {
    int oc = e >> 7, k = e & 127;
    wl[oc][k] = (oc < 3) ? wc[oc * 128 + k] : wb[(oc - 3) * 128 + k];
  }
  if (threadIdx.x < 15)
    bl[threadIdx.x] = (threadIdx.x < 3) ? bcs[threadIdx.x] : bbx[threadIdx.x - 3];
  __syncthreads();
  int m = blockIdx.x * 256 + threadIdx.x;
  if (m >= HW) return;
  const float* trow = tbuf + (size_t)m * 128;
  float dot[15];
#pragma unroll
  for (int o = 0; o < 15; o++) dot[o] = 0.f;
  for (int k = 0; k < 128; k += 4) {
    float4 v = *(const float4*)&trow[k];
#pragma unroll
    for (int o = 0; o < 15; o++) {
      dot[o] = fmaf(wl[o][k], v.x, dot[o]);
      dot[o] = fmaf(wl[o][k + 1], v.y, dot[o]);
      dot[o] = fmaf(wl[o][k + 2], v.z, dot[o]);
      dot[o] = fmaf(wl[o][k + 3], v.w, dot[o]);
    }
  }
#pragma unroll
  for (int oc = 0; oc < 15; oc++) {
    float s = dot[oc] + bl[oc];
    if (oc < 3) {
      keys[aoff + m * 3 + oc] = keyOf(s);
    } else {
      int bc = oc - 3, a = bc >> 2, comp = bc & 3;
      deltas[(size_t)(aoff + m * 3 + a) * 4 + comp] = s;
    }
  }
}

// ============================ radix select per (image,level 0..2) ============================
__global__ __launch_bounds__(1024) void radix_select_kernel(
    const unsigned* __restrict__ keys, unsigned* __restrict__ tkT, unsigned* __restrict__ tkNeed) {
  int job = blockIdx.x;
  int b = job / 3, l = job - b * 3;
  const unsigned* kb = keys + (size_t)b * kAImg + c_AOFF[l];
  int n = c_ALVL[l];
  __shared__ unsigned hist[256];
  __shared__ unsigned s_sel, s_remk;
  unsigned prefix = 0, pmask = 0, remk = 2000;
  for (int shift = 24; shift >= 0; shift -= 8) {
    if (threadIdx.x < 256) hist[threadIdx.x] = 0;
    __syncthreads();
    for (int i = threadIdx.x; i < n; i += 1024) {
      unsigned key = kb[i];
      if ((key & pmask) == prefix) atomicAdd(&hist[(key >> shift) & 255u], 1u);
    }
    __syncthreads();
    if (threadIdx.x == 0) {
      unsigned cum = 0; int sel = 0;
      for (int d = 255; d >= 0; d--) {
        unsigned c = hist[d];
        if (cum + c >= remk) { sel = d; break; }
        cum += c;
      }
      s_sel = (unsigned)sel; s_remk = remk - cum;
    }
    __syncthreads();
    prefix |= (s_sel << shift);
    pmask |= (255u << shift);
    remk = s_remk;
    __syncthreads();
  }
  if (threadIdx.x == 0) { tkT[b * 4 + l] = prefix; tkNeed[b * 4 + l] = remk; }
}

// ============================ cand pass A: per-chunk gt/eq counts ============================
__global__ __launch_bounds__(1024) void cand_count_kernel(
    const unsigned* __restrict__ keys, const unsigned* __restrict__ tkT,
    unsigned* __restrict__ gtCnt, unsigned* __restrict__ eqCnt) {
  __shared__ unsigned wg[16], we[16];
  int cb = blockIdx.x;
  int j = 0;
#pragma unroll
  for (int t = 1; t < 8; t++) if (cb >= c_JCHUNK[t]) j = t;
  int chunk = cb - c_JCHUNK[j];
  int b = j >> 2, l = j & 3;
  int n = c_ALVL[l];
  int i = chunk * 1024 + (int)threadIdx.x;
  bool act = i < n;
  unsigned key = act ? keys[(size_t)b * kAImg + c_AOFF[l] + i] : 0u;
  unsigned T = (l == 3) ? 0u : tkT[b * 4 + l];
  bool gt = act && (l != 3) && (key > T);
  bool eq = act && (l != 3) && (key == T);
  unsigned long long mg = __ballot(gt), me = __ballot(eq);
  int lane = threadIdx.x & 63, wid = threadIdx.x >> 6;
  if (lane == 0) { wg[wid] = (unsigned)__popcll(mg); we[wid] = (unsigned)__popcll(me); }
  __syncthreads();
  if (threadIdx.x == 0) {
    unsigned g = 0, e = 0;
#pragma unroll
    for (int t = 0; t < 16; t++) { g += wg[t]; e += we[t]; }
    gtCnt[cb] = g; eqCnt[cb] = e;
  }
}

// ============================ cand pass B: per-job exclusive prefix over chunks ============================
__global__ __launch_bounds__(512) void cand_prefix_kernel(
    unsigned* __restrict__ gtCnt, unsigned* __restrict__ eqCnt,
    unsigned* __restrict__ gtBase, unsigned* __restrict__ eqBase) {
  int j = threadIdx.x >> 6;
  int lane = threadIdx.x & 63;
  if (lane != 0) return;
  int c0 = c_JCHUNK[j], c1 = c_JCHUNK[j + 1];
  unsigned g = 0, e = 0;
  for (int c = c0; c < c1; c++) {
    gtBase[c] = g; eqBase[c] = e;
    g += gtCnt[c]; e += eqCnt[c];
  }
}

// ============================ cand pass C: parallel stable scatter + decode ============================
__global__ __launch_bounds__(1024) void cand_scatter_kernel(
    const unsigned* __restrict__ keys, const float* __restrict__ deltas,
    const unsigned* __restrict__ tkT, const unsigned* __restrict__ tkNeed,
    const unsigned* __restrict__ gtBase, const unsigned* __restrict__ eqBase,
    Cand* __restrict__ cand, AnchTab tab) {
  __shared__ unsigned wbuf[16];
  int cb = blockIdx.x;
  int j = 0;
#pragma unroll
  for (int t = 1; t < 8; t++) if (cb >= c_JCHUNK[t]) j = t;
  int chunk = cb - c_JCHUNK[j];
  int b = j >> 2, l = j & 3;
  int n = c_ALVL[l];
  int W = c_LW[l];
  int stride = c_STRIDE[l];
  const float* db = deltas + ((size_t)b * kAImg + c_AOFF[l]) * 4;
  Cand* cbuf = cand + (size_t)b * kNCand + c_CBASE[l];
  bool selAll = (l == 3);
  unsigned T = selAll ? 0u : tkT[b * 4 + l];
  unsigned need = selAll ? 0u : tkNeed[b * 4 + l];
  int i = chunk * 1024 + (int)threadIdx.x;
  bool act = i < n;
  unsigned key = act ? keys[(size_t)b * kAImg + c_AOFF[l] + i] : 0u;
  bool gt = act && !selAll && (key > T);
  bool eq = act && !selAll && (key == T);
  unsigned tmp;
  unsigned gtExc = block_scan_bool(gt, wbuf, tmp);
  unsigned eqExc = block_scan_bool(eq, wbuf, tmp);
  unsigned gtCount = gtBase[cb] + gtExc;
  unsigned eqCount = eqBase[cb] + eqExc;
  bool isSel = act && (selAll || gt || (eq && eqCount < need));
  if (!isSel) return;
  int slot = selAll ? i : (int)(gtCount + (eqCount < need ? eqCount : need));
  int pos = i / 3, a = i - pos * 3;
  int yy = pos / W, xx = pos - yy * W;
  float sx = (float)(xx * stride), sy = (float)(yy * stride);
  float ax1 = tab.v[l][a][0] + sx;
  float ay1 = tab.v[l][a][1] + sy;
  float ax2 = tab.v[l][a][2] + sx;
  float ay2 = tab.v[l][a][3] + sy;
  float d0 = db[(size_t)i * 4 + 0], d1 = db[(size_t)i * 4 + 1];
  float d2 = db[(size_t)i * 4 + 2], d3 = db[(size_t)i * 4 + 3];
  float4 bx = decode_clip(ax1, ay1, ax2, ay2, d0, d1, d2, d3, 1.f, 1.f, 1.f, 1.f);
  bool ok = (bx.z - bx.x >= 0.001f) && (bx.w - bx.y >= 0.001f);
  Cand cd;
  cd.x1 = bx.x; cd.y1 = bx.y; cd.x2 = bx.z; cd.y2 = bx.w;
  cd.key = ok ? key : 0u; cd.lvl = (unsigned)l; cd.pad0 = 0; cd.pad1 = 0;
  cbuf[slot] = cd;
}

// ============================ single-block bitonic sort (desc key, asc slot) ============================
template <int NPAD>
__global__ __launch_bounds__(1024) void sort_desc_kernel(
    const unsigned* __restrict__ keyBase, int strideWords, int nFixed,
    const unsigned* __restrict__ nPtr, unsigned* __restrict__ sortedSlot,
    unsigned* __restrict__ validCnt, int imgStrideKeyWords, int imgStrideSlot) {
  __shared__ unsigned sk[NPAD];
  __shared__ unsigned short sslot[NPAD];
  __shared__ unsigned s_cnt;
  int b = blockIdx.x;
  const unsigned* kbase = keyBase + (size_t)b * imgStrideKeyWords;
  unsigned* oslot = sortedSlot + (size_t)b * imgStrideSlot;
  unsigned* ocnt = validCnt + b;
  int n = nFixed;
  if (nPtr) { int m = (int)nPtr[b]; n = n < m ? n : m; }
  for (int i = threadIdx.x; i < NPAD; i += 1024) {
    sk[i] = (i < n) ? kbase[(size_t)i * strideWords] : 0u;
    sslot[i] = (unsigned short)i;
  }
  if (threadIdx.x == 0) s_cnt = 0;
  __syncthreads();
  for (int k2 = 2; k2 <= NPAD; k2 <<= 1) {
    for (int j = k2 >> 1; j > 0; j >>= 1) {
      for (int i = threadIdx.x; i < NPAD; i += 1024) {
        int ixj = i ^ j;
        if (ixj > i) {
          unsigned ka = sk[i], kb2 = sk[ixj];
          unsigned short sa = sslot[i], sb = sslot[ixj];
          bool aGreater = (ka > kb2) || (ka == kb2 && sa < sb);
          bool up = ((i & k2) == 0);
          bool doSwap = up ? (!aGreater) : aGreater;
          if (doSwap) { sk[i] = kb2; sk[ixj] = ka; sslot[i] = sb; sslot[ixj] = sa; }
        }
      }
      __syncthreads();
    }
  }
  unsigned local = 0;
  for (int i = threadIdx.x; i < NPAD; i += 1024) {
    oslot[i] = (unsigned)sslot[i];
    if (sk[i] > 0u) local++;
  }
  atomicAdd(&s_cnt, local);
  __syncthreads();
  if (threadIdx.x == 0) *ocnt = s_cnt;
}

// ============================ sorted gather (RPN): raw boxes per sorted pos ============================
__global__ __launch_bounds__(256) void rpn_sort_gather(
    const Cand* __restrict__ cand, const unsigned* __restrict__ ss,
    const unsigned* __restrict__ validCnt, float4* __restrict__ boxRaw) {
  int b = blockIdx.y;
  int pos = blockIdx.x * 256 + threadIdx.x;
  int valid = (int)validCnt[b];
  float4 raw = make_float4(0.f, 0.f, 0.f, 0.f);
  if (pos < valid) {
    Cand c = cand[(size_t)b * kNCand + ss[(size_t)b * 8192 + pos]];
    raw = make_float4(c.x1, c.y1, c.x2, c.y2);
  }
  boxRaw[(size_t)b * 8192 + pos] = raw;
}

// ============================ per-level stable compaction (sorted order, offset boxes) ============================
__global__ __launch_bounds__(1024) void lvl_compact_kernel(
    const Cand* __restrict__ cand, const unsigned* __restrict__ ss,
    const unsigned* __restrict__ validCnt, float4* __restrict__ boxLvl,
    unsigned* __restrict__ lvlList, unsigned* __restrict__ lvlCnt) {
  int b = blockIdx.x;
  int valid = (int)validCnt[b];
  __shared__ unsigned wbuf[16];
  __shared__ unsigned s_run;
  for (int l = 0; l < 4; l++) {
    if (threadIdx.x == 0) s_run = 0;
    __syncthreads();
    for (int c0 = 0; c0 < 8192; c0 += 1024) {
      int pos = c0 + (int)threadIdx.x;
      bool act = pos < valid;
      unsigned lv = 99u;
      float4 off4 = make_float4(0.f, 0.f, 0.f, 0.f);
      if (act) {
#pragma clang fp contract(off)
        Cand c = cand[(size_t)b * kNCand + ss[(size_t)b * 8192 + pos]];
        lv = c.lvl;
        float off = 801.0f * (float)c.lvl;
        off4 = make_float4(c.x1 + off, c.y1 + off, c.x2 + off, c.y2 + off);
      }
      bool isl = act && (lv == (unsigned)l);
      unsigned tot;
      unsigned exc = block_scan_bool(isl, wbuf, tot);
      unsigned run = s_run;
      if (isl) {
        unsigned slot = run + exc;
        lvlList[((size_t)b * 4 + l) * 2048 + slot] = (unsigned)pos;
        boxLvl[((size_t)b * 4 + l) * 2048 + slot] = off4;
      }
      __syncthreads();
      if (threadIdx.x == 0) s_run = run + tot;
      __syncthreads();
    }
    if (threadIdx.x == 0) lvlCnt[b * 4 + l] = s_run;
    __syncthreads();
  }
}

// ============================ sorted gather (head): boxes + scores ============================
__global__ __launch_bounds__(256) void head_sort_gather(
    const HeadCand* __restrict__ hc, const unsigned* __restrict__ hsorted,
    const unsigned* __restrict__ hvalid, float4* __restrict__ hbox, float* __restrict__ hsc) {
  int pos = blockIdx.x * 256 + threadIdx.x;
  int valid = (int)*hvalid;
  float4 v = make_float4(0.f, 0.f, 0.f, 0.f);
  float s = 0.f;
  if (pos < valid) {
    HeadCand c = hc[hsorted[pos]];
    v = make_float4(c.x1, c.y1, c.x2, c.y2);
    s = c.score;
  }
  hbox[pos] = v;
  hsc[pos] = s;
}

// ============================ NMS suppression-mask build (rows) ============================
__global__ __launch_bounds__(64) void nms_mask_kernel(
    const float4* __restrict__ boxesOff, const unsigned* __restrict__ validCnt,
    unsigned long long* __restrict__ mask, int rowStrideWords,
    int imgBoxStride, long long imgMaskStride, float th) {
  int b = blockIdx.z;
  const float4* bx = boxesOff + (size_t)b * imgBoxStride;
  unsigned long long* mrow = mask + (size_t)b * imgMaskStride;
  int valid = (int)validCnt[b];
  int i = blockIdx.x * 64 + threadIdx.x;
  int j0 = blockIdx.y * 64;
  __shared__ float4 sb[64];
  sb[threadIdx.x] = bx[j0 + threadIdx.x];
  __syncthreads();
  float4 a = bx[i];
  unsigned long long bits = 0;
  for (int t = 0; t < 64; t++) {
    int j = j0 + t;
    if (j > i && j < valid && iou_pair(a, sb[t]) > th) bits |= (1ull << t);
  }
  mrow[(size_t)i * rowStrideWords + (j0 >> 6)] = bits;
}

// ============================ in-tile column masks ============================
__global__ __launch_bounds__(64) void nms_col_kernel(
    const float4* __restrict__ boxes, const unsigned* __restrict__ validCnt,
    unsigned long long* __restrict__ colw, int jobBoxStride, int jobColStride, float th) {
  int job = blockIdx.y;
  int base = blockIdx.x * 64;
  const float4* bx = boxes + (size_t)job * jobBoxStride;
  int valid = (int)validCnt[job];
  int lane = threadIdx.x;
  __shared__ float4 sb[64];
  sb[lane] = bx[base + lane];
  __syncthreads();
  float4 a = sb[lane];
  unsigned long long bits = 0;
  if (base + lane < valid) {
    for (int t = 0; t < lane; t++) {
      if (iou_pair(sb[t], a) > th) bits |= (1ull << t);
    }
  }
  colw[(size_t)job * jobColStride + base + lane] = bits;
}

// ============================ ballot-frontier greedy NMS reduce ============================
template <int KMAX>
__global__ __launch_bounds__(64) void nms_reduce_frontier_kernel(
    const unsigned long long* __restrict__ mask,   // rows [job][2048][32]
    const unsigned long long* __restrict__ colw,   // cols [job][2048]
    const unsigned* __restrict__ validCnt,
    unsigned* __restrict__ keptIdx, unsigned* __restrict__ keptCnt,
    long long jobMaskStride, int jobColStride) {
  int job = blockIdx.x;
  const unsigned long long* mrow = mask + (size_t)job * jobMaskStride;
  const unsigned long long* mcol = colw + (size_t)job * jobColStride;
  int valid = (int)validCnt[job];
  unsigned* kout = keptIdx + (size_t)job * KMAX;
  int lane = threadIdx.x;
  int half = lane >> 5, w = lane & 31;
  unsigned long long removed = 0ull;
  int keptTotal = 0;
  int ntiles = (valid + 63) >> 6;

  unsigned long long pf[32];
  unsigned long long colNext = 0ull;
  auto issue = [&](int k) {
    int base = k * 64;
#pragma unroll
    for (int i = 0; i < 32; i++) {
      int r = base + 2 * i + half;
      pf[i] = (r < valid) ? mrow[(size_t)r * 32 + w] : 0ull;
    }
    colNext = (base + lane < valid) ? mcol[base + lane] : 0ull;
  };
  if (ntiles > 0) issue(0);

  for (int k = 0; k < ntiles; k++) {
    int base = k * 64;
    int nt = valid - base; if (nt > 64) nt = 64;
    unsigned long long col = colNext;
    unsigned long long Wrm = shfl64(removed, k);
    bool dead = (lane >= nt) || (((Wrm >> lane) & 1ull) != 0ull);
    bool kept = false;
    unsigned long long Kb = 0ull, Db = __ballot(dead);
    while (~(Kb | Db) != 0ull) {
      if (!kept && !dead) {
        if (col & Kb) dead = true;
        else if ((col & ~Db) == 0ull) kept = true;
      }
      Kb = __ballot(kept);
      Db = __ballot(dead);
    }
    int tk = __popcll(Kb);
    bool full = false;
    if (keptTotal + tk > KMAX) {
      int drop = keptTotal + tk - KMAX;
      unsigned long long kk = Kb;
      for (int d = 0; d < drop; d++) kk &= ~(1ull << (63 - __builtin_clzll(kk)));
      Kb = kk; tk = KMAX - keptTotal; full = true;
    }
    if (lane == 0) {
      unsigned long long km = Kb;
      int kc = keptTotal;
      while (km) { int t = __builtin_ctzll(km); km &= km - 1; kout[kc++] = (unsigned)(base + t); }
    }
    keptTotal += tk;
    if (full) break;
    unsigned long long acc = 0ull;
    unsigned long long kb = Kb >> half;
#pragma unroll
    for (int i = 0; i < 32; i++) {
      if ((kb >> (2 * i)) & 1ull) acc |= pf[i];
    }
    unsigned long long accOther = shfl64(acc, (lane + 32) & 63);
    if (lane < 32) removed |= acc | accOther;
    if (k + 1 < ntiles) issue(k + 1);
  }
  if (lane == 0) keptCnt[job] = (unsigned)keptTotal;
}

// ============================ scatter per-level kept -> global-pos flags ============================
__global__ __launch_bounds__(256) void flag_scatter_kernel(
    const unsigned* __restrict__ keptLoc, const unsigned* __restrict__ lvlKeptCnt,
    const unsigned* __restrict__ lvlList, unsigned char* __restrict__ kflag) {
  int job = blockIdx.y;
  int k = blockIdx.x * 256 + threadIdx.x;
  if (k >= (int)lvlKeptCnt[job]) return;
  unsigned local = keptLoc[(size_t)job * 2048 + k];
  unsigned pos = lvlList[(size_t)job * 2048 + local];
  int b = job >> 2;
  kflag[(size_t)b * 8192 + pos] = 1;
}

// ============================ merge kept flags ============================
__global__ __launch_bounds__(1024) void merge_kept_kernel(
    const unsigned char* __restrict__ kflag, const unsigned* __restrict__ validCnt,
    unsigned* __restrict__ keptIdx, unsigned* __restrict__ Mc) {
  int b = blockIdx.x;
  int valid = (int)validCnt[b];
  __shared__ unsigned wbuf[16];
  __shared__ unsigned s_run;
  if (threadIdx.x == 0) s_run = 0;
  __syncthreads();
  for (int c0 = 0; c0 < 8192; c0 += 1024) {
    int i = c0 + (int)threadIdx.x;
    bool k = (i < valid) && kflag[(size_t)b * 8192 + i];
    unsigned tot;
    unsigned exc = block_scan_bool(k, wbuf, tot);
    unsigned run = s_run;
    if (k) {
      unsigned slot = run + exc;
      if (slot < kPostNms) keptIdx[(size_t)b * kPostNms + slot] = (unsigned)i;
    }
    __syncthreads();
    if (threadIdx.x == 0) s_run = run + tot;
    __syncthreads();
  }
  if (threadIdx.x == 0) {
    unsigned r = s_run;
    Mc[b] = r < kPostNms ? r : kPostNms;
  }
}

// ============================ kept-index gathers ============================
__global__ __launch_bounds__(256) void rpn_roi_gather(
    const unsigned* __restrict__ keptIdx, const unsigned* __restrict__ Mc,
    const float4* __restrict__ boxRaw, float* __restrict__ rois) {
  int b = blockIdx.y;
  int k = blockIdx.x * 256 + threadIdx.x;
  if (k >= (int)Mc[b]) return;
  unsigned i = keptIdx[(size_t)b * kPostNms + k];
  float4 v = boxRaw[(size_t)b * 8192 + i];
  float* r = rois + ((size_t)b * kPostNms + k) * 4;
  r[0] = v.x; r[1] = v.y; r[2] = v.z; r[3] = v.w;
}

__global__ __launch_bounds__(128) void head_det_gather(
    const unsigned* __restrict__ keptIdx, const unsigned* __restrict__ cnt,
    const float4* __restrict__ hbox, const float* __restrict__ hsc,
    float* __restrict__ detBox, float* __restrict__ detSc) {
  int k = threadIdx.x;
  if (k >= (int)*cnt || k >= 100) return;
  unsigned i = keptIdx[k];
  float4 v = hbox[i];
  detBox[k * 4 + 0] = v.x; detBox[k * 4 + 1] = v.y;
  detBox[k * 4 + 2] = v.z; detBox[k * 4 + 3] = v.w;
  detSc[k] = hsc[i];
}

// ============================ ROI params ============================
__global__ __launch_bounds__(256) void roi_params_kernel(
    const float* __restrict__ rois, const unsigned* __restrict__ Mc, RoiParam* __restrict__ par) {
  int b = blockIdx.y;
  int i = blockIdx.x * 256 + threadIdx.x;
  if (i >= (int)Mc[b]) return;
  const float* r = rois + ((size_t)b * kPostNms + i) * 4;
  float x1 = r[0], y1 = r[1], x2 = r[2], y2 = r[3];
  float area = (x2 - x1) * (y2 - y1);
  float tgt = floorf(4.0f + log2f(sqrtf(fmaxf(area, 0.f)) / 224.0f + 1e-6f));
  tgt = fminf(fmaxf(tgt, 2.f), 5.f);
  int l = (int)tgt - 2;
  const float scales[4] = {0.25f, 0.125f, 0.0625f, 0.03125f};
  float sc = scales[l];
  RoiParam p;
  p.lvl = l;
  p.x1 = x1 * sc; p.y1 = y1 * sc;
  p.rw = fmaxf(x2 * sc - p.x1, 1.0f);
  p.rh = fmaxf(y2 * sc - p.y1, 1.0f);
  p.pad0 = p.pad1 = p.pad2 = 0;
  par[(size_t)b * kPostNms + i] = p;
}

// ============================ pooled pad (zero rows >= Mc) ============================
__global__ __launch_bounds__(256) void pad_pooled_kernel(
    u16* __restrict__ hi, u16* __restrict__ lo, const unsigned* __restrict__ Mc, int b) {
  int start = (int)Mc[b] * 6272;
  const int total = kMPad * 6272;
  for (int i = start + (int)(blockIdx.x * 256 + threadIdx.x); i < total; i += 512 * 256) {
    hi[i] = 0; lo[i] = 0;
  }
}

// ============================ multi-scale ROI align (writes split-f16) ============================
__global__ __launch_bounds__(256) void roi_align_kernel(
    const float* __restrict__ f0, const float* __restrict__ f1,
    const float* __restrict__ f2, const float* __restrict__ f3,
    const RoiParam* __restrict__ par, const unsigned* __restrict__ Mc,
    u16* __restrict__ pooledHi, u16* __restrict__ pooledLo, int b) {
  int idx = blockIdx.x * 256 + threadIdx.x;
  int roi = idx / 6272;
  if (roi >= (int)Mc[b]) return;
  int rem = idx - roi * 6272;
  int c = rem / 49, bin = rem - c * 49;
  int py = bin / 7, px = bin - py * 7;
  RoiParam p = par[roi];
  int H = c_LH[p.lvl], W = c_LW[p.lvl];
  const float* f = (p.lvl == 0 ? f0 : p.lvl == 1 ? f1 : p.lvl == 2 ? f2 : f3);
  f += ((size_t)b * 128 + c) * (size_t)(H * W);
  float Hf = (float)H, Wf = (float)W;
  float rh7 = p.rh / 7.0f, rw7 = p.rw / 7.0f;
  float sum = 0.f;
#pragma unroll
  for (int sy = 0; sy < 2; sy++) {
    float offy = (float)py + ((float)sy + 0.5f) * 0.5f;
    float Y = p.y1 + offy * rh7;
    float yc = fminf(fmaxf(Y, 0.f), Hf - 1.f);
    float y0f = floorf(yc);
    int y0 = (int)y0f;
    int y1 = min(y0 + 1, H - 1);
    float ly = yc - y0f, hy = 1.f - ly;
#pragma unroll
    for (int sx = 0; sx < 2; sx++) {
      float offx = (float)px + ((float)sx + 0.5f) * 0.5f;
      float X = p.x1 + offx * rw7;
      bool valid = (Y > -1.f) && (Y < Hf) && (X > -1.f) && (X < Wf);
      float xc = fminf(fmaxf(X, 0.f), Wf - 1.f);
      float x0f = floorf(xc);
      int x0 = (int)x0f;
      int x1i = min(x0 + 1, W - 1);
      float lx = xc - x0f, hx = 1.f - lx;
      float v = hy * hx * f[y0 * W + x0] + hy * lx * f[y0 * W + x1i] +
                ly * hx * f[y1 * W + x0] + ly * lx * f[y1 * W + x1i];
      sum += valid ? v : 0.f;
    }
  }
  float v = sum * 0.25f;
  u16 hi, lo;
  split_f16(v, hi, lo);
  pooledHi[idx] = hi;
  pooledLo[idx] = lo;
}

// ============================ weight split conversion ============================
__global__ __launch_bounds__(256) void convert_split_kernel(
    const float* __restrict__ src, u16* __restrict__ hi, u16* __restrict__ lo, int n) {
  for (int i = blockIdx.x * 256 + threadIdx.x; i < n; i += gridDim.x * 256) {
    u16 h, l;
    split_f16(src[i], h, l);
    hi[i] = h; lo[i] = l;
  }
}

// ============================ f16x3 dual-acc split-K MFMA GEMM ============================
__global__ __launch_bounds__(256) void gemm_f16x3_kernel(
    const u16* __restrict__ Ah, const u16* __restrict__ Al,
    const u16* __restrict__ Bh, const u16* __restrict__ Bl,
    float* __restrict__ Cpart, int K, int kChunks) {
  __shared__ u16 sAh[128][40], sAl[128][40], sBh[128][40], sBl[128][40];
  int tid = threadIdx.x;
  int m0 = blockIdx.y * 128, n0 = blockIdx.x * 128;
  int kBase = blockIdx.z * kChunks * 32;
  int w = tid >> 6, lane = tid & 63;
  int wm = (w >> 1) * 64, wn = (w & 1) * 64;
  int quad = lane >> 4, lrow = lane & 15;
  f32x4 acc1[4][4], acc2[4][4];
#pragma unroll
  for (int i = 0; i < 4; i++)
#pragma unroll
    for (int j = 0; j < 4; j++) { acc1[i][j] = (f32x4)0.f; acc2[i][j] = (f32x4)0.f; }

  for (int c = 0; c < kChunks; c++) {
    int k0 = kBase + c * 32;
    for (int e = tid; e < 512; e += 256) {
      int row = e >> 2, kk = (e & 3) * 8;
      size_t ga = (size_t)(m0 + row) * K + k0 + kk;
      size_t gb = (size_t)(n0 + row) * K + k0 + kk;
      *(short8*)&sAh[row][kk] = *(const short8*)&Ah[ga];
      *(short8*)&sAl[row][kk] = *(const short8*)&Al[ga];
      *(short8*)&sBh[row][kk] = *(const short8*)&Bh[gb];
      *(short8*)&sBl[row][kk] = *(const short8*)&Bl[gb];
    }
    __syncthreads();
    int kb = quad * 8;
    f16x8 afh[4], afl[4], bfh[4], bfl[4];
#pragma unroll
    for (int t = 0; t < 4; t++) {
      afh[t] = *(const f16x8*)&sAh[wm + t * 16 + lrow][kb];
      afl[t] = *(const f16x8*)&sAl[wm + t * 16 + lrow][kb];
      bfh[t] = *(const f16x8*)&sBh[wn + t * 16 + lrow][kb];
      bfl[t] = *(const f16x8*)&sBl[wn + t * 16 + lrow][kb];
    }
#pragma unroll
    for (int mt = 0; mt < 4; mt++)
#pragma unroll
      for (int nt = 0; nt < 4; nt++) {
        acc1[mt][nt] = __builtin_amdgcn_mfma_f32_16x16x32_f16(afh[mt], bfh[nt], acc1[mt][nt], 0, 0, 0);
        acc2[mt][nt] = __builtin_amdgcn_mfma_f32_16x16x32_f16(afh[mt], bfl[nt], acc2[mt][nt], 0, 0, 0);
        acc2[mt][nt] = __builtin_amdgcn_mfma_f32_16x16x32_f16(afl[mt], bfh[nt], acc2[mt][nt], 0, 0, 0);
      }
    __syncthreads();
  }
  float* out = Cpart + (size_t)blockIdx.z * (kMPad * 1024);
#pragma unroll
  for (int mt = 0; mt < 4; mt++)
#pragma unroll
    for (int nt = 0; nt < 4; nt++) {
      int col = n0 + wn + nt * 16 + lrow;
#pragma unroll
      for (int reg = 0; reg < 4; reg++) {
        int row = m0 + wm + mt * 16 + quad * 4 + reg;
        out[(size_t)row * 1024 + col] = acc1[mt][nt][reg] + kISC * acc2[mt][nt][reg];
      }
    }
}

// ============================ combine partials: bias+relu -> split-f16 ============================
__global__ __launch_bounds__(256) void combine_relu_split_kernel(
    const float* __restrict__ part, const float* __restrict__ bias,
    u16* __restrict__ hi, u16* __restrict__ lo) {
  int idx = blockIdx.x * 256 + threadIdx.x;
  int n = idx & 1023;
  float v = fmaxf(part[idx] + part[idx + kMPad * 1024] + bias[n], 0.f);
  u16 h, l;
  split_f16(v, h, l);
  hi[idx] = h; lo[idx] = l;
}

// ============================ combine partials: bias+relu -> f32 ============================
__global__ __launch_bounds__(256) void combine_relu_f32_kernel(
    const float* __restrict__ part, const float* __restrict__ bias,
    float* __restrict__ out) {
  int idx = blockIdx.x * 256 + threadIdx.x;
  int n = idx & 1023;
  out[idx] = fmaxf(part[idx] + part[idx + kMPad * 1024] + bias[n], 0.f);
}

// ============================ head linear (cls 2 + bbox 8 per roi) ============================
__global__ __launch_bounds__(64) void head_linear_kernel(
    const float* __restrict__ H2, const float* __restrict__ cw, const float* __restrict__ cb2,
    const float* __restrict__ bw, const float* __restrict__ bb2,
    const unsigned* __restrict__ Mc, float* __restrict__ out10) {
  int r = blockIdx.x;
  if (r >= (int)*Mc) return;
  __shared__ float x[1024];
  const float* h = H2 + (size_t)r * 1024;
  for (int i = threadIdx.x; i < 1024; i += 64) x[i] = h[i];
  __syncthreads();
  int t = threadIdx.x;
  if (t < 10) {
    const float* w = (t < 2) ? (cw + t * 1024) : (bw + (t - 2) * 1024);
    float bias = (t < 2) ? cb2[t] : bb2[t - 2];
    float dot = 0.f;
    for (int k = 0; k < 1024; k++) dot = fmaf(w[k], x[k], dot);
    out10[r * 10 + t] = dot + bias;
  }
}

// ============================ head decode ============================
__global__ __launch_bounds__(256) void head_decode_kernel(
    const float* __restrict__ out10, const float* __restrict__ rois,
    const unsigned* __restrict__ Mc, HeadCand* __restrict__ hc, int b) {
#pragma clang fp contract(off)
  int r = blockIdx.x * 256 + threadIdx.x;
  if (r >= (int)Mc[b]) return;
  const float* h = out10 + (size_t)r * 10;
  float l0 = h[0], l1 = h[1];
  float mx = fmaxf(l0, l1);
  float e0 = expf(l0 - mx), e1 = expf(l1 - mx);
  float sfg = e1 / (e0 + e1);
  const float* rr = rois + ((size_t)b * kPostNms + r) * 4;
  float4 bx = decode_clip(rr[0], rr[1], rr[2], rr[3], h[6], h[7], h[8], h[9],
                          10.f, 10.f, 5.f, 5.f);
  bool keep = (sfg > 0.05f) && (bx.z - bx.x >= 0.01f) && (bx.w - bx.y >= 0.01f);
  HeadCand c;
  c.x1 = bx.x; c.y1 = bx.y; c.x2 = bx.z; c.y2 = bx.w;
  c.score = sfg;
  c.key = keep ? keyOf(sfg) : 0u;
  c.pad0 = c.pad1 = 0;
  hc[r] = c;
}

// ============================ final output ============================
__global__ __launch_bounds__(256) void output_kernel(
    const float* __restrict__ detBox, const float* __restrict__ detSc,
    const unsigned* __restrict__ detCnt, float* __restrict__ out) {
  int t = threadIdx.x;
  if (t >= 200) return;
  int b = t / 100, q = t - b * 100;
  int cnt = (int)detCnt[b];
  float bx0 = 0.f, bx1 = 0.f, bx2 = 0.f, bx3 = 0.f, sc = 0.f, lb = 0.f;
  if (q < cnt) {
    const float* d = detBox + ((size_t)b * 100 + q) * 4;
    bx0 = d[0]; bx1 = d[1]; bx2 = d[2]; bx3 = d[3];
    sc = detSc[b * 100 + q];
    lb = 1.0f;
  }
  float* ob = out + ((size_t)b * 100 + q) * 4;
  ob[0] = bx0; ob[1] = bx1; ob[2] = bx2; ob[3] = bx3;
  out[800 + t] = sc;
  out[1000 + t] = lb;
}

// ============================ host launcher ============================
extern "C" void kernel_launch(void* const* d_in, const int* in_sizes, int n_in,
                              void* d_out, int out_size, void* d_ws, size_t ws_size,
                              hipStream_t stream) {
  (void)in_sizes; (void)n_in; (void)out_size; (void)ws_size;
  const float* feats[4] = {(const float*)d_in[0], (const float*)d_in[1],
                           (const float*)d_in[2], (const float*)d_in[3]};
  const float* w3 = (const float*)d_in[4];
  const float* b3 = (const float*)d_in[5];
  const float* wc = (const float*)d_in[6];
  const float* bcs = (const float*)d_in[7];
  const float* wb = (const float*)d_in[8];
  const float* bbx = (const float*)d_in[9];
  const float* fc6w = (const float*)d_in[10];
  const float* fc6b = (const float*)d_in[11];
  const float* fc7w = (const float*)d_in[12];
  const float* fc7b = (const float*)d_in[13];
  const float* clsw = (const float*)d_in[14];
  const float* clsb = (const float*)d_in[15];
  const float* bboxw = (const float*)d_in[16];
  const float* bboxb = (const float*)d_in[17];

  unsigned char* base = (unsigned char*)d_ws;
  size_t off = 0;
  auto alloc = [&](size_t bytes) -> void* {
    void* p = base + off;
    off += (bytes + 255) & ~(size_t)255;
    return p;
  };
  unsigned* keys = (unsigned*)alloc((size_t)2 * kAImg * 4);
  float* deltas = (float*)alloc((size_t)2 * kAImg * 16);
  unsigned* tkT = (unsigned*)alloc(32);
  unsigned* tkNeed = (unsigned*)alloc(32);
  unsigned* gtCnt = (unsigned*)alloc(316 * 4);
  unsigned* eqCnt = (unsigned*)alloc(316 * 4);
  unsigned* gtBase = (unsigned*)alloc(316 * 4);
  unsigned* eqBase = (unsigned*)alloc(316 * 4);
  Cand* cand = (Cand*)alloc((size_t)2 * kNCand * sizeof(Cand));
  unsigned* sortedSlot = (unsigned*)alloc((size_t)2 * 8192 * 4);
  unsigned* validCnt = (unsigned*)alloc(8);
  float4* boxRaw = (float4*)alloc((size_t)2 * 8192 * 16);
  float4* boxLvl = (float4*)alloc((size_t)8 * 2048 * 16);
  unsigned* lvlList = (unsigned*)alloc((size_t)8 * 2048 * 4);
  unsigned* lvlCnt = (unsigned*)alloc(32);
  unsigned long long* lvlMask = (unsigned long long*)alloc((size_t)8 * 2048 * 32 * 8);
  unsigned long long* lvlCol = (unsigned long long*)alloc((size_t)8 * 2048 * 8);
  unsigned* keptLoc = (unsigned*)alloc((size_t)8 * 2048 * 4);
  unsigned* lvlKeptCnt = (unsigned*)alloc(32);
  unsigned char* kflag = (unsigned char*)alloc((size_t)2 * 8192);
  unsigned* keptIdx = (unsigned*)alloc((size_t)2 * kPostNms * 4);
  float* rois = (float*)alloc((size_t)2 * kPostNms * 16);
  unsigned* Mc = (unsigned*)alloc(8);
  RoiParam* roiPar = (RoiParam*)alloc((size_t)2 * kPostNms * sizeof(RoiParam));
  // conv pipeline buffers (reused per image/level)
  u16* padHi = (u16*)alloc((size_t)204 * 202 * 128 * 2);
  u16* padLo = (u16*)alloc((size_t)204 * 202 * 128 * 2);
  u16* wTapHi = (u16*)alloc((size_t)9 * 128 * 128 * 2);
  u16* wTapLo = (u16*)alloc((size_t)9 * 128 * 128 * 2);
  float* tbuf = (float*)alloc((size_t)313 * 128 * 128 * 4);
  u16* pooledHi = (u16*)alloc((size_t)kMPad * 6272 * 2);
  u16* pooledLo = (u16*)alloc((size_t)kMPad * 6272 * 2);
  u16* fc6wHi = (u16*)alloc((size_t)1024 * 6272 * 2);
  u16* fc6wLo = (u16*)alloc((size_t)1024 * 6272 * 2);
  u16* fc7wHi = (u16*)alloc((size_t)1024 * 1024 * 2);
  u16* fc7wLo = (u16*)alloc((size_t)1024 * 1024 * 2);
  float* part = (float*)alloc((size_t)2 * kMPad * 1024 * 4);
  u16* H1hi = (u16*)alloc((size_t)kMPad * 1024 * 2);
  u16* H1lo = (u16*)alloc((size_t)kMPad * 1024 * 2);
  float* H2buf = (float*)alloc((size_t)kMPad * 1024 * 4);
  float* out10 = (float*)alloc((size_t)kPostNms * 10 * 4);
  HeadCand* hc = (HeadCand*)alloc((size_t)kPostNms * sizeof(HeadCand));
  unsigned* hsorted = (unsigned*)alloc((size_t)2048 * 4);
  unsigned* hvalid = (unsigned*)alloc(4);
  float4* hbox = (float4*)alloc((size_t)2048 * 16);
  float* hsc = (float*)alloc((size_t)2048 * 4);
  unsigned long long* hMask = (unsigned long long*)alloc((size_t)2048 * 32 * 8);
  unsigned long long* hCol = (unsigned long long*)alloc((size_t)2048 * 8);
  unsigned* hkept = (unsigned*)alloc((size_t)128 * 4);
  float* detBox = (float*)alloc((size_t)2 * 100 * 4 * 4);
  float* detSc = (float*)alloc((size_t)2 * 100 * 4);
  unsigned* detCnt = (unsigned*)alloc(8);

  // anchor base table, double precision, round-half-even (matches np.round)
  AnchTab tab;
  {
    const double aspects[3] = {0.5, 1.0, 2.0};
    const int sizes[4] = {32, 64, 128, 256};
    for (int l = 0; l < 4; l++)
      for (int a = 0; a < 3; a++) {
        double hr = sqrt(aspects[a]);
        double wr = 1.0 / hr;
        double wsz = wr * sizes[l], hsz = hr * sizes[l];
        tab.v[l][a][0] = (float)rint(-wsz / 2.0);
        tab.v[l][a][1] = (float)rint(-hsz / 2.0);
        tab.v[l][a][2] = (float)rint(wsz / 2.0);
        tab.v[l][a][3] = (float)rint(hsz / 2.0);
      }
  }

  const int LH[4] = {200, 100, 50, 25}, LW[4] = {200, 100, 50, 25};
  const int AOFF[4] = {0, 120000, 150000, 157500};

  // weight conversions (same work every call; graph-capture safe)
  convert_split_kernel<<<4096, 256, 0, stream>>>(fc6w, fc6wHi, fc6wLo, 1024 * 6272);
  convert_split_kernel<<<1024, 256, 0, stream>>>(fc7w, fc7wHi, fc7wLo, 1024 * 1024);
  conv_w_repack_kernel<<<(9 * 128 * 128 + 255) / 256, 256, 0, stream>>>(w3, wTapHi, wTapLo);

  // RPN conv pipeline (MFMA implicit GEMM) per image per level
  for (int b = 0; b < 2; b++) {
    for (int l = 0; l < 4; l++) {
      int H = LH[l], W = LW[l];
      int HW = H * W;
      int mtiles = (HW + 127) / 128;
      int n32 = (H + 4) * (W + 2) * 128 / 2;
      zero_u32_kernel<<<512, 256, 0, stream>>>((unsigned*)padHi, n32);
      zero_u32_kernel<<<512, 256, 0, stream>>>((unsigned*)padLo, n32);
      const float* fsrc = feats[l] + (size_t)b * 128 * HW;
      dim3 tgrid((W + 63) / 64, H);
      switch (l) {
        case 0:
          transpose_pad_kernel<200, 200><<<tgrid, 256, 0, stream>>>(fsrc, padHi, padLo);
          conv_mfma_kernel<200, 200><<<mtiles, 256, 0, stream>>>(padHi, padLo, wTapHi, wTapLo, b3, tbuf);
          break;
        case 1:
          transpose_pad_kernel<100, 100><<<tgrid, 256, 0, stream>>>(fsrc, padHi, padLo);
          conv_mfma_kernel<100, 100><<<mtiles, 256, 0, stream>>>(padHi, padLo, wTapHi, wTapLo, b3, tbuf);
          break;
        case 2:
          transpose_pad_kernel<50, 50><<<tgrid, 256, 0, stream>>>(fsrc, padHi, padLo);
          conv_mfma_kernel<50, 50><<<mtiles, 256, 0, stream>>>(padHi, padLo, wTapHi, wTapLo, b3, tbuf);
          break;
        default:
          transpose_pad_kernel<25, 25><<<tgrid, 256, 0, stream>>>(fsrc, padHi, padLo);
          conv_mfma_kernel<25, 25><<<mtiles, 256, 0, stream>>>(padHi, padLo, wTapHi, wTapLo, b3, tbuf);
          break;
      }
      head_1x1_kernel<<<(HW + 255) / 256, 256, 0, stream>>>(
          tbuf, wc, bcs, wb, bbx, keys + (size_t)b * kAImg,
          deltas + (size_t)b * kAImg * 4, AOFF[l], HW);
    }
  }

  radix_select_kernel<<<6, 1024, 0, stream>>>(keys, tkT, tkNeed);
  cand_count_kernel<<<316, 1024, 0, stream>>>(keys, tkT, gtCnt, eqCnt);
  cand_prefix_kernel<<<1, 512, 0, stream>>>(gtCnt, eqCnt, gtBase, eqBase);
  cand_scatter_kernel<<<316, 1024, 0, stream>>>(
      keys, deltas, tkT, tkNeed, gtBase, eqBase, cand, tab);
  sort_desc_kernel<8192><<<2, 1024, 0, stream>>>(
      ((const unsigned*)cand) + 4, 8, kNCand, nullptr, sortedSlot, validCnt, kNCand * 8, 8192);
  rpn_sort_gather<<<dim3(32, 2), 256, 0, stream>>>(cand, sortedSlot, validCnt, boxRaw);
  lvl_compact_kernel<<<2, 1024, 0, stream>>>(cand, sortedSlot, validCnt, boxLvl, lvlList, lvlCnt);
  nms_mask_kernel<<<dim3(32, 32, 8), 64, 0, stream>>>(
      boxLvl, lvlCnt, lvlMask, 32, 2048, (long long)2048 * 32, 0.7f);
  nms_col_kernel<<<dim3(32, 8), 64, 0, stream>>>(
      boxLvl, lvlCnt, lvlCol, 2048, 2048, 0.7f);
  nms_reduce_frontier_kernel<2048><<<8, 64, 0, stream>>>(
      lvlMask, lvlCol, lvlCnt, keptLoc, lvlKeptCnt, (long long)2048 * 32, 2048);
  zero_u32_kernel<<<16, 256, 0, stream>>>((unsigned*)kflag, 4096);
  flag_scatter_kernel<<<dim3(8, 8), 256, 0, stream>>>(keptLoc, lvlKeptCnt, lvlList, kflag);
  merge_kept_kernel<<<2, 1024, 0, stream>>>(kflag, validCnt, keptIdx, Mc);
  rpn_roi_gather<<<dim3(8, 2), 256, 0, stream>>>(keptIdx, Mc, boxRaw, rois);
  roi_params_kernel<<<dim3(8, 2), 256, 0, stream>>>(rois, Mc, roiPar);

  for (int b = 0; b < 2; b++) {
    pad_pooled_kernel<<<512, 256, 0, stream>>>(pooledHi, pooledLo, Mc, b);
    roi_align_kernel<<<49000, 256, 0, stream>>>(
        feats[0], feats[1], feats[2], feats[3], roiPar + (size_t)b * kPostNms, Mc,
        pooledHi, pooledLo, b);
    // fc6: M=2048, N=1024, K=6272 (split 2 x 98 chunks of 32)
    gemm_f16x3_kernel<<<dim3(8, 16, 2), 256, 0, stream>>>(
        pooledHi, pooledLo, fc6wHi, fc6wLo, part, 6272, 98);
    combine_relu_split_kernel<<<8192, 256, 0, stream>>>(part, fc6b, H1hi, H1lo);
    // fc7: M=2048, N=1024, K=1024 (split 2 x 16 chunks of 32)
    gemm_f16x3_kernel<<<dim3(8, 16, 2), 256, 0, stream>>>(
        H1hi, H1lo, fc7wHi, fc7wLo, part, 1024, 16);
    combine_relu_f32_kernel<<<8192, 256, 0, stream>>>(part, fc7b, H2buf);
    head_linear_kernel<<<2000, 64, 0, stream>>>(H2buf, clsw, clsb, bboxw, bboxb, Mc + b, out10);
    head_decode_kernel<<<8, 256, 0, stream>>>(out10, rois, Mc, hc, b);
    sort_desc_kernel<2048><<<1, 1024, 0, stream>>>(
        ((const unsigned*)hc) + 5, 8, 2000, Mc + b, hsorted, hvalid, 0, 0);
    head_sort_gather<<<8, 256, 0, stream>>>(hc, hsorted, hvalid, hbox, hsc);
    nms_mask_kernel<<<dim3(32, 32, 1), 64, 0, stream>>>(
        hbox, hvalid, hMask, 32, 0, 0, 0.5f);
    nms_col_kernel<<<dim3(32, 1), 64, 0, stream>>>(
        hbox, hvalid, hCol, 0, 0, 0.5f);
    nms_reduce_frontier_kernel<100><<<1, 64, 0, stream>>>(
        hMask, hCol, hvalid, hkept, detCnt + b, (long long)2048 * 32, 0);
    head_det_gather<<<1, 128, 0, stream>>>(
        hkept, detCnt + b, hbox, hsc, detBox + (size_t)b * 400, detSc + (size_t)b * 100);
  }
  output_kernel<<<1, 256, 0, stream>>>(detBox, detSc, detCnt, (float*)d_out);
}

// Round 12
// 2203.392 us; speedup vs baseline: 1.3207x; 1.0711x over previous
//
#include <hip/hip_runtime.h>
#include <cmath>

// ============================ constants ============================
static constexpr int kAImg = 159375;   // anchors per image
static constexpr int kNCand = 7875;    // 2000+2000+2000+1875
static constexpr int kPostNms = 2000;
static constexpr int kMPad = 2048;     // padded roi count for MFMA GEMM
static constexpr int kHWCImg = 53125;  // positions per image (sum of lvl H*W)
static constexpr float kISC = 1.0f / 4096.0f;

__constant__ int c_AOFF[4]   = {0, 120000, 150000, 157500};
__constant__ int c_ALVL[4]   = {120000, 30000, 7500, 1875};
__constant__ int c_CBASE[4]  = {0, 2000, 4000, 6000};
__constant__ int c_LW[4]     = {200, 100, 50, 25};
__constant__ int c_LH[4]     = {200, 100, 50, 25};
__constant__ int c_STRIDE[4] = {4, 8, 16, 32};
__constant__ int c_POFF[4]   = {0, 40000, 50000, 52500};
// chunk bases per job (1024-elem chunks): lvl chunks {118,30,8,2}, 158/image
__constant__ int c_JCHUNK[9] = {0, 118, 148, 156, 158, 276, 306, 314, 316};

struct Cand     { float x1, y1, x2, y2; unsigned key; unsigned lvl; unsigned pad0, pad1; };
struct HeadCand { float x1, y1, x2, y2; float score; unsigned key; unsigned pad0, pad1; };
struct RoiParam { int lvl; float x1, y1, rw, rh; int pad0, pad1, pad2; };
struct AnchTab  { float v[4][3][4]; };

typedef unsigned short u16;
typedef __attribute__((ext_vector_type(8))) short short8;
typedef __attribute__((ext_vector_type(4))) float f32x4;
typedef _Float16 f16x8 __attribute__((ext_vector_type(8)));

// ============================ device helpers ============================
__device__ __forceinline__ unsigned keyOf(float f) {
  unsigned u = __float_as_uint(f);
  return (u & 0x80000000u) ? ~u : (u | 0x80000000u);
}

// fp32 -> (f16 hi, f16 lo*4096). value = hi + lo/4096, err ~ 2^-24 relative.
__device__ __forceinline__ void split_f16(float f, u16& hi, u16& lo) {
  union { _Float16 h; u16 u; } a, b;
  a.h = (_Float16)f;
  float r = (f - (float)a.h) * 4096.0f;
  b.h = (_Float16)r;
  hi = a.u; lo = b.u;
}

__device__ __forceinline__ unsigned long long shfl64(unsigned long long v, int src) {
  int lo = __shfl((int)(unsigned)(v & 0xffffffffull), src);
  int hi = __shfl((int)(unsigned)(v >> 32), src);
  return ((unsigned long long)(unsigned)hi << 32) | (unsigned)lo;
}

__device__ __forceinline__ float iou_pair(float4 a, float4 b) {
#pragma clang fp contract(off)
  float ix1 = fmaxf(a.x, b.x), iy1 = fmaxf(a.y, b.y);
  float ix2 = fminf(a.z, b.z), iy2 = fminf(a.w, b.w);
  float iw = fmaxf(ix2 - ix1, 0.f), ih = fmaxf(iy2 - iy1, 0.f);
  float inter = iw * ih;
  float a1 = (a.z - a.x) * (a.w - a.y);
  float a2 = (b.z - b.x) * (b.w - b.y);
  float uni = a1 + a2 - inter;
  return uni > 0.f ? inter / uni : 0.f;
}

__device__ __forceinline__ float4 decode_clip(float bx1, float by1, float bx2, float by2,
                                              float d0, float d1, float d2, float d3,
                                              float wx, float wy, float ww, float wh) {
#pragma clang fp contract(off)
  float w = bx2 - bx1, h = by2 - by1;
  float cx = bx1 + 0.5f * w, cy = by1 + 0.5f * h;
  float dx = d0 / wx, dy = d1 / wy;
  float dw = fminf(d2 / ww, 4.135166556742356f);
  float dh = fminf(d3 / wh, 4.135166556742356f);
  float pcx = dx * w + cx, pcy = dy * h + cy;
  float pw = expf(dw) * w, ph = expf(dh) * h;
  float x1 = pcx - 0.5f * pw, y1 = pcy - 0.5f * ph;
  float x2 = pcx + 0.5f * pw, y2 = pcy + 0.5f * ph;
  x1 = fminf(fmaxf(x1, 0.f), 800.f); y1 = fminf(fmaxf(y1, 0.f), 800.f);
  x2 = fminf(fmaxf(x2, 0.f), 800.f); y2 = fminf(fmaxf(y2, 0.f), 800.f);
  return make_float4(x1, y1, x2, y2);
}

// block-wide exclusive scan of a bool over 1024 threads (16 waves)
__device__ __forceinline__ unsigned block_scan_bool(bool p, unsigned* wbuf, unsigned& total) {
  unsigned long long m = __ballot(p);
  int lane = threadIdx.x & 63;
  int wid = threadIdx.x >> 6;
  unsigned exc = (unsigned)__popcll(m & ((lane == 0) ? 0ull : ((~0ull) >> (64 - lane))));
  if (lane == 0) wbuf[wid] = (unsigned)__popcll(m);
  __syncthreads();
  unsigned pre = 0, tot = 0;
#pragma unroll
  for (int w = 0; w < 16; w++) { unsigned c = wbuf[w]; if (w < wid) pre += c; tot += c; }
  total = tot;
  __syncthreads();
  return pre + exc;
}

// ============================ zero fill ============================
__global__ __launch_bounds__(256) void zero_u32_kernel(unsigned* __restrict__ p, int n32) {
  for (int i = blockIdx.x * 256 + threadIdx.x; i < n32; i += gridDim.x * 256) p[i] = 0u;
}

// ============================ NCHW -> padded HWC f16-split transpose (+ fp32 HWC copy) ============================
template <int H, int W>
__global__ __launch_bounds__(256) void transpose_pad_kernel(
    const float* __restrict__ feat, u16* __restrict__ Fh, u16* __restrict__ Fl,
    float* __restrict__ Fw) {
  __shared__ float tile[128][65];
  int y = blockIdx.y;
  int x0 = blockIdx.x * 64;
  for (int e = threadIdx.x; e < 128 * 64; e += 256) {
    int ci = e >> 6, x = e & 63;
    float v = 0.f;
    if (x0 + x < W) v = feat[(size_t)ci * (H * W) + y * W + x0 + x];
    tile[ci][x] = v;
  }
  __syncthreads();
  for (int e = threadIdx.x; e < 64 * 128; e += 256) {
    int x = e >> 7, ci = e & 127;
    if (x0 + x >= W) continue;
    float v = tile[ci][x];
    u16 hi, lo;
    split_f16(v, hi, lo);
    size_t out = ((size_t)(y + 1) * (W + 2) + (x0 + x + 1)) * 128 + ci;
    Fh[out] = hi; Fl[out] = lo;
    Fw[((size_t)y * W + (x0 + x)) * 128 + ci] = v;
  }
}

// ============================ conv weight repack ============================
__global__ __launch_bounds__(256) void conv_w_repack_kernel(
    const float* __restrict__ w3, u16* __restrict__ Wh, u16* __restrict__ Wl) {
  int idx = blockIdx.x * 256 + threadIdx.x;
  if (idx >= 9 * 128 * 128) return;
  int tap = idx >> 14;
  int r = idx & 16383;
  int co = r >> 7, ci = r & 127;
  u16 hi, lo;
  split_f16(w3[co * 1152 + ci * 9 + tap], hi, lo);
  Wh[idx] = hi; Wl[idx] = lo;
}

// ============================ implicit-GEMM MFMA 3x3 conv (f16x3 dual-acc) ============================
template <int H, int W>
__global__ __launch_bounds__(256) void conv_mfma_kernel(
    const u16* __restrict__ Fh, const u16* __restrict__ Fl,
    const u16* __restrict__ Wh, const u16* __restrict__ Wl,
    const float* __restrict__ b3, float* __restrict__ tbuf) {
  __shared__ u16 sAh[128][40], sAl[128][40], sBh[128][40], sBl[128][40];
  int tid = threadIdx.x;
  int m0 = blockIdx.x * 128;
  int w = tid >> 6, lane = tid & 63;
  int wm = (w >> 1) * 64, wn = (w & 1) * 64;
  int quad = lane >> 4, lrow = lane & 15;
  f32x4 acc1[4][4], acc2[4][4];
#pragma unroll
  for (int i = 0; i < 4; i++)
#pragma unroll
    for (int j = 0; j < 4; j++) { acc1[i][j] = (f32x4)0.f; acc2[i][j] = (f32x4)0.f; }

  for (int tap = 0; tap < 9; tap++) {
    int ky = tap / 3, kx = tap - (tap / 3) * 3;
    for (int c = 0; c < 4; c++) {
      for (int e = tid; e < 512; e += 256) {
        int row = e >> 2, seg = (e & 3) * 8;
        int m = m0 + row;
        int y = m / W, x = m - y * W;
        size_t pidx = ((size_t)(y + ky) * (W + 2) + x + kx) * 128 + c * 32 + seg;
        *(short8*)&sAh[row][seg] = *(const short8*)&Fh[pidx];
        *(short8*)&sAl[row][seg] = *(const short8*)&Fl[pidx];
        size_t bidx = ((size_t)tap * 128 + row) * 128 + c * 32 + seg;
        *(short8*)&sBh[row][seg] = *(const short8*)&Wh[bidx];
        *(short8*)&sBl[row][seg] = *(const short8*)&Wl[bidx];
      }
      __syncthreads();
      int kb = quad * 8;
      f16x8 afh[4], afl[4], bfh[4], bfl[4];
#pragma unroll
      for (int t = 0; t < 4; t++) {
        afh[t] = *(const f16x8*)&sAh[wm + t * 16 + lrow][kb];
        afl[t] = *(const f16x8*)&sAl[wm + t * 16 + lrow][kb];
        bfh[t] = *(const f16x8*)&sBh[wn + t * 16 + lrow][kb];
        bfl[t] = *(const f16x8*)&sBl[wn + t * 16 + lrow][kb];
      }
#pragma unroll
      for (int mt = 0; mt < 4; mt++)
#pragma unroll
        for (int nt = 0; nt < 4; nt++) {
          acc1[mt][nt] = __builtin_amdgcn_mfma_f32_16x16x32_f16(afh[mt], bfh[nt], acc1[mt][nt], 0, 0, 0);
          acc2[mt][nt] = __builtin_amdgcn_mfma_f32_16x16x32_f16(afh[mt], bfl[nt], acc2[mt][nt], 0, 0, 0);
          acc2[mt][nt] = __builtin_amdgcn_mfma_f32_16x16x32_f16(afl[mt], bfh[nt], acc2[mt][nt], 0, 0, 0);
        }
      __syncthreads();
    }
  }
#pragma unroll
  for (int nt = 0; nt < 4; nt++) {
    int col = wn + nt * 16 + lrow;
    float bias = b3[col];
#pragma unroll
    for (int mt = 0; mt < 4; mt++) {
#pragma unroll
      for (int reg = 0; reg < 4; reg++) {
        int row = m0 + wm + mt * 16 + quad * 4 + reg;
        float v = acc1[mt][nt][reg] + kISC * acc2[mt][nt][reg] + bias;
        tbuf[(size_t)row * 128 + col] = fmaxf(v, 0.f);
      }
    }
  }
}

// ============================ 1x1 heads from t (HWC fp32) ============================
__global__ __launch_bounds__(256) void head_1x1_kernel(
    const float* __restrict__ tbuf,
    const float* __restrict__ wc, const float* __restrict__ bcs,
    const float* __restrict__ wb, const float* __restrict__ bbx,
    unsigned* __restrict__ keys, float* __restrict__ deltas, int aoff, int HW) {
  __shared__ float wl[15][128];
  __shared__ float bl[15];
  for (int e = threadIdx.x; e < 15 * 128; e += 256) {
    int oc = e >> 7, k = e & 127;
    wl[oc][k] = (oc < 3) ? wc[oc * 128 + k] : wb[(oc - 3) * 128 + k];
  }
  if (threadIdx.x < 15)
    bl[threadIdx.x] = (threadIdx.x < 3) ? bcs[threadIdx.x] : bbx[threadIdx.x - 3];
  __syncthreads();
  int m = blockIdx.x * 256 + threadIdx.x;
  if (m >= HW) return;
  const float* trow = tbuf + (size_t)m * 128;
  float dot[15];
#pragma unroll
  for (int o = 0; o < 15; o++) dot[o] = 0.f;
  for (int k = 0; k < 128; k += 4) {
    float4 v = *(const float4*)&trow[k];
#pragma unroll
    for (int o = 0; o < 15; o++) {
      dot[o] = fmaf(wl[o][k], v.x, dot[o]);
      dot[o] = fmaf(wl[o][k + 1], v.y, dot[o]);
      dot[o] = fmaf(wl[o][k + 2], v.z, dot[o]);
      dot[o] = fmaf(wl[o][k + 3], v.w, dot[o]);
    }
  }
#pragma unroll
  for (int oc = 0; oc < 15; oc++) {
    float s = dot[oc] + bl[oc];
    if (oc < 3) {
      keys[aoff + m * 3 + oc] = keyOf(s);
    } else {
      int bc = oc - 3, a = bc >> 2, comp = bc & 3;
      deltas[(size_t)(aoff + m * 3 + a) * 4 + comp] = s;
    }
  }
}

// ============================ radix select per (image,level 0..2) ============================
__global__ __launch_bounds__(1024) void radix_select_kernel(
    const unsigned* __restrict__ keys, unsigned* __restrict__ tkT, unsigned* __restrict__ tkNeed) {
  int job = blockIdx.x;
  int b = job / 3, l = job - b * 3;
  const unsigned* kb = keys + (size_t)b * kAImg + c_AOFF[l];
  int n = c_ALVL[l];
  __shared__ unsigned hist[256];
  __shared__ unsigned s_sel, s_remk;
  unsigned prefix = 0, pmask = 0, remk = 2000;
  for (int shift = 24; shift >= 0; shift -= 8) {
    if (threadIdx.x < 256) hist[threadIdx.x] = 0;
    __syncthreads();
    for (int i = threadIdx.x; i < n; i += 1024) {
      unsigned key = kb[i];
      if ((key & pmask) == prefix) atomicAdd(&hist[(key >> shift) & 255u], 1u);
    }
    __syncthreads();
    if (threadIdx.x == 0) {
      unsigned cum = 0; int sel = 0;
      for (int d = 255; d >= 0; d--) {
        unsigned c = hist[d];
        if (cum + c >= remk) { sel = d; break; }
        cum += c;
      }
      s_sel = (unsigned)sel; s_remk = remk - cum;
    }
    __syncthreads();
    prefix |= (s_sel << shift);
    pmask |= (255u << shift);
    remk = s_remk;
    __syncthreads();
  }
  if (threadIdx.x == 0) { tkT[b * 4 + l] = prefix; tkNeed[b * 4 + l] = remk; }
}

// ============================ cand pass A: per-chunk gt/eq counts ============================
__global__ __launch_bounds__(1024) void cand_count_kernel(
    const unsigned* __restrict__ keys, const unsigned* __restrict__ tkT,
    unsigned* __restrict__ gtCnt, unsigned* __restrict__ eqCnt) {
  __shared__ unsigned wg[16], we[16];
  int cb = blockIdx.x;
  int j = 0;
#pragma unroll
  for (int t = 1; t < 8; t++) if (cb >= c_JCHUNK[t]) j = t;
  int chunk = cb - c_JCHUNK[j];
  int b = j >> 2, l = j & 3;
  int n = c_ALVL[l];
  int i = chunk * 1024 + (int)threadIdx.x;
  bool act = i < n;
  unsigned key = act ? keys[(size_t)b * kAImg + c_AOFF[l] + i] : 0u;
  unsigned T = (l == 3) ? 0u : tkT[b * 4 + l];
  bool gt = act && (l != 3) && (key > T);
  bool eq = act && (l != 3) && (key == T);
  unsigned long long mg = __ballot(gt), me = __ballot(eq);
  int lane = threadIdx.x & 63, wid = threadIdx.x >> 6;
  if (lane == 0) { wg[wid] = (unsigned)__popcll(mg); we[wid] = (unsigned)__popcll(me); }
  __syncthreads();
  if (threadIdx.x == 0) {
    unsigned g = 0, e = 0;
#pragma unroll
    for (int t = 0; t < 16; t++) { g += wg[t]; e += we[t]; }
    gtCnt[cb] = g; eqCnt[cb] = e;
  }
}

// ============================ cand pass B: per-job exclusive prefix over chunks ============================
__global__ __launch_bounds__(512) void cand_prefix_kernel(
    unsigned* __restrict__ gtCnt, unsigned* __restrict__ eqCnt,
    unsigned* __restrict__ gtBase, unsigned* __restrict__ eqBase) {
  int j = threadIdx.x >> 6;
  int lane = threadIdx.x & 63;
  if (lane != 0) return;
  int c0 = c_JCHUNK[j], c1 = c_JCHUNK[j + 1];
  unsigned g = 0, e = 0;
  for (int c = c0; c < c1; c++) {
    gtBase[c] = g; eqBase[c] = e;
    g += gtCnt[c]; e += eqCnt[c];
  }
}

// ============================ cand pass C: parallel stable scatter + decode ============================
__global__ __launch_bounds__(1024) void cand_scatter_kernel(
    const unsigned* __restrict__ keys, const float* __restrict__ deltas,
    const unsigned* __restrict__ tkT, const unsigned* __restrict__ tkNeed,
    const unsigned* __restrict__ gtBase, const unsigned* __restrict__ eqBase,
    Cand* __restrict__ cand, AnchTab tab) {
  __shared__ unsigned wbuf[16];
  int cb = blockIdx.x;
  int j = 0;
#pragma unroll
  for (int t = 1; t < 8; t++) if (cb >= c_JCHUNK[t]) j = t;
  int chunk = cb - c_JCHUNK[j];
  int b = j >> 2, l = j & 3;
  int n = c_ALVL[l];
  int W = c_LW[l];
  int stride = c_STRIDE[l];
  const float* db = deltas + ((size_t)b * kAImg + c_AOFF[l]) * 4;
  Cand* cbuf = cand + (size_t)b * kNCand + c_CBASE[l];
  bool selAll = (l == 3);
  unsigned T = selAll ? 0u : tkT[b * 4 + l];
  unsigned need = selAll ? 0u : tkNeed[b * 4 + l];
  int i = chunk * 1024 + (int)threadIdx.x;
  bool act = i < n;
  unsigned key = act ? keys[(size_t)b * kAImg + c_AOFF[l] + i] : 0u;
  bool gt = act && !selAll && (key > T);
  bool eq = act && !selAll && (key == T);
  unsigned tmp;
  unsigned gtExc = block_scan_bool(gt, wbuf, tmp);
  unsigned eqExc = block_scan_bool(eq, wbuf, tmp);
  unsigned gtCount = gtBase[cb] + gtExc;
  unsigned eqCount = eqBase[cb] + eqExc;
  bool isSel = act && (selAll || gt || (eq && eqCount < need));
  if (!isSel) return;
  int slot = selAll ? i : (int)(gtCount + (eqCount < need ? eqCount : need));
  int pos = i / 3, a = i - pos * 3;
  int yy = pos / W, xx = pos - yy * W;
  float sx = (float)(xx * stride), sy = (float)(yy * stride);
  float ax1 = tab.v[l][a][0] + sx;
  float ay1 = tab.v[l][a][1] + sy;
  float ax2 = tab.v[l][a][2] + sx;
  float ay2 = tab.v[l][a][3] + sy;
  float d0 = db[(size_t)i * 4 + 0], d1 = db[(size_t)i * 4 + 1];
  float d2 = db[(size_t)i * 4 + 2], d3 = db[(size_t)i * 4 + 3];
  float4 bx = decode_clip(ax1, ay1, ax2, ay2, d0, d1, d2, d3, 1.f, 1.f, 1.f, 1.f);
  bool ok = (bx.z - bx.x >= 0.001f) && (bx.w - bx.y >= 0.001f);
  Cand cd;
  cd.x1 = bx.x; cd.y1 = bx.y; cd.x2 = bx.z; cd.y2 = bx.w;
  cd.key = ok ? key : 0u; cd.lvl = (unsigned)l; cd.pad0 = 0; cd.pad1 = 0;
  cbuf[slot] = cd;
}

// ============================ single-block bitonic sort (desc key, asc slot) ============================
template <int NPAD>
__global__ __launch_bounds__(1024) void sort_desc_kernel(
    const unsigned* __restrict__ keyBase, int strideWords, int nFixed,
    const unsigned* __restrict__ nPtr, unsigned* __restrict__ sortedSlot,
    unsigned* __restrict__ validCnt, int imgStrideKeyWords, int imgStrideSlot) {
  __shared__ unsigned sk[NPAD];
  __shared__ unsigned short sslot[NPAD];
  __shared__ unsigned s_cnt;
  int b = blockIdx.x;
  const unsigned* kbase = keyBase + (size_t)b * imgStrideKeyWords;
  unsigned* oslot = sortedSlot + (size_t)b * imgStrideSlot;
  unsigned* ocnt = validCnt + b;
  int n = nFixed;
  if (nPtr) { int m = (int)nPtr[b]; n = n < m ? n : m; }
  for (int i = threadIdx.x; i < NPAD; i += 1024) {
    sk[i] = (i < n) ? kbase[(size_t)i * strideWords] : 0u;
    sslot[i] = (unsigned short)i;
  }
  if (threadIdx.x == 0) s_cnt = 0;
  __syncthreads();
  for (int k2 = 2; k2 <= NPAD; k2 <<= 1) {
    for (int j = k2 >> 1; j > 0; j >>= 1) {
      for (int i = threadIdx.x; i < NPAD; i += 1024) {
        int ixj = i ^ j;
        if (ixj > i) {
          unsigned ka = sk[i], kb2 = sk[ixj];
          unsigned short sa = sslot[i], sb = sslot[ixj];
          bool aGreater = (ka > kb2) || (ka == kb2 && sa < sb);
          bool up = ((i & k2) == 0);
          bool doSwap = up ? (!aGreater) : aGreater;
          if (doSwap) { sk[i] = kb2; sk[ixj] = ka; sslot[i] = sb; sslot[ixj] = sa; }
        }
      }
      __syncthreads();
    }
  }
  unsigned local = 0;
  for (int i = threadIdx.x; i < NPAD; i += 1024) {
    oslot[i] = (unsigned)sslot[i];
    if (sk[i] > 0u) local++;
  }
  atomicAdd(&s_cnt, local);
  __syncthreads();
  if (threadIdx.x == 0) *ocnt = s_cnt;
}

// ============================ sorted gather (RPN): raw boxes per sorted pos ============================
__global__ __launch_bounds__(256) void rpn_sort_gather(
    const Cand* __restrict__ cand, const unsigned* __restrict__ ss,
    const unsigned* __restrict__ validCnt, float4* __restrict__ boxRaw) {
  int b = blockIdx.y;
  int pos = blockIdx.x * 256 + threadIdx.x;
  int valid = (int)validCnt[b];
  float4 raw = make_float4(0.f, 0.f, 0.f, 0.f);
  if (pos < valid) {
    Cand c = cand[(size_t)b * kNCand + ss[(size_t)b * 8192 + pos]];
    raw = make_float4(c.x1, c.y1, c.x2, c.y2);
  }
  boxRaw[(size_t)b * 8192 + pos] = raw;
}

// ============================ per-level stable compaction (sorted order, offset boxes) ============================
__global__ __launch_bounds__(1024) void lvl_compact_kernel(
    const Cand* __restrict__ cand, const unsigned* __restrict__ ss,
    const unsigned* __restrict__ validCnt, float4* __restrict__ boxLvl,
    unsigned* __restrict__ lvlList, unsigned* __restrict__ lvlCnt) {
  int b = blockIdx.x;
  int valid = (int)validCnt[b];
  __shared__ unsigned wbuf[16];
  __shared__ unsigned s_run;
  for (int l = 0; l < 4; l++) {
    if (threadIdx.x == 0) s_run = 0;
    __syncthreads();
    for (int c0 = 0; c0 < 8192; c0 += 1024) {
      int pos = c0 + (int)threadIdx.x;
      bool act = pos < valid;
      unsigned lv = 99u;
      float4 off4 = make_float4(0.f, 0.f, 0.f, 0.f);
      if (act) {
#pragma clang fp contract(off)
        Cand c = cand[(size_t)b * kNCand + ss[(size_t)b * 8192 + pos]];
        lv = c.lvl;
        float off = 801.0f * (float)c.lvl;
        off4 = make_float4(c.x1 + off, c.y1 + off, c.x2 + off, c.y2 + off);
      }
      bool isl = act && (lv == (unsigned)l);
      unsigned tot;
      unsigned exc = block_scan_bool(isl, wbuf, tot);
      unsigned run = s_run;
      if (isl) {
        unsigned slot = run + exc;
        lvlList[((size_t)b * 4 + l) * 2048 + slot] = (unsigned)pos;
        boxLvl[((size_t)b * 4 + l) * 2048 + slot] = off4;
      }
      __syncthreads();
      if (threadIdx.x == 0) s_run = run + tot;
      __syncthreads();
    }
    if (threadIdx.x == 0) lvlCnt[b * 4 + l] = s_run;
    __syncthreads();
  }
}

// ============================ sorted gather (head): boxes + scores ============================
__global__ __launch_bounds__(256) void head_sort_gather(
    const HeadCand* __restrict__ hc, const unsigned* __restrict__ hsorted,
    const unsigned* __restrict__ hvalid, float4* __restrict__ hbox, float* __restrict__ hsc) {
  int pos = blockIdx.x * 256 + threadIdx.x;
  int valid = (int)*hvalid;
  float4 v = make_float4(0.f, 0.f, 0.f, 0.f);
  float s = 0.f;
  if (pos < valid) {
    HeadCand c = hc[hsorted[pos]];
    v = make_float4(c.x1, c.y1, c.x2, c.y2);
    s = c.score;
  }
  hbox[pos] = v;
  hsc[pos] = s;
}

// ============================ NMS suppression-mask build (rows) ============================
__global__ __launch_bounds__(64) void nms_mask_kernel(
    const float4* __restrict__ boxesOff, const unsigned* __restrict__ validCnt,
    unsigned long long* __restrict__ mask, int rowStrideWords,
    int imgBoxStride, long long imgMaskStride, float th) {
  int b = blockIdx.z;
  const float4* bx = boxesOff + (size_t)b * imgBoxStride;
  unsigned long long* mrow = mask + (size_t)b * imgMaskStride;
  int valid = (int)validCnt[b];
  int i = blockIdx.x * 64 + threadIdx.x;
  int j0 = blockIdx.y * 64;
  __shared__ float4 sb[64];
  sb[threadIdx.x] = bx[j0 + threadIdx.x];
  __syncthreads();
  float4 a = bx[i];
  unsigned long long bits = 0;
  for (int t = 0; t < 64; t++) {
    int j = j0 + t;
    if (j > i && j < valid && iou_pair(a, sb[t]) > th) bits |= (1ull << t);
  }
  mrow[(size_t)i * rowStrideWords + (j0 >> 6)] = bits;
}

// ============================ in-tile column masks ============================
__global__ __launch_bounds__(64) void nms_col_kernel(
    const float4* __restrict__ boxes, const unsigned* __restrict__ validCnt,
    unsigned long long* __restrict__ colw, int jobBoxStride, int jobColStride, float th) {
  int job = blockIdx.y;
  int base = blockIdx.x * 64;
  const float4* bx = boxes + (size_t)job * jobBoxStride;
  int valid = (int)validCnt[job];
  int lane = threadIdx.x;
  __shared__ float4 sb[64];
  sb[lane] = bx[base + lane];
  __syncthreads();
  float4 a = sb[lane];
  unsigned long long bits = 0;
  if (base + lane < valid) {
    for (int t = 0; t < lane; t++) {
      if (iou_pair(sb[t], a) > th) bits |= (1ull << t);
    }
  }
  colw[(size_t)job * jobColStride + base + lane] = bits;
}

// ============================ ballot-frontier greedy NMS reduce ============================
template <int KMAX>
__global__ __launch_bounds__(64) void nms_reduce_frontier_kernel(
    const unsigned long long* __restrict__ mask,   // rows [job][2048][32]
    const unsigned long long* __restrict__ colw,   // cols [job][2048]
    const unsigned* __restrict__ validCnt,
    unsigned* __restrict__ keptIdx, unsigned* __restrict__ keptCnt,
    long long jobMaskStride, int jobColStride) {
  int job = blockIdx.x;
  const unsigned long long* mrow = mask + (size_t)job * jobMaskStride;
  const unsigned long long* mcol = colw + (size_t)job * jobColStride;
  int valid = (int)validCnt[job];
  unsigned* kout = keptIdx + (size_t)job * KMAX;
  int lane = threadIdx.x;
  int half = lane >> 5, w = lane & 31;
  unsigned long long removed = 0ull;
  int keptTotal = 0;
  int ntiles = (valid + 63) >> 6;

  unsigned long long pf[32];
  unsigned long long colNext = 0ull;
  auto issue = [&](int k) {
    int base = k * 64;
#pragma unroll
    for (int i = 0; i < 32; i++) {
      int r = base + 2 * i + half;
      pf[i] = (r < valid) ? mrow[(size_t)r * 32 + w] : 0ull;
    }
    colNext = (base + lane < valid) ? mcol[base + lane] : 0ull;
  };
  if (ntiles > 0) issue(0);

  for (int k = 0; k < ntiles; k++) {
    int base = k * 64;
    int nt = valid - base; if (nt > 64) nt = 64;
    unsigned long long col = colNext;
    unsigned long long Wrm = shfl64(removed, k);
    bool dead = (lane >= nt) || (((Wrm >> lane) & 1ull) != 0ull);
    bool kept = false;
    unsigned long long Kb = 0ull, Db = __ballot(dead);
    while (~(Kb | Db) != 0ull) {
      if (!kept && !dead) {
        if (col & Kb) dead = true;
        else if ((col & ~Db) == 0ull) kept = true;
      }
      Kb = __ballot(kept);
      Db = __ballot(dead);
    }
    int tk = __popcll(Kb);
    bool full = false;
    if (keptTotal + tk > KMAX) {
      int drop = keptTotal + tk - KMAX;
      unsigned long long kk = Kb;
      for (int d = 0; d < drop; d++) kk &= ~(1ull << (63 - __builtin_clzll(kk)));
      Kb = kk; tk = KMAX - keptTotal; full = true;
    }
    if (lane == 0) {
      unsigned long long km = Kb;
      int kc = keptTotal;
      while (km) { int t = __builtin_ctzll(km); km &= km - 1; kout[kc++] = (unsigned)(base + t); }
    }
    keptTotal += tk;
    if (full) break;
    unsigned long long acc = 0ull;
    unsigned long long kb = Kb >> half;
#pragma unroll
    for (int i = 0; i < 32; i++) {
      if ((kb >> (2 * i)) & 1ull) acc |= pf[i];
    }
    unsigned long long accOther = shfl64(acc, (lane + 32) & 63);
    if (lane < 32) removed |= acc | accOther;
    if (k + 1 < ntiles) issue(k + 1);
  }
  if (lane == 0) keptCnt[job] = (unsigned)keptTotal;
}

// ============================ scatter per-level kept -> global-pos flags ============================
__global__ __launch_bounds__(256) void flag_scatter_kernel(
    const unsigned* __restrict__ keptLoc, const unsigned* __restrict__ lvlKeptCnt,
    const unsigned* __restrict__ lvlList, unsigned char* __restrict__ kflag) {
  int job = blockIdx.y;
  int k = blockIdx.x * 256 + threadIdx.x;
  if (k >= (int)lvlKeptCnt[job]) return;
  unsigned local = keptLoc[(size_t)job * 2048 + k];
  unsigned pos = lvlList[(size_t)job * 2048 + local];
  int b = job >> 2;
  kflag[(size_t)b * 8192 + pos] = 1;
}

// ============================ merge kept flags ============================
__global__ __launch_bounds__(1024) void merge_kept_kernel(
    const unsigned char* __restrict__ kflag, const unsigned* __restrict__ validCnt,
    unsigned* __restrict__ keptIdx, unsigned* __restrict__ Mc) {
  int b = blockIdx.x;
  int valid = (int)validCnt[b];
  __shared__ unsigned wbuf[16];
  __shared__ unsigned s_run;
  if (threadIdx.x == 0) s_run = 0;
  __syncthreads();
  for (int c0 = 0; c0 < 8192; c0 += 1024) {
    int i = c0 + (int)threadIdx.x;
    bool k = (i < valid) && kflag[(size_t)b * 8192 + i];
    unsigned tot;
    unsigned exc = block_scan_bool(k, wbuf, tot);
    unsigned run = s_run;
    if (k) {
      unsigned slot = run + exc;
      if (slot < kPostNms) keptIdx[(size_t)b * kPostNms + slot] = (unsigned)i;
    }
    __syncthreads();
    if (threadIdx.x == 0) s_run = run + tot;
    __syncthreads();
  }
  if (threadIdx.x == 0) {
    unsigned r = s_run;
    Mc[b] = r < kPostNms ? r : kPostNms;
  }
}

// ============================ kept-index gathers ============================
__global__ __launch_bounds__(256) void rpn_roi_gather(
    const unsigned* __restrict__ keptIdx, const unsigned* __restrict__ Mc,
    const float4* __restrict__ boxRaw, float* __restrict__ rois) {
  int b = blockIdx.y;
  int k = blockIdx.x * 256 + threadIdx.x;
  if (k >= (int)Mc[b]) return;
  unsigned i = keptIdx[(size_t)b * kPostNms + k];
  float4 v = boxRaw[(size_t)b * 8192 + i];
  float* r = rois + ((size_t)b * kPostNms + k) * 4;
  r[0] = v.x; r[1] = v.y; r[2] = v.z; r[3] = v.w;
}

__global__ __launch_bounds__(128) void head_det_gather(
    const unsigned* __restrict__ keptIdx, const unsigned* __restrict__ cnt,
    const float4* __restrict__ hbox, const float* __restrict__ hsc,
    float* __restrict__ detBox, float* __restrict__ detSc) {
  int k = threadIdx.x;
  if (k >= (int)*cnt || k >= 100) return;
  unsigned i = keptIdx[k];
  float4 v = hbox[i];
  detBox[k * 4 + 0] = v.x; detBox[k * 4 + 1] = v.y;
  detBox[k * 4 + 2] = v.z; detBox[k * 4 + 3] = v.w;
  detSc[k] = hsc[i];
}

// ============================ ROI params ============================
__global__ __launch_bounds__(256) void roi_params_kernel(
    const float* __restrict__ rois, const unsigned* __restrict__ Mc, RoiParam* __restrict__ par) {
  int b = blockIdx.y;
  int i = blockIdx.x * 256 + threadIdx.x;
  if (i >= (int)Mc[b]) return;
  const float* r = rois + ((size_t)b * kPostNms + i) * 4;
  float x1 = r[0], y1 = r[1], x2 = r[2], y2 = r[3];
  float area = (x2 - x1) * (y2 - y1);
  float tgt = floorf(4.0f + log2f(sqrtf(fmaxf(area, 0.f)) / 224.0f + 1e-6f));
  tgt = fminf(fmaxf(tgt, 2.f), 5.f);
  int l = (int)tgt - 2;
  const float scales[4] = {0.25f, 0.125f, 0.0625f, 0.03125f};
  float sc = scales[l];
  RoiParam p;
  p.lvl = l;
  p.x1 = x1 * sc; p.y1 = y1 * sc;
  p.rw = fmaxf(x2 * sc - p.x1, 1.0f);
  p.rh = fmaxf(y2 * sc - p.y1, 1.0f);
  p.pad0 = p.pad1 = p.pad2 = 0;
  par[(size_t)b * kPostNms + i] = p;
}

// ============================ pooled pad (zero rows >= Mc) ============================
__global__ __launch_bounds__(256) void pad_pooled_kernel(
    u16* __restrict__ hi, u16* __restrict__ lo, const unsigned* __restrict__ Mc, int b) {
  int start = (int)Mc[b] * 6272;
  const int total = kMPad * 6272;
  for (int i = start + (int)(blockIdx.x * 256 + threadIdx.x); i < total; i += 512 * 256) {
    hi[i] = 0; lo[i] = 0;
  }
}

// ============================ HWC ROI align: one wave per (roi,bin), bin-major pooled ============================
__global__ __launch_bounds__(256) void roi_align_hwc_kernel(
    const float* __restrict__ fhwc, const RoiParam* __restrict__ par,
    const unsigned* __restrict__ Mc, u16* __restrict__ pooledHi,
    u16* __restrict__ pooledLo, int b) {
  int wave = blockIdx.x * 4 + (int)(threadIdx.x >> 6);
  int lane = threadIdx.x & 63;
  int roi = wave / 49;
  if (roi >= (int)Mc[b]) return;
  int bin = wave - roi * 49;
  int py = bin / 7, px = bin - py * 7;
  RoiParam p = par[roi];
  int H = c_LH[p.lvl], W = c_LW[p.lvl];
  const float* f = fhwc + ((size_t)b * kHWCImg + c_POFF[p.lvl]) * 128;
  float Hf = (float)H, Wf = (float)W;
  float rh7 = p.rh / 7.0f, rw7 = p.rw / 7.0f;
  int c0 = lane * 2;
  float acc0 = 0.f, acc1 = 0.f;
#pragma unroll
  for (int sy = 0; sy < 2; sy++) {
    float offy = (float)py + ((float)sy + 0.5f) * 0.5f;
    float Y = p.y1 + offy * rh7;
    float yc = fminf(fmaxf(Y, 0.f), Hf - 1.f);
    float y0f = floorf(yc);
    int y0 = (int)y0f;
    int y1 = min(y0 + 1, H - 1);
    float ly = yc - y0f, hy = 1.f - ly;
#pragma unroll
    for (int sx = 0; sx < 2; sx++) {
      float offx = (float)px + ((float)sx + 0.5f) * 0.5f;
      float X = p.x1 + offx * rw7;
      bool valid = (Y > -1.f) && (Y < Hf) && (X > -1.f) && (X < Wf);
      float xc = fminf(fmaxf(X, 0.f), Wf - 1.f);
      float x0f = floorf(xc);
      int x0 = (int)x0f;
      int x1i = min(x0 + 1, W - 1);
      float lx = xc - x0f, hx = 1.f - lx;
      if (valid) {
        const float* p00 = f + ((size_t)y0 * W + x0) * 128 + c0;
        const float* p01 = f + ((size_t)y0 * W + x1i) * 128 + c0;
        const float* p10 = f + ((size_t)y1 * W + x0) * 128 + c0;
        const float* p11 = f + ((size_t)y1 * W + x1i) * 128 + c0;
        float2 v00 = *(const float2*)p00;
        float2 v01 = *(const float2*)p01;
        float2 v10 = *(const float2*)p10;
        float2 v11 = *(const float2*)p11;
        acc0 += hy * hx * v00.x + hy * lx * v01.x + ly * hx * v10.x + ly * lx * v11.x;
        acc1 += hy * hx * v00.y + hy * lx * v01.y + ly * hx * v10.y + ly * lx * v11.y;
      }
    }
  }
  float va = acc0 * 0.25f, vb = acc1 * 0.25f;
  u16 h0, l0, h1, l1;
  split_f16(va, h0, l0);
  split_f16(vb, h1, l1);
  size_t o = (size_t)roi * 6272 + bin * 128 + c0;
  *(unsigned*)&pooledHi[o] = (unsigned)h0 | ((unsigned)h1 << 16);
  *(unsigned*)&pooledLo[o] = (unsigned)l0 | ((unsigned)l1 << 16);
}

// ============================ weight split conversion (plain) ============================
__global__ __launch_bounds__(256) void convert_split_kernel(
    const float* __restrict__ src, u16* __restrict__ hi, u16* __restrict__ lo, int n) {
  for (int i = blockIdx.x * 256 + threadIdx.x; i < n; i += gridDim.x * 256) {
    u16 h, l;
    split_f16(src[i], h, l);
    hi[i] = h; lo[i] = l;
  }
}

// ============================ fc6 weight split + K-permute (c*49+bin -> bin*128+c) ============================
__global__ __launch_bounds__(256) void convert_split_fc6_kernel(
    const float* __restrict__ src, u16* __restrict__ hi, u16* __restrict__ lo) {
  int d = blockIdx.x * 256 + threadIdx.x;
  if (d >= 1024 * 6272) return;
  int n = d / 6272, r = d - n * 6272;
  int bin = r >> 7, c = r & 127;
  u16 h, l;
  split_f16(src[n * 6272 + c * 49 + bin], h, l);
  hi[d] = h; lo[d] = l;
}

// ============================ f16x3 dual-acc split-K MFMA GEMM ============================
__global__ __launch_bounds__(256) void gemm_f16x3_kernel(
    const u16* __restrict__ Ah, const u16* __restrict__ Al,
    const u16* __restrict__ Bh, const u16* __restrict__ Bl,
    float* __restrict__ Cpart, int K, int kChunks) {
  __shared__ u16 sAh[128][40], sAl[128][40], sBh[128][40], sBl[128][40];
  int tid = threadIdx.x;
  int m0 = blockIdx.y * 128, n0 = blockIdx.x * 128;
  int kBase = blockIdx.z * kChunks * 32;
  int w = tid >> 6, lane = tid & 63;
  int wm = (w >> 1) * 64, wn = (w & 1) * 64;
  int quad = lane >> 4, lrow = lane & 15;
  f32x4 acc1[4][4], acc2[4][4];
#pragma unroll
  for (int i = 0; i < 4; i++)
#pragma unroll
    for (int j = 0; j < 4; j++) { acc1[i][j] = (f32x4)0.f; acc2[i][j] = (f32x4)0.f; }

  for (int c = 0; c < kChunks; c++) {
    int k0 = kBase + c * 32;
    for (int e = tid; e < 512; e += 256) {
      int row = e >> 2, kk = (e & 3) * 8;
      size_t ga = (size_t)(m0 + row) * K + k0 + kk;
      size_t gb = (size_t)(n0 + row) * K + k0 + kk;
      *(short8*)&sAh[row][kk] = *(const short8*)&Ah[ga];
      *(short8*)&sAl[row][kk] = *(const short8*)&Al[ga];
      *(short8*)&sBh[row][kk] = *(const short8*)&Bh[gb];
      *(short8*)&sBl[row][kk] = *(const short8*)&Bl[gb];
    }
    __syncthreads();
    int kb = quad * 8;
    f16x8 afh[4], afl[4], bfh[4], bfl[4];
#pragma unroll
    for (int t = 0; t < 4; t++) {
      afh[t] = *(const f16x8*)&sAh[wm + t * 16 + lrow][kb];
      afl[t] = *(const f16x8*)&sAl[wm + t * 16 + lrow][kb];
      bfh[t] = *(const f16x8*)&sBh[wn + t * 16 + lrow][kb];
      bfl[t] = *(const f16x8*)&sBl[wn + t * 16 + lrow][kb];
    }
#pragma unroll
    for (int mt = 0; mt < 4; mt++)
#pragma unroll
      for (int nt = 0; nt < 4; nt++) {
        acc1[mt][nt] = __builtin_amdgcn_mfma_f32_16x16x32_f16(afh[mt], bfh[nt], acc1[mt][nt], 0, 0, 0);
        acc2[mt][nt] = __builtin_amdgcn_mfma_f32_16x16x32_f16(afh[mt], bfl[nt], acc2[mt][nt], 0, 0, 0);
        acc2[mt][nt] = __builtin_amdgcn_mfma_f32_16x16x32_f16(afl[mt], bfh[nt], acc2[mt][nt], 0, 0, 0);
      }
    __syncthreads();
  }
  float* out = Cpart + (size_t)blockIdx.z * (kMPad * 1024);
#pragma unroll
  for (int mt = 0; mt < 4; mt++)
#pragma unroll
    for (int nt = 0; nt < 4; nt++) {
      int col = n0 + wn + nt * 16 + lrow;
#pragma unroll
      for (int reg = 0; reg < 4; reg++) {
        int row = m0 + wm + mt * 16 + quad * 4 + reg;
        out[(size_t)row * 1024 + col] = acc1[mt][nt][reg] + kISC * acc2[mt][nt][reg];
      }
    }
}

// ============================ combine partials: bias+relu -> split-f16 ============================
__global__ __launch_bounds__(256) void combine_relu_split_kernel(
    const float* __restrict__ part, const float* __restrict__ bias,
    u16* __restrict__ hi, u16* __restrict__ lo) {
  int idx = blockIdx.x * 256 + threadIdx.x;
  int n = idx & 1023;
  float v = fmaxf(part[idx] + part[idx + kMPad * 1024] + bias[n], 0.f);
  u16 h, l;
  split_f16(v, h, l);
  hi[idx] = h; lo[idx] = l;
}

// ============================ combine partials: bias+relu -> f32 ============================
__global__ __launch_bounds__(256) void combine_relu_f32_kernel(
    const float* __restrict__ part, const float* __restrict__ bias,
    float* __restrict__ out) {
  int idx = blockIdx.x * 256 + threadIdx.x;
  int n = idx & 1023;
  out[idx] = fmaxf(part[idx] + part[idx + kMPad * 1024] + bias[n], 0.f);
}

// ============================ head linear (cls 2 + bbox 8 per roi) ============================
__global__ __launch_bounds__(64) void head_linear_kernel(
    const float* __restrict__ H2, const float* __restrict__ cw, const float* __restrict__ cb2,
    const float* __restrict__ bw, const float* __restrict__ bb2,
    const unsigned* __restrict__ Mc, float* __restrict__ out10) {
  int r = blockIdx.x;
  if (r >= (int)*Mc) return;
  __shared__ float x[1024];
  const float* h = H2 + (size_t)r * 1024;
  for (int i = threadIdx.x; i < 1024; i += 64) x[i] = h[i];
  __syncthreads();
  int t = threadIdx.x;
  if (t < 10) {
    const float* w = (t < 2) ? (cw + t * 1024) : (bw + (t - 2) * 1024);
    float bias = (t < 2) ? cb2[t] : bb2[t - 2];
    float dot = 0.f;
    for (int k = 0; k < 1024; k++) dot = fmaf(w[k], x[k], dot);
    out10[r * 10 + t] = dot + bias;
  }
}

// ============================ head decode ============================
__global__ __launch_bounds__(256) void head_decode_kernel(
    const float* __restrict__ out10, const float* __restrict__ rois,
    const unsigned* __restrict__ Mc, HeadCand* __restrict__ hc, int b) {
#pragma clang fp contract(off)
  int r = blockIdx.x * 256 + threadIdx.x;
  if (r >= (int)Mc[b]) return;
  const float* h = out10 + (size_t)r * 10;
  float l0 = h[0], l1 = h[1];
  float mx = fmaxf(l0, l1);
  float e0 = expf(l0 - mx), e1 = expf(l1 - mx);
  float sfg = e1 / (e0 + e1);
  const float* rr = rois + ((size_t)b * kPostNms + r) * 4;
  float4 bx = decode_clip(rr[0], rr[1], rr[2], rr[3], h[6], h[7], h[8], h[9],
                          10.f, 10.f, 5.f, 5.f);
  bool keep = (sfg > 0.05f) && (bx.z - bx.x >= 0.01f) && (bx.w - bx.y >= 0.01f);
  HeadCand c;
  c.x1 = bx.x; c.y1 = bx.y; c.x2 = bx.z; c.y2 = bx.w;
  c.score = sfg;
  c.key = keep ? keyOf(sfg) : 0u;
  c.pad0 = c.pad1 = 0;
  hc[r] = c;
}

// ============================ final output ============================
__global__ __launch_bounds__(256) void output_kernel(
    const float* __restrict__ detBox, const float* __restrict__ detSc,
    const unsigned* __restrict__ detCnt, float* __restrict__ out) {
  int t = threadIdx.x;
  if (t >= 200) return;
  int b = t / 100, q = t - b * 100;
  int cnt = (int)detCnt[b];
  float bx0 = 0.f, bx1 = 0.f, bx2 = 0.f, bx3 = 0.f, sc = 0.f, lb = 0.f;
  if (q < cnt) {
    const float* d = detBox + ((size_t)b * 100 + q) * 4;
    bx0 = d[0]; bx1 = d[1]; bx2 = d[2]; bx3 = d[3];
    sc = detSc[b * 100 + q];
    lb = 1.0f;
  }
  float* ob = out + ((size_t)b * 100 + q) * 4;
  ob[0] = bx0; ob[1] = bx1; ob[2] = bx2; ob[3] = bx3;
  out[800 + t] = sc;
  out[1000 + t] = lb;
}

// ============================ host launcher ============================
extern "C" void kernel_launch(void* const* d_in, const int* in_sizes, int n_in,
                              void* d_out, int out_size, void* d_ws, size_t ws_size,
                              hipStream_t stream) {
  (void)in_sizes; (void)n_in; (void)out_size; (void)ws_size;
  const float* feats[4] = {(const float*)d_in[0], (const float*)d_in[1],
                           (const float*)d_in[2], (const float*)d_in[3]};
  const float* w3 = (const float*)d_in[4];
  const float* b3 = (const float*)d_in[5];
  const float* wc = (const float*)d_in[6];
  const float* bcs = (const float*)d_in[7];
  const float* wb = (const float*)d_in[8];
  const float* bbx = (const float*)d_in[9];
  const float* fc6w = (const float*)d_in[10];
  const float* fc6b = (const float*)d_in[11];
  const float* fc7w = (const float*)d_in[12];
  const float* fc7b = (const float*)d_in[13];
  const float* clsw = (const float*)d_in[14];
  const float* clsb = (const float*)d_in[15];
  const float* bboxw = (const float*)d_in[16];
  const float* bboxb = (const float*)d_in[17];

  unsigned char* base = (unsigned char*)d_ws;
  size_t off = 0;
  auto alloc = [&](size_t bytes) -> void* {
    void* p = base + off;
    off += (bytes + 255) & ~(size_t)255;
    return p;
  };
  unsigned* keys = (unsigned*)alloc((size_t)2 * kAImg * 4);
  float* deltas = (float*)alloc((size_t)2 * kAImg * 16);
  unsigned* tkT = (unsigned*)alloc(32);
  unsigned* tkNeed = (unsigned*)alloc(32);
  unsigned* gtCnt = (unsigned*)alloc(316 * 4);
  unsigned* eqCnt = (unsigned*)alloc(316 * 4);
  unsigned* gtBase = (unsigned*)alloc(316 * 4);
  unsigned* eqBase = (unsigned*)alloc(316 * 4);
  Cand* cand = (Cand*)alloc((size_t)2 * kNCand * sizeof(Cand));
  unsigned* sortedSlot = (unsigned*)alloc((size_t)2 * 8192 * 4);
  unsigned* validCnt = (unsigned*)alloc(8);
  float4* boxRaw = (float4*)alloc((size_t)2 * 8192 * 16);
  float4* boxLvl = (float4*)alloc((size_t)8 * 2048 * 16);
  unsigned* lvlList = (unsigned*)alloc((size_t)8 * 2048 * 4);
  unsigned* lvlCnt = (unsigned*)alloc(32);
  unsigned long long* lvlMask = (unsigned long long*)alloc((size_t)8 * 2048 * 32 * 8);
  unsigned long long* lvlCol = (unsigned long long*)alloc((size_t)8 * 2048 * 8);
  unsigned* keptLoc = (unsigned*)alloc((size_t)8 * 2048 * 4);
  unsigned* lvlKeptCnt = (unsigned*)alloc(32);
  unsigned char* kflag = (unsigned char*)alloc((size_t)2 * 8192);
  unsigned* keptIdx = (unsigned*)alloc((size_t)2 * kPostNms * 4);
  float* rois = (float*)alloc((size_t)2 * kPostNms * 16);
  unsigned* Mc = (unsigned*)alloc(8);
  RoiParam* roiPar = (RoiParam*)alloc((size_t)2 * kPostNms * sizeof(RoiParam));
  // conv pipeline buffers
  u16* padHi = (u16*)alloc((size_t)204 * 202 * 128 * 2);
  u16* padLo = (u16*)alloc((size_t)204 * 202 * 128 * 2);
  u16* wTapHi = (u16*)alloc((size_t)9 * 128 * 128 * 2);
  u16* wTapLo = (u16*)alloc((size_t)9 * 128 * 128 * 2);
  float* tbuf = (float*)alloc((size_t)313 * 128 * 128 * 4);
  float* fhwc = (float*)alloc((size_t)2 * kHWCImg * 128 * 4);
  u16* pooledHi = (u16*)alloc((size_t)kMPad * 6272 * 2);
  u16* pooledLo = (u16*)alloc((size_t)kMPad * 6272 * 2);
  u16* fc6wHi = (u16*)alloc((size_t)1024 * 6272 * 2);
  u16* fc6wLo = (u16*)alloc((size_t)1024 * 6272 * 2);
  u16* fc7wHi = (u16*)alloc((size_t)1024 * 1024 * 2);
  u16* fc7wLo = (u16*)alloc((size_t)1024 * 1024 * 2);
  float* part = (float*)alloc((size_t)2 * kMPad * 1024 * 4);
  u16* H1hi = (u16*)alloc((size_t)kMPad * 1024 * 2);
  u16* H1lo = (u16*)alloc((size_t)kMPad * 1024 * 2);
  float* H2buf = (float*)alloc((size_t)kMPad * 1024 * 4);
  float* out10 = (float*)alloc((size_t)kPostNms * 10 * 4);
  HeadCand* hc = (HeadCand*)alloc((size_t)kPostNms * sizeof(HeadCand));
  unsigned* hsorted = (unsigned*)alloc((size_t)2048 * 4);
  unsigned* hvalid = (unsigned*)alloc(4);
  float4* hbox = (float4*)alloc((size_t)2048 * 16);
  float* hsc = (float*)alloc((size_t)2048 * 4);
  unsigned long long* hMask = (unsigned long long*)alloc((size_t)2048 * 32 * 8);
  unsigned long long* hCol = (unsigned long long*)alloc((size_t)2048 * 8);
  unsigned* hkept = (unsigned*)alloc((size_t)128 * 4);
  float* detBox = (float*)alloc((size_t)2 * 100 * 4 * 4);
  float* detSc = (float*)alloc((size_t)2 * 100 * 4);
  unsigned* detCnt = (unsigned*)alloc(8);

  // anchor base table, double precision, round-half-even (matches np.round)
  AnchTab tab;
  {
    const double aspects[3] = {0.5, 1.0, 2.0};
    const int sizes[4] = {32, 64, 128, 256};
    for (int l = 0; l < 4; l++)
      for (int a = 0; a < 3; a++) {
        double hr = sqrt(aspects[a]);
        double wr = 1.0 / hr;
        double wsz = wr * sizes[l], hsz = hr * sizes[l];
        tab.v[l][a][0] = (float)rint(-wsz / 2.0);
        tab.v[l][a][1] = (float)rint(-hsz / 2.0);
        tab.v[l][a][2] = (float)rint(wsz / 2.0);
        tab.v[l][a][3] = (float)rint(hsz / 2.0);
      }
  }

  const int LH[4] = {200, 100, 50, 25}, LW[4] = {200, 100, 50, 25};
  const int AOFF[4] = {0, 120000, 150000, 157500};
  const int POFF[4] = {0, 40000, 50000, 52500};

  // weight conversions (same work every call; graph-capture safe)
  convert_split_fc6_kernel<<<(1024 * 6272 + 255) / 256, 256, 0, stream>>>(fc6w, fc6wHi, fc6wLo);
  convert_split_kernel<<<1024, 256, 0, stream>>>(fc7w, fc7wHi, fc7wLo, 1024 * 1024);
  conv_w_repack_kernel<<<(9 * 128 * 128 + 255) / 256, 256, 0, stream>>>(w3, wTapHi, wTapLo);

  // RPN conv pipeline (MFMA implicit GEMM) per image per level; also emits fp32 HWC copy
  for (int b = 0; b < 2; b++) {
    for (int l = 0; l < 4; l++) {
      int H = LH[l], W = LW[l];
      int HW = H * W;
      int mtiles = (HW + 127) / 128;
      int n32 = (H + 4) * (W + 2) * 128 / 2;
      zero_u32_kernel<<<512, 256, 0, stream>>>((unsigned*)padHi, n32);
      zero_u32_kernel<<<512, 256, 0, stream>>>((unsigned*)padLo, n32);
      const float* fsrc = feats[l] + (size_t)b * 128 * HW;
      float* fdst = fhwc + ((size_t)b * kHWCImg + POFF[l]) * 128;
      dim3 tgrid((W + 63) / 64, H);
      switch (l) {
        case 0:
          transpose_pad_kernel<200, 200><<<tgrid, 256, 0, stream>>>(fsrc, padHi, padLo, fdst);
          conv_mfma_kernel<200, 200><<<mtiles, 256, 0, stream>>>(padHi, padLo, wTapHi, wTapLo, b3, tbuf);
          break;
        case 1:
          transpose_pad_kernel<100, 100><<<tgrid, 256, 0, stream>>>(fsrc, padHi, padLo, fdst);
          conv_mfma_kernel<100, 100><<<mtiles, 256, 0, stream>>>(padHi, padLo, wTapHi, wTapLo, b3, tbuf);
          break;
        case 2:
          transpose_pad_kernel<50, 50><<<tgrid, 256, 0, stream>>>(fsrc, padHi, padLo, fdst);
          conv_mfma_kernel<50, 50><<<mtiles, 256, 0, stream>>>(padHi, padLo, wTapHi, wTapLo, b3, tbuf);
          break;
        default:
          transpose_pad_kernel<25, 25><<<tgrid, 256, 0, stream>>>(fsrc, padHi, padLo, fdst);
          conv_mfma_kernel<25, 25><<<mtiles, 256, 0, stream>>>(padHi, padLo, wTapHi, wTapLo, b3, tbuf);
          break;
      }
      head_1x1_kernel<<<(HW + 255) / 256, 256, 0, stream>>>(
          tbuf, wc, bcs, wb, bbx, keys + (size_t)b * kAImg,
          deltas + (size_t)b * kAImg * 4, AOFF[l], HW);
    }
  }

  radix_select_kernel<<<6, 1024, 0, stream>>>(keys, tkT, tkNeed);
  cand_count_kernel<<<316, 1024, 0, stream>>>(keys, tkT, gtCnt, eqCnt);
  cand_prefix_kernel<<<1, 512, 0, stream>>>(gtCnt, eqCnt, gtBase, eqBase);
  cand_scatter_kernel<<<316, 1024, 0, stream>>>(
      keys, deltas, tkT, tkNeed, gtBase, eqBase, cand, tab);
  sort_desc_kernel<8192><<<2, 1024, 0, stream>>>(
      ((const unsigned*)cand) + 4, 8, kNCand, nullptr, sortedSlot, validCnt, kNCand * 8, 8192);
  rpn_sort_gather<<<dim3(32, 2), 256, 0, stream>>>(cand, sortedSlot, validCnt, boxRaw);
  lvl_compact_kernel<<<2, 1024, 0, stream>>>(cand, sortedSlot, validCnt, boxLvl, lvlList, lvlCnt);
  nms_mask_kernel<<<dim3(32, 32, 8), 64, 0, stream>>>(
      boxLvl, lvlCnt, lvlMask, 32, 2048, (long long)2048 * 32, 0.7f);
  nms_col_kernel<<<dim3(32, 8), 64, 0, stream>>>(
      boxLvl, lvlCnt, lvlCol, 2048, 2048, 0.7f);
  nms_reduce_frontier_kernel<2048><<<8, 64, 0, stream>>>(
      lvlMask, lvlCol, lvlCnt, keptLoc, lvlKeptCnt, (long long)2048 * 32, 2048);
  zero_u32_kernel<<<16, 256, 0, stream>>>((unsigned*)kflag, 4096);
  flag_scatter_kernel<<<dim3(8, 8), 256, 0, stream>>>(keptLoc, lvlKeptCnt, lvlList, kflag);
  merge_kept_kernel<<<2, 1024, 0, stream>>>(kflag, validCnt, keptIdx, Mc);
  rpn_roi_gather<<<dim3(8, 2), 256, 0, stream>>>(keptIdx, Mc, boxRaw, rois);
  roi_params_kernel<<<dim3(8, 2), 256, 0, stream>>>(rois, Mc, roiPar);

  for (int b = 0; b < 2; b++) {
    pad_pooled_kernel<<<512, 256, 0, stream>>>(pooledHi, pooledLo, Mc, b);
    roi_align_hwc_kernel<<<(kPostNms * 49 + 3) / 4, 256, 0, stream>>>(
        fhwc, roiPar + (size_t)b * kPostNms, Mc, pooledHi, pooledLo, b);
    // fc6: M=2048, N=1024, K=6272 (split 2 x 98 chunks of 32)
    gemm_f16x3_kernel<<<dim3(8, 16, 2), 256, 0, stream>>>(
        pooledHi, pooledLo, fc6wHi, fc6wLo, part, 6272, 98);
    combine_relu_split_kernel<<<8192, 256, 0, stream>>>(part, fc6b, H1hi, H1lo);
    // fc7: M=2048, N=1024, K=1024 (split 2 x 16 chunks of 32)
    gemm_f16x3_kernel<<<dim3(8, 16, 2), 256, 0, stream>>>(
        H1hi, H1lo, fc7wHi, fc7wLo, part, 1024, 16);
    combine_relu_f32_kernel<<<8192, 256, 0, stream>>>(part, fc7b, H2buf);
    head_linear_kernel<<<2000, 64, 0, stream>>>(H2buf, clsw, clsb, bboxw, bboxb, Mc + b, out10);
    head_decode_kernel<<<8, 256, 0, stream>>>(out10, rois, Mc, hc, b);
    sort_desc_kernel<2048><<<1, 1024, 0, stream>>>(
        ((const unsigned*)hc) + 5, 8, 2000, Mc + b, hsorted, hvalid, 0, 0);
    head_sort_gather<<<8, 256, 0, stream>>>(hc, hsorted, hvalid, hbox, hsc);
    nms_mask_kernel<<<dim3(32, 32, 1), 64, 0, stream>>>(
        hbox, hvalid, hMask, 32, 0, 0, 0.5f);
    nms_col_kernel<<<dim3(32, 1), 64, 0, stream>>>(
        hbox, hvalid, hCol, 0, 0, 0.5f);
    nms_reduce_frontier_kernel<100><<<1, 64, 0, stream>>>(
        hMask, hCol, hvalid, hkept, detCnt + b, (long long)2048 * 32, 0);
    head_det_gather<<<1, 128, 0, stream>>>(
        hkept, detCnt + b, hbox, hsc, detBox + (size_t)b * 400, detSc + (size_t)b * 100);
  }
  output_kernel<<<1, 256, 0, stream>>>(detBox, detSc, detCnt, (float*)d_out);
}

// Round 14
// 2049.460 us; speedup vs baseline: 1.4199x; 1.0751x over previous
//
#include <hip/hip_runtime.h>
#include <cmath>

// ============================ constants ============================
static constexpr int kAImg = 159375;   // anchors per image
static constexpr int kNCand = 7875;    // 2000+2000+2000+1875
static constexpr int kPostNms = 2000;
static constexpr int kMPad = 2048;     // padded roi count for MFMA GEMM
static constexpr int kHWCImg = 53125;  // positions per image (sum of lvl H*W)
static constexpr float kISC = 1.0f / 4096.0f;

__constant__ int c_AOFF[4]   = {0, 120000, 150000, 157500};
__constant__ int c_ALVL[4]   = {120000, 30000, 7500, 1875};
__constant__ int c_CBASE[4]  = {0, 2000, 4000, 6000};
__constant__ int c_NLVL[4]   = {2000, 2000, 2000, 1875};
__constant__ int c_LW[4]     = {200, 100, 50, 25};
__constant__ int c_LH[4]     = {200, 100, 50, 25};
__constant__ int c_STRIDE[4] = {4, 8, 16, 32};
__constant__ int c_POFF[4]   = {0, 40000, 50000, 52500};
// chunk bases per job (1024-elem chunks): lvl chunks {118,30,8,2}, 158/image
__constant__ int c_JCHUNK[9] = {0, 118, 148, 156, 158, 276, 306, 314, 316};

struct Cand     { float x1, y1, x2, y2; unsigned key; unsigned lvl; unsigned pad0, pad1; };
struct HeadCand { float x1, y1, x2, y2; float score; unsigned key; unsigned pad0, pad1; };
struct RoiParam { int lvl; float x1, y1, rw, rh; int pad0, pad1, pad2; };
struct AnchTab  { float v[4][3][4]; };

typedef unsigned short u16;
typedef __attribute__((ext_vector_type(8))) short short8;
typedef __attribute__((ext_vector_type(4))) float f32x4;
typedef _Float16 f16x8 __attribute__((ext_vector_type(8)));

// ============================ device helpers ============================
__device__ __forceinline__ unsigned keyOf(float f) {
  unsigned u = __float_as_uint(f);
  return (u & 0x80000000u) ? ~u : (u | 0x80000000u);
}

// fp32 -> (f16 hi, f16 lo*4096). value = hi + lo/4096, err ~ 2^-24 relative.
__device__ __forceinline__ void split_f16(float f, u16& hi, u16& lo) {
  union { _Float16 h; u16 u; } a, b;
  a.h = (_Float16)f;
  float r = (f - (float)a.h) * 4096.0f;
  b.h = (_Float16)r;
  hi = a.u; lo = b.u;
}

__device__ __forceinline__ unsigned long long shfl64(unsigned long long v, int src) {
  int lo = __shfl((int)(unsigned)(v & 0xffffffffull), src);
  int hi = __shfl((int)(unsigned)(v >> 32), src);
  return ((unsigned long long)(unsigned)hi << 32) | (unsigned)lo;
}

__device__ __forceinline__ float iou_pair(float4 a, float4 b) {
#pragma clang fp contract(off)
  float ix1 = fmaxf(a.x, b.x), iy1 = fmaxf(a.y, b.y);
  float ix2 = fminf(a.z, b.z), iy2 = fminf(a.w, b.w);
  float iw = fmaxf(ix2 - ix1, 0.f), ih = fmaxf(iy2 - iy1, 0.f);
  float inter = iw * ih;
  float a1 = (a.z - a.x) * (a.w - a.y);
  float a2 = (b.z - b.x) * (b.w - b.y);
  float uni = a1 + a2 - inter;
  return uni > 0.f ? inter / uni : 0.f;
}

__device__ __forceinline__ float4 decode_clip(float bx1, float by1, float bx2, float by2,
                                              float d0, float d1, float d2, float d3,
                                              float wx, float wy, float ww, float wh) {
#pragma clang fp contract(off)
  float w = bx2 - bx1, h = by2 - by1;
  float cx = bx1 + 0.5f * w, cy = by1 + 0.5f * h;
  float dx = d0 / wx, dy = d1 / wy;
  float dw = fminf(d2 / ww, 4.135166556742356f);
  float dh = fminf(d3 / wh, 4.135166556742356f);
  float pcx = dx * w + cx, pcy = dy * h + cy;
  float pw = expf(dw) * w, ph = expf(dh) * h;
  float x1 = pcx - 0.5f * pw, y1 = pcy - 0.5f * ph;
  float x2 = pcx + 0.5f * pw, y2 = pcy + 0.5f * ph;
  x1 = fminf(fmaxf(x1, 0.f), 800.f); y1 = fminf(fmaxf(y1, 0.f), 800.f);
  x2 = fminf(fmaxf(x2, 0.f), 800.f); y2 = fminf(fmaxf(y2, 0.f), 800.f);
  return make_float4(x1, y1, x2, y2);
}

// count of elems > k in a DESC-sorted array
__device__ __forceinline__ int cnt_gt(const unsigned* __restrict__ arr, int n, unsigned k) {
  int lo = 0, hi = n;
  while (lo < hi) { int mid = (lo + hi) >> 1; if (arr[mid] > k) lo = mid + 1; else hi = mid; }
  return lo;
}
// count of elems >= k in a DESC-sorted array
__device__ __forceinline__ int cnt_ge(const unsigned* __restrict__ arr, int n, unsigned k) {
  int lo = 0, hi = n;
  while (lo < hi) { int mid = (lo + hi) >> 1; if (arr[mid] >= k) lo = mid + 1; else hi = mid; }
  return lo;
}

// block-wide exclusive scan of a bool over 1024 threads (16 waves)
__device__ __forceinline__ unsigned block_scan_bool(bool p, unsigned* wbuf, unsigned& total) {
  unsigned long long m = __ballot(p);
  int lane = threadIdx.x & 63;
  int wid = threadIdx.x >> 6;
  unsigned exc = (unsigned)__popcll(m & ((lane == 0) ? 0ull : ((~0ull) >> (64 - lane))));
  if (lane == 0) wbuf[wid] = (unsigned)__popcll(m);
  __syncthreads();
  unsigned pre = 0, tot = 0;
#pragma unroll
  for (int w = 0; w < 16; w++) { unsigned c = wbuf[w]; if (w < wid) pre += c; tot += c; }
  total = tot;
  __syncthreads();
  return pre + exc;
}

// ============================ zero fill ============================
__global__ __launch_bounds__(256) void zero_u32_kernel(unsigned* __restrict__ p, int n32) {
  for (int i = blockIdx.x * 256 + threadIdx.x; i < n32; i += gridDim.x * 256) p[i] = 0u;
}

// ============================ NCHW -> padded HWC f16-split transpose (+ fp32 HWC copy) ============================
template <int H, int W>
__global__ __launch_bounds__(256) void transpose_pad_kernel(
    const float* __restrict__ feat, u16* __restrict__ Fh, u16* __restrict__ Fl,
    float* __restrict__ Fw) {
  __shared__ float tile[128][65];
  int y = blockIdx.y;
  int x0 = blockIdx.x * 64;
  for (int e = threadIdx.x; e < 128 * 64; e += 256) {
    int ci = e >> 6, x = e & 63;
    float v = 0.f;
    if (x0 + x < W) v = feat[(size_t)ci * (H * W) + y * W + x0 + x];
    tile[ci][x] = v;
  }
  __syncthreads();
  for (int e = threadIdx.x; e < 64 * 128; e += 256) {
    int x = e >> 7, ci = e & 127;
    if (x0 + x >= W) continue;
    float v = tile[ci][x];
    u16 hi, lo;
    split_f16(v, hi, lo);
    size_t out = ((size_t)(y + 1) * (W + 2) + (x0 + x + 1)) * 128 + ci;
    Fh[out] = hi; Fl[out] = lo;
    Fw[((size_t)y * W + (x0 + x)) * 128 + ci] = v;
  }
}

// ============================ conv weight repack ============================
__global__ __launch_bounds__(256) void conv_w_repack_kernel(
    const float* __restrict__ w3, u16* __restrict__ Wh, u16* __restrict__ Wl) {
  int idx = blockIdx.x * 256 + threadIdx.x;
  if (idx >= 9 * 128 * 128) return;
  int tap = idx >> 14;
  int r = idx & 16383;
  int co = r >> 7, ci = r & 127;
  u16 hi, lo;
  split_f16(w3[co * 1152 + ci * 9 + tap], hi, lo);
  Wh[idx] = hi; Wl[idx] = lo;
}

// ============================ implicit-GEMM MFMA 3x3 conv (f16x3 dual-acc) ============================
template <int H, int W>
__global__ __launch_bounds__(256) void conv_mfma_kernel(
    const u16* __restrict__ Fh, const u16* __restrict__ Fl,
    const u16* __restrict__ Wh, const u16* __restrict__ Wl,
    const float* __restrict__ b3, float* __restrict__ tbuf) {
  __shared__ u16 sAh[128][40], sAl[128][40], sBh[128][40], sBl[128][40];
  int tid = threadIdx.x;
  int m0 = blockIdx.x * 128;
  int w = tid >> 6, lane = tid & 63;
  int wm = (w >> 1) * 64, wn = (w & 1) * 64;
  int quad = lane >> 4, lrow = lane & 15;
  f32x4 acc1[4][4], acc2[4][4];
#pragma unroll
  for (int i = 0; i < 4; i++)
#pragma unroll
    for (int j = 0; j < 4; j++) { acc1[i][j] = (f32x4)0.f; acc2[i][j] = (f32x4)0.f; }

  for (int tap = 0; tap < 9; tap++) {
    int ky = tap / 3, kx = tap - (tap / 3) * 3;
    for (int c = 0; c < 4; c++) {
      for (int e = tid; e < 512; e += 256) {
        int row = e >> 2, seg = (e & 3) * 8;
        int m = m0 + row;
        int y = m / W, x = m - y * W;
        size_t pidx = ((size_t)(y + ky) * (W + 2) + x + kx) * 128 + c * 32 + seg;
        *(short8*)&sAh[row][seg] = *(const short8*)&Fh[pidx];
        *(short8*)&sAl[row][seg] = *(const short8*)&Fl[pidx];
        size_t bidx = ((size_t)tap * 128 + row) * 128 + c * 32 + seg;
        *(short8*)&sBh[row][seg] = *(const short8*)&Wh[bidx];
        *(short8*)&sBl[row][seg] = *(const short8*)&Wl[bidx];
      }
      __syncthreads();
      int kb = quad * 8;
      f16x8 afh[4], afl[4], bfh[4], bfl[4];
#pragma unroll
      for (int t = 0; t < 4; t++) {
        afh[t] = *(const f16x8*)&sAh[wm + t * 16 + lrow][kb];
        afl[t] = *(const f16x8*)&sAl[wm + t * 16 + lrow][kb];
        bfh[t] = *(const f16x8*)&sBh[wn + t * 16 + lrow][kb];
        bfl[t] = *(const f16x8*)&sBl[wn + t * 16 + lrow][kb];
      }
#pragma unroll
      for (int mt = 0; mt < 4; mt++)
#pragma unroll
        for (int nt = 0; nt < 4; nt++) {
          acc1[mt][nt] = __builtin_amdgcn_mfma_f32_16x16x32_f16(afh[mt], bfh[nt], acc1[mt][nt], 0, 0, 0);
          acc2[mt][nt] = __builtin_amdgcn_mfma_f32_16x16x32_f16(afh[mt], bfl[nt], acc2[mt][nt], 0, 0, 0);
          acc2[mt][nt] = __builtin_amdgcn_mfma_f32_16x16x32_f16(afl[mt], bfh[nt], acc2[mt][nt], 0, 0, 0);
        }
      __syncthreads();
    }
  }
#pragma unroll
  for (int nt = 0; nt < 4; nt++) {
    int col = wn + nt * 16 + lrow;
    float bias = b3[col];
#pragma unroll
    for (int mt = 0; mt < 4; mt++) {
#pragma unroll
      for (int reg = 0; reg < 4; reg++) {
        int row = m0 + wm + mt * 16 + quad * 4 + reg;
        float v = acc1[mt][nt][reg] + kISC * acc2[mt][nt][reg] + bias;
        tbuf[(size_t)row * 128 + col] = fmaxf(v, 0.f);
      }
    }
  }
}

// ============================ 1x1 heads from t (HWC fp32) ============================
__global__ __launch_bounds__(256) void head_1x1_kernel(
    const float* __restrict__ tbuf,
    const float* __restrict__ wc, const float* __restrict__ bcs,
    const float* __restrict__ wb, const float* __restrict__ bbx,
    unsigned* __restrict__ keys, float* __restrict__ deltas, int aoff, int HW) {
  __shared__ float wl[15][128];
  __shared__ float bl[15];
  for (int e = threadIdx.x; e < 15 * 128; e += 256) {
    int oc = e >> 7, k = e & 127;
    wl[oc][k] = (oc < 3) ? wc[oc * 128 + k] : wb[(oc - 3) * 128 + k];
  }
  if (threadIdx.x < 15)
    bl[threadIdx.x] = (threadIdx.x < 3) ? bcs[threadIdx.x] : bbx[threadIdx.x - 3];
  __syncthreads();
  int m = blockIdx.x * 256 + threadIdx.x;
  if (m >= HW) return;
  const float* trow = tbuf + (size_t)m * 128;
  float dot[15];
#pragma unroll
  for (int o = 0; o < 15; o++) dot[o] = 0.f;
  for (int k = 0; k < 128; k += 4) {
    float4 v = *(const float4*)&trow[k];
#pragma unroll
    for (int o = 0; o < 15; o++) {
      dot[o] = fmaf(wl[o][k], v.x, dot[o]);
      dot[o] = fmaf(wl[o][k + 1], v.y, dot[o]);
      dot[o] = fmaf(wl[o][k + 2], v.z, dot[o]);
      dot[o] = fmaf(wl[o][k + 3], v.w, dot[o]);
    }
  }
#pragma unroll
  for (int oc = 0; oc < 15; oc++) {
    float s = dot[oc] + bl[oc];
    if (oc < 3) {
      keys[aoff + m * 3 + oc] = keyOf(s);
    } else {
      int bc = oc - 3, a = bc >> 2, comp = bc & 3;
      deltas[(size_t)(aoff + m * 3 + a) * 4 + comp] = s;
    }
  }
}

// ============================ radix select per (image,level 0..2) ============================
__global__ __launch_bounds__(1024) void radix_select_kernel(
    const unsigned* __restrict__ keys, unsigned* __restrict__ tkT, unsigned* __restrict__ tkNeed) {
  int job = blockIdx.x;
  int b = job / 3, l = job - b * 3;
  const unsigned* kb = keys + (size_t)b * kAImg + c_AOFF[l];
  int n = c_ALVL[l];
  __shared__ unsigned hist[256];
  __shared__ unsigned s_sel, s_remk;
  unsigned prefix = 0, pmask = 0, remk = 2000;
  for (int shift = 24; shift >= 0; shift -= 8) {
    if (threadIdx.x < 256) hist[threadIdx.x] = 0;
    __syncthreads();
    for (int i = threadIdx.x; i < n; i += 1024) {
      unsigned key = kb[i];
      if ((key & pmask) == prefix) atomicAdd(&hist[(key >> shift) & 255u], 1u);
    }
    __syncthreads();
    if (threadIdx.x == 0) {
      unsigned cum = 0; int sel = 0;
      for (int d = 255; d >= 0; d--) {
        unsigned c = hist[d];
        if (cum + c >= remk) { sel = d; break; }
        cum += c;
      }
      s_sel = (unsigned)sel; s_remk = remk - cum;
    }
    __syncthreads();
    prefix |= (s_sel << shift);
    pmask |= (255u << shift);
    remk = s_remk;
    __syncthreads();
  }
  if (threadIdx.x == 0) { tkT[b * 4 + l] = prefix; tkNeed[b * 4 + l] = remk; }
}

// ============================ cand pass A: per-chunk gt/eq counts ============================
__global__ __launch_bounds__(1024) void cand_count_kernel(
    const unsigned* __restrict__ keys, const unsigned* __restrict__ tkT,
    unsigned* __restrict__ gtCnt, unsigned* __restrict__ eqCnt) {
  __shared__ unsigned wg[16], we[16];
  int cb = blockIdx.x;
  int j = 0;
#pragma unroll
  for (int t = 1; t < 8; t++) if (cb >= c_JCHUNK[t]) j = t;
  int chunk = cb - c_JCHUNK[j];
  int b = j >> 2, l = j & 3;
  int n = c_ALVL[l];
  int i = chunk * 1024 + (int)threadIdx.x;
  bool act = i < n;
  unsigned key = act ? keys[(size_t)b * kAImg + c_AOFF[l] + i] : 0u;
  unsigned T = (l == 3) ? 0u : tkT[b * 4 + l];
  bool gt = act && (l != 3) && (key > T);
  bool eq = act && (l != 3) && (key == T);
  unsigned long long mg = __ballot(gt), me = __ballot(eq);
  int lane = threadIdx.x & 63, wid = threadIdx.x >> 6;
  if (lane == 0) { wg[wid] = (unsigned)__popcll(mg); we[wid] = (unsigned)__popcll(me); }
  __syncthreads();
  if (threadIdx.x == 0) {
    unsigned g = 0, e = 0;
#pragma unroll
    for (int t = 0; t < 16; t++) { g += wg[t]; e += we[t]; }
    gtCnt[cb] = g; eqCnt[cb] = e;
  }
}

// ============================ cand pass B: per-job exclusive prefix over chunks ============================
__global__ __launch_bounds__(512) void cand_prefix_kernel(
    unsigned* __restrict__ gtCnt, unsigned* __restrict__ eqCnt,
    unsigned* __restrict__ gtBase, unsigned* __restrict__ eqBase) {
  int j = threadIdx.x >> 6;
  int lane = threadIdx.x & 63;
  if (lane != 0) return;
  int c0 = c_JCHUNK[j], c1 = c_JCHUNK[j + 1];
  unsigned g = 0, e = 0;
  for (int c = c0; c < c1; c++) {
    gtBase[c] = g; eqBase[c] = e;
    g += gtCnt[c]; e += eqCnt[c];
  }
}

// ============================ cand pass C: parallel stable scatter + decode ============================
__global__ __launch_bounds__(1024) void cand_scatter_kernel(
    const unsigned* __restrict__ keys, const float* __restrict__ deltas,
    const unsigned* __restrict__ tkT, const unsigned* __restrict__ tkNeed,
    const unsigned* __restrict__ gtBase, const unsigned* __restrict__ eqBase,
    Cand* __restrict__ cand, AnchTab tab) {
  __shared__ unsigned wbuf[16];
  int cb = blockIdx.x;
  int j = 0;
#pragma unroll
  for (int t = 1; t < 8; t++) if (cb >= c_JCHUNK[t]) j = t;
  int chunk = cb - c_JCHUNK[j];
  int b = j >> 2, l = j & 3;
  int n = c_ALVL[l];
  int W = c_LW[l];
  int stride = c_STRIDE[l];
  const float* db = deltas + ((size_t)b * kAImg + c_AOFF[l]) * 4;
  Cand* cbuf = cand + (size_t)b * kNCand + c_CBASE[l];
  bool selAll = (l == 3);
  unsigned T = selAll ? 0u : tkT[b * 4 + l];
  unsigned need = selAll ? 0u : tkNeed[b * 4 + l];
  int i = chunk * 1024 + (int)threadIdx.x;
  bool act = i < n;
  unsigned key = act ? keys[(size_t)b * kAImg + c_AOFF[l] + i] : 0u;
  bool gt = act && !selAll && (key > T);
  bool eq = act && !selAll && (key == T);
  unsigned tmp;
  unsigned gtExc = block_scan_bool(gt, wbuf, tmp);
  unsigned eqExc = block_scan_bool(eq, wbuf, tmp);
  unsigned gtCount = gtBase[cb] + gtExc;
  unsigned eqCount = eqBase[cb] + eqExc;
  bool isSel = act && (selAll || gt || (eq && eqCount < need));
  if (!isSel) return;
  int slot = selAll ? i : (int)(gtCount + (eqCount < need ? eqCount : need));
  int pos = i / 3, a = i - pos * 3;
  int yy = pos / W, xx = pos - yy * W;
  float sx = (float)(xx * stride), sy = (float)(yy * stride);
  float ax1 = tab.v[l][a][0] + sx;
  float ay1 = tab.v[l][a][1] + sy;
  float ax2 = tab.v[l][a][2] + sx;
  float ay2 = tab.v[l][a][3] + sy;
  float d0 = db[(size_t)i * 4 + 0], d1 = db[(size_t)i * 4 + 1];
  float d2 = db[(size_t)i * 4 + 2], d3 = db[(size_t)i * 4 + 3];
  float4 bx = decode_clip(ax1, ay1, ax2, ay2, d0, d1, d2, d3, 1.f, 1.f, 1.f, 1.f);
  bool ok = (bx.z - bx.x >= 0.001f) && (bx.w - bx.y >= 0.001f);
  Cand cd;
  cd.x1 = bx.x; cd.y1 = bx.y; cd.x2 = bx.z; cd.y2 = bx.w;
  cd.key = ok ? key : 0u; cd.lvl = (unsigned)l; cd.pad0 = 0; cd.pad1 = 0;
  cbuf[slot] = cd;
}

// ============================ per-(image,level) bitonic sort (desc key, asc slot) ============================
__global__ __launch_bounds__(1024) void lvl_sort_kernel(
    const Cand* __restrict__ cand, unsigned* __restrict__ lvlKeys,
    unsigned* __restrict__ lvlSlot, unsigned* __restrict__ lvlCnt) {
  __shared__ unsigned sk[2048];
  __shared__ unsigned short ss[2048];
  __shared__ unsigned s_cnt;
  int job = blockIdx.x;
  int b = job >> 2, l = job & 3;
  const Cand* seg = cand + (size_t)b * kNCand + c_CBASE[l];
  int n = c_NLVL[l];
  for (int i = threadIdx.x; i < 2048; i += 1024) {
    sk[i] = (i < n) ? seg[i].key : 0u;
    ss[i] = (unsigned short)i;
  }
  if (threadIdx.x == 0) s_cnt = 0;
  __syncthreads();
  for (int k2 = 2; k2 <= 2048; k2 <<= 1) {
    for (int j = k2 >> 1; j > 0; j >>= 1) {
      for (int i = threadIdx.x; i < 2048; i += 1024) {
        int ixj = i ^ j;
        if (ixj > i) {
          unsigned ka = sk[i], kb2 = sk[ixj];
          unsigned short sa = ss[i], sb = ss[ixj];
          bool aGreater = (ka > kb2) || (ka == kb2 && sa < sb);
          bool up = ((i & k2) == 0);
          bool doSwap = up ? (!aGreater) : aGreater;
          if (doSwap) { sk[i] = kb2; sk[ixj] = ka; ss[i] = sb; ss[ixj] = sa; }
        }
      }
      __syncthreads();
    }
  }
  unsigned local = 0;
  for (int i = threadIdx.x; i < 2048; i += 1024) {
    lvlKeys[(size_t)job * 2048 + i] = sk[i];
    lvlSlot[(size_t)job * 2048 + i] = (unsigned)ss[i];
    if (sk[i] > 0u) local++;
  }
  atomicAdd(&s_cnt, local);
  __syncthreads();
  if (threadIdx.x == 0) lvlCnt[job] = s_cnt;
}

// ============================ global rank via 3 binary searches + box emit ============================
__global__ __launch_bounds__(256) void rank_box_kernel(
    const Cand* __restrict__ cand, const unsigned* __restrict__ lvlKeys,
    const unsigned* __restrict__ lvlSlot, const unsigned* __restrict__ lvlCnt,
    float4* __restrict__ boxLvl, unsigned* __restrict__ gposOf,
    float4* __restrict__ boxRaw) {
  int job = blockIdx.y;
  int b = job >> 2, l = job & 3;
  int i = blockIdx.x * 256 + threadIdx.x;
  if (i >= (int)lvlCnt[job]) return;
  unsigned k = lvlKeys[(size_t)job * 2048 + i];
  int gpos = i;
  for (int l2 = 0; l2 < 4; l2++) {
    if (l2 == l) continue;
    const unsigned* arr = lvlKeys + (size_t)(b * 4 + l2) * 2048;
    int n2 = (int)lvlCnt[b * 4 + l2];
    gpos += (l2 < l) ? cnt_ge(arr, n2, k) : cnt_gt(arr, n2, k);
  }
  unsigned slot = lvlSlot[(size_t)job * 2048 + i];
  Cand c = cand[(size_t)b * kNCand + c_CBASE[l] + slot];
  {
#pragma clang fp contract(off)
    float off = 801.0f * (float)l;
    boxLvl[(size_t)job * 2048 + i] = make_float4(c.x1 + off, c.y1 + off, c.x2 + off, c.y2 + off);
  }
  gposOf[(size_t)job * 2048 + i] = (unsigned)gpos;
  boxRaw[(size_t)b * 8192 + gpos] = make_float4(c.x1, c.y1, c.x2, c.y2);
}

// ============================ total valid per image ============================
__global__ __launch_bounds__(64) void total_valid_kernel(
    const unsigned* __restrict__ lvlCnt, unsigned* __restrict__ validCnt) {
  if (threadIdx.x < 2) {
    int b = threadIdx.x;
    validCnt[b] = lvlCnt[b * 4] + lvlCnt[b * 4 + 1] + lvlCnt[b * 4 + 2] + lvlCnt[b * 4 + 3];
  }
}

// ============================ single-block bitonic sort (head) ============================
template <int NPAD>
__global__ __launch_bounds__(1024) void sort_desc_kernel(
    const unsigned* __restrict__ keyBase, int strideWords, int nFixed,
    const unsigned* __restrict__ nPtr, unsigned* __restrict__ sortedSlot,
    unsigned* __restrict__ validCnt, int imgStrideKeyWords, int imgStrideSlot) {
  __shared__ unsigned sk[NPAD];
  __shared__ unsigned short sslot[NPAD];
  __shared__ unsigned s_cnt;
  int b = blockIdx.x;
  const unsigned* kbase = keyBase + (size_t)b * imgStrideKeyWords;
  unsigned* oslot = sortedSlot + (size_t)b * imgStrideSlot;
  unsigned* ocnt = validCnt + b;
  int n = nFixed;
  if (nPtr) { int m = (int)nPtr[b]; n = n < m ? n : m; }
  for (int i = threadIdx.x; i < NPAD; i += 1024) {
    sk[i] = (i < n) ? kbase[(size_t)i * strideWords] : 0u;
    sslot[i] = (unsigned short)i;
  }
  if (threadIdx.x == 0) s_cnt = 0;
  __syncthreads();
  for (int k2 = 2; k2 <= NPAD; k2 <<= 1) {
    for (int j = k2 >> 1; j > 0; j >>= 1) {
      for (int i = threadIdx.x; i < NPAD; i += 1024) {
        int ixj = i ^ j;
        if (ixj > i) {
          unsigned ka = sk[i], kb2 = sk[ixj];
          unsigned short sa = sslot[i], sb = sslot[ixj];
          bool aGreater = (ka > kb2) || (ka == kb2 && sa < sb);
          bool up = ((i & k2) == 0);
          bool doSwap = up ? (!aGreater) : aGreater;
          if (doSwap) { sk[i] = kb2; sk[ixj] = ka; sslot[i] = sb; sslot[ixj] = sa; }
        }
      }
      __syncthreads();
    }
  }
  unsigned local = 0;
  for (int i = threadIdx.x; i < NPAD; i += 1024) {
    oslot[i] = (unsigned)sslot[i];
    if (sk[i] > 0u) local++;
  }
  atomicAdd(&s_cnt, local);
  __syncthreads();
  if (threadIdx.x == 0) *ocnt = s_cnt;
}

// ============================ sorted gather (head): boxes + scores ============================
__global__ __launch_bounds__(256) void head_sort_gather(
    const HeadCand* __restrict__ hc, const unsigned* __restrict__ hsorted,
    const unsigned* __restrict__ hvalid, float4* __restrict__ hbox, float* __restrict__ hsc) {
  int pos = blockIdx.x * 256 + threadIdx.x;
  int valid = (int)*hvalid;
  float4 v = make_float4(0.f, 0.f, 0.f, 0.f);
  float s = 0.f;
  if (pos < valid) {
    HeadCand c = hc[hsorted[pos]];
    v = make_float4(c.x1, c.y1, c.x2, c.y2);
    s = c.score;
  }
  hbox[pos] = v;
  hsc[pos] = s;
}

// ============================ NMS suppression-mask build (rows) ============================
__global__ __launch_bounds__(64) void nms_mask_kernel(
    const float4* __restrict__ boxesOff, const unsigned* __restrict__ validCnt,
    unsigned long long* __restrict__ mask, int rowStrideWords,
    int imgBoxStride, long long imgMaskStride, float th) {
  int b = blockIdx.z;
  const float4* bx = boxesOff + (size_t)b * imgBoxStride;
  unsigned long long* mrow = mask + (size_t)b * imgMaskStride;
  int valid = (int)validCnt[b];
  int i = blockIdx.x * 64 + threadIdx.x;
  int j0 = blockIdx.y * 64;
  __shared__ float4 sb[64];
  sb[threadIdx.x] = bx[j0 + threadIdx.x];
  __syncthreads();
  float4 a = bx[i];
  unsigned long long bits = 0;
  for (int t = 0; t < 64; t++) {
    int j = j0 + t;
    if (j > i && j < valid && iou_pair(a, sb[t]) > th) bits |= (1ull << t);
  }
  mrow[(size_t)i * rowStrideWords + (j0 >> 6)] = bits;
}

// ============================ in-tile column masks ============================
__global__ __launch_bounds__(64) void nms_col_kernel(
    const float4* __restrict__ boxes, const unsigned* __restrict__ validCnt,
    unsigned long long* __restrict__ colw, int jobBoxStride, int jobColStride, float th) {
  int job = blockIdx.y;
  int base = blockIdx.x * 64;
  const float4* bx = boxes + (size_t)job * jobBoxStride;
  int valid = (int)validCnt[job];
  int lane = threadIdx.x;
  __shared__ float4 sb[64];
  sb[lane] = bx[base + lane];
  __syncthreads();
  float4 a = sb[lane];
  unsigned long long bits = 0;
  if (base + lane < valid) {
    for (int t = 0; t < lane; t++) {
      if (iou_pair(sb[t], a) > th) bits |= (1ull << t);
    }
  }
  colw[(size_t)job * jobColStride + base + lane] = bits;
}

// ============================ ballot-frontier greedy NMS reduce ============================
template <int KMAX>
__global__ __launch_bounds__(64) void nms_reduce_frontier_kernel(
    const unsigned long long* __restrict__ mask,
    const unsigned long long* __restrict__ colw,
    const unsigned* __restrict__ validCnt,
    unsigned* __restrict__ keptIdx, unsigned* __restrict__ keptCnt,
    long long jobMaskStride, int jobColStride) {
  int job = blockIdx.x;
  const unsigned long long* mrow = mask + (size_t)job * jobMaskStride;
  const unsigned long long* mcol = colw + (size_t)job * jobColStride;
  int valid = (int)validCnt[job];
  unsigned* kout = keptIdx + (size_t)job * KMAX;
  int lane = threadIdx.x;
  int half = lane >> 5, w = lane & 31;
  unsigned long long removed = 0ull;
  int keptTotal = 0;
  int ntiles = (valid + 63) >> 6;

  unsigned long long pf[32];
  unsigned long long colNext = 0ull;
  auto issue = [&](int k) {
    int base = k * 64;
#pragma unroll
    for (int i = 0; i < 32; i++) {
      int r = base + 2 * i + half;
      pf[i] = (r < valid) ? mrow[(size_t)r * 32 + w] : 0ull;
    }
    colNext = (base + lane < valid) ? mcol[base + lane] : 0ull;
  };
  if (ntiles > 0) issue(0);

  for (int k = 0; k < ntiles; k++) {
    int base = k * 64;
    int nt = valid - base; if (nt > 64) nt = 64;
    unsigned long long col = colNext;
    unsigned long long Wrm = shfl64(removed, k);
    bool dead = (lane >= nt) || (((Wrm >> lane) & 1ull) != 0ull);
    bool kept = false;
    unsigned long long Kb = 0ull, Db = __ballot(dead);
    while (~(Kb | Db) != 0ull) {
      if (!kept && !dead) {
        if (col & Kb) dead = true;
        else if ((col & ~Db) == 0ull) kept = true;
      }
      Kb = __ballot(kept);
      Db = __ballot(dead);
    }
    int tk = __popcll(Kb);
    bool full = false;
    if (keptTotal + tk > KMAX) {
      int drop = keptTotal + tk - KMAX;
      unsigned long long kk = Kb;
      for (int d = 0; d < drop; d++) kk &= ~(1ull << (63 - __builtin_clzll(kk)));
      Kb = kk; tk = KMAX - keptTotal; full = true;
    }
    if (lane == 0) {
      unsigned long long km = Kb;
      int kc = keptTotal;
      while (km) { int t = __builtin_ctzll(km); km &= km - 1; kout[kc++] = (unsigned)(base + t); }
    }
    keptTotal += tk;
    if (full) break;
    unsigned long long acc = 0ull;
    unsigned long long kb = Kb >> half;
#pragma unroll
    for (int i = 0; i < 32; i++) {
      if ((kb >> (2 * i)) & 1ull) acc |= pf[i];
    }
    unsigned long long accOther = shfl64(acc, (lane + 32) & 63);
    if (lane < 32) removed |= acc | accOther;
    if (k + 1 < ntiles) issue(k + 1);
  }
  if (lane == 0) keptCnt[job] = (unsigned)keptTotal;
}

// ============================ scatter per-level kept -> global-pos flags ============================
__global__ __launch_bounds__(256) void flag_scatter_kernel(
    const unsigned* __restrict__ keptLoc, const unsigned* __restrict__ lvlKeptCnt,
    const unsigned* __restrict__ gposOf, unsigned char* __restrict__ kflag) {
  int job = blockIdx.y;
  int k = blockIdx.x * 256 + threadIdx.x;
  if (k >= (int)lvlKeptCnt[job]) return;
  unsigned local = keptLoc[(size_t)job * 2048 + k];
  unsigned pos = gposOf[(size_t)job * 2048 + local];
  int b = job >> 2;
  kflag[(size_t)b * 8192 + pos] = 1;
}

// ============================ merge kept flags ============================
__global__ __launch_bounds__(1024) void merge_kept_kernel(
    const unsigned char* __restrict__ kflag, const unsigned* __restrict__ validCnt,
    unsigned* __restrict__ keptIdx, unsigned* __restrict__ Mc) {
  int b = blockIdx.x;
  int valid = (int)validCnt[b];
  __shared__ unsigned wbuf[16];
  __shared__ unsigned s_run;
  if (threadIdx.x == 0) s_run = 0;
  __syncthreads();
  for (int c0 = 0; c0 < 8192; c0 += 1024) {
    int i = c0 + (int)threadIdx.x;
    bool k = (i < valid) && kflag[(size_t)b * 8192 + i];
    unsigned tot;
    unsigned exc = block_scan_bool(k, wbuf, tot);
    unsigned run = s_run;
    if (k) {
      unsigned slot = run + exc;
      if (slot < kPostNms) keptIdx[(size_t)b * kPostNms + slot] = (unsigned)i;
    }
    __syncthreads();
    if (threadIdx.x == 0) s_run = run + tot;
    __syncthreads();
  }
  if (threadIdx.x == 0) {
    unsigned r = s_run;
    Mc[b] = r < kPostNms ? r : kPostNms;
  }
}

// ============================ kept-index gathers ============================
__global__ __launch_bounds__(256) void rpn_roi_gather(
    const unsigned* __restrict__ keptIdx, const unsigned* __restrict__ Mc,
    const float4* __restrict__ boxRaw, float* __restrict__ rois) {
  int b = blockIdx.y;
  int k = blockIdx.x * 256 + threadIdx.x;
  if (k >= (int)Mc[b]) return;
  unsigned i = keptIdx[(size_t)b * kPostNms + k];
  float4 v = boxRaw[(size_t)b * 8192 + i];
  float* r = rois + ((size_t)b * kPostNms + k) * 4;
  r[0] = v.x; r[1] = v.y; r[2] = v.z; r[3] = v.w;
}

__global__ __launch_bounds__(128) void head_det_gather(
    const unsigned* __restrict__ keptIdx, const unsigned* __restrict__ cnt,
    const float4* __restrict__ hbox, const float* __restrict__ hsc,
    float* __restrict__ detBox, float* __restrict__ detSc) {
  int k = threadIdx.x;
  if (k >= (int)*cnt || k >= 100) return;
  unsigned i = keptIdx[k];
  float4 v = hbox[i];
  detBox[k * 4 + 0] = v.x; detBox[k * 4 + 1] = v.y;
  detBox[k * 4 + 2] = v.z; detBox[k * 4 + 3] = v.w;
  detSc[k] = hsc[i];
}

// ============================ ROI params ============================
__global__ __launch_bounds__(256) void roi_params_kernel(
    const float* __restrict__ rois, const unsigned* __restrict__ Mc, RoiParam* __restrict__ par) {
  int b = blockIdx.y;
  int i = blockIdx.x * 256 + threadIdx.x;
  if (i >= (int)Mc[b]) return;
  const float* r = rois + ((size_t)b * kPostNms + i) * 4;
  float x1 = r[0], y1 = r[1], x2 = r[2], y2 = r[3];
  float area = (x2 - x1) * (y2 - y1);
  float tgt = floorf(4.0f + log2f(sqrtf(fmaxf(area, 0.f)) / 224.0f + 1e-6f));
  tgt = fminf(fmaxf(tgt, 2.f), 5.f);
  int l = (int)tgt - 2;
  const float scales[4] = {0.25f, 0.125f, 0.0625f, 0.03125f};
  float sc = scales[l];
  RoiParam p;
  p.lvl = l;
  p.x1 = x1 * sc; p.y1 = y1 * sc;
  p.rw = fmaxf(x2 * sc - p.x1, 1.0f);
  p.rh = fmaxf(y2 * sc - p.y1, 1.0f);
  p.pad0 = p.pad1 = p.pad2 = 0;
  par[(size_t)b * kPostNms + i] = p;
}

// ============================ pooled pad (zero rows >= Mc) ============================
__global__ __launch_bounds__(256) void pad_pooled_kernel(
    u16* __restrict__ hi, u16* __restrict__ lo, const unsigned* __restrict__ Mc, int b) {
  int start = (int)Mc[b] * 6272;
  const int total = kMPad * 6272;
  for (int i = start + (int)(blockIdx.x * 256 + threadIdx.x); i < total; i += 512 * 256) {
    hi[i] = 0; lo[i] = 0;
  }
}

// ============================ HWC ROI align: one wave per (roi,bin), bin-major pooled ============================
__global__ __launch_bounds__(256) void roi_align_hwc_kernel(
    const float* __restrict__ fhwc, const RoiParam* __restrict__ par,
    const unsigned* __restrict__ Mc, u16* __restrict__ pooledHi,
    u16* __restrict__ pooledLo, int b) {
  int wave = blockIdx.x * 4 + (int)(threadIdx.x >> 6);
  int lane = threadIdx.x & 63;
  int roi = wave / 49;
  if (roi >= (int)Mc[b]) return;
  int bin = wave - roi * 49;
  int py = bin / 7, px = bin - py * 7;
  RoiParam p = par[roi];
  int H = c_LH[p.lvl], W = c_LW[p.lvl];
  const float* f = fhwc + ((size_t)b * kHWCImg + c_POFF[p.lvl]) * 128;
  float Hf = (float)H, Wf = (float)W;
  float rh7 = p.rh / 7.0f, rw7 = p.rw / 7.0f;
  int c0 = lane * 2;
  float acc0 = 0.f, acc1 = 0.f;
#pragma unroll
  for (int sy = 0; sy < 2; sy++) {
    float offy = (float)py + ((float)sy + 0.5f) * 0.5f;
    float Y = p.y1 + offy * rh7;
    float yc = fminf(fmaxf(Y, 0.f), Hf - 1.f);
    float y0f = floorf(yc);
    int y0 = (int)y0f;
    int y1 = min(y0 + 1, H - 1);
    float ly = yc - y0f, hy = 1.f - ly;
#pragma unroll
    for (int sx = 0; sx < 2; sx++) {
      float offx = (float)px + ((float)sx + 0.5f) * 0.5f;
      float X = p.x1 + offx * rw7;
      bool valid = (Y > -1.f) && (Y < Hf) && (X > -1.f) && (X < Wf);
      float xc = fminf(fmaxf(X, 0.f), Wf - 1.f);
      float x0f = floorf(xc);
      int x0 = (int)x0f;
      int x1i = min(x0 + 1, W - 1);
      float lx = xc - x0f, hx = 1.f - lx;
      if (valid) {
        const float* p00 = f + ((size_t)y0 * W + x0) * 128 + c0;
        const float* p01 = f + ((size_t)y0 * W + x1i) * 128 + c0;
        const float* p10 = f + ((size_t)y1 * W + x0) * 128 + c0;
        const float* p11 = f + ((size_t)y1 * W + x1i) * 128 + c0;
        float2 v00 = *(const float2*)p00;
        float2 v01 = *(const float2*)p01;
        float2 v10 = *(const float2*)p10;
        float2 v11 = *(const float2*)p11;
        acc0 += hy * hx * v00.x + hy * lx * v01.x + ly * hx * v10.x + ly * lx * v11.x;
        acc1 += hy * hx * v00.y + hy * lx * v01.y + ly * hx * v10.y + ly * lx * v11.y;
      }
    }
  }
  float va = acc0 * 0.25f, vb = acc1 * 0.25f;
  u16 h0, l0, h1, l1;
  split_f16(va, h0, l0);
  split_f16(vb, h1, l1);
  size_t o = (size_t)roi * 6272 + bin * 128 + c0;
  *(unsigned*)&pooledHi[o] = (unsigned)h0 | ((unsigned)h1 << 16);
  *(unsigned*)&pooledLo[o] = (unsigned)l0 | ((unsigned)l1 << 16);
}

// ============================ weight split conversion (plain) ============================
__global__ __launch_bounds__(256) void convert_split_kernel(
    const float* __restrict__ src, u16* __restrict__ hi, u16* __restrict__ lo, int n) {
  for (int i = blockIdx.x * 256 + threadIdx.x; i < n; i += gridDim.x * 256) {
    u16 h, l;
    split_f16(src[i], h, l);
    hi[i] = h; lo[i] = l;
  }
}

// ============================ fc6 weight split + K-permute (c*49+bin -> bin*128+c) ============================
__global__ __launch_bounds__(256) void convert_split_fc6_kernel(
    const float* __restrict__ src, u16* __restrict__ hi, u16* __restrict__ lo) {
  int d = blockIdx.x * 256 + threadIdx.x;
  if (d >= 1024 * 6272) return;
  int n = d / 6272, r = d - n * 6272;
  int bin = r >> 7, c = r & 127;
  u16 h, l;
  split_f16(src[n * 6272 + c * 49 + bin], h, l);
  hi[d] = h; lo[d] = l;
}

// ============================ f16x3 dual-acc split-K MFMA GEMM ============================
__global__ __launch_bounds__(256) void gemm_f16x3_kernel(
    const u16* __restrict__ Ah, const u16* __restrict__ Al,
    const u16* __restrict__ Bh, const u16* __restrict__ Bl,
    float* __restrict__ Cpart, int K, int kChunks) {
  __shared__ u16 sAh[128][40], sAl[128][40], sBh[128][40], sBl[128][40];
  int tid = threadIdx.x;
  int m0 = blockIdx.y * 128, n0 = blockIdx.x * 128;
  int kBase = blockIdx.z * kChunks * 32;
  int w = tid >> 6, lane = tid & 63;
  int wm = (w >> 1) * 64, wn = (w & 1) * 64;
  int quad = lane >> 4, lrow = lane & 15;
  f32x4 acc1[4][4], acc2[4][4];
#pragma unroll
  for (int i = 0; i < 4; i++)
#pragma unroll
    for (int j = 0; j < 4; j++) { acc1[i][j] = (f32x4)0.f; acc2[i][j] = (f32x4)0.f; }

  for (int c = 0; c < kChunks; c++) {
    int k0 = kBase + c * 32;
    for (int e = tid; e < 512; e += 256) {
      int row = e >> 2, kk = (e & 3) * 8;
      size_t ga = (size_t)(m0 + row) * K + k0 + kk;
      size_t gb = (size_t)(n0 + row) * K + k0 + kk;
      *(short8*)&sAh[row][kk] = *(const short8*)&Ah[ga];
      *(short8*)&sAl[row][kk] = *(const short8*)&Al[ga];
      *(short8*)&sBh[row][kk] = *(const short8*)&Bh[gb];
      *(short8*)&sBl[row][kk] = *(const short8*)&Bl[gb];
    }
    __syncthreads();
    int kb = quad * 8;
    f16x8 afh[4], afl[4], bfh[4], bfl[4];
#pragma unroll
    for (int t = 0; t < 4; t++) {
      afh[t] = *(const f16x8*)&sAh[wm + t * 16 + lrow][kb];
      afl[t] = *(const f16x8*)&sAl[wm + t * 16 + lrow][kb];
      bfh[t] = *(const f16x8*)&sBh[wn + t * 16 + lrow][kb];
      bfl[t] = *(const f16x8*)&sBl[wn + t * 16 + lrow][kb];
    }
#pragma unroll
    for (int mt = 0; mt < 4; mt++)
#pragma unroll
      for (int nt = 0; nt < 4; nt++) {
        acc1[mt][nt] = __builtin_amdgcn_mfma_f32_16x16x32_f16(afh[mt], bfh[nt], acc1[mt][nt], 0, 0, 0);
        acc2[mt][nt] = __builtin_amdgcn_mfma_f32_16x16x32_f16(afh[mt], bfl[nt], acc2[mt][nt], 0, 0, 0);
        acc2[mt][nt] = __builtin_amdgcn_mfma_f32_16x16x32_f16(afl[mt], bfh[nt], acc2[mt][nt], 0, 0, 0);
      }
    __syncthreads();
  }
  float* out = Cpart + (size_t)blockIdx.z * (kMPad * 1024);
#pragma unroll
  for (int mt = 0; mt < 4; mt++)
#pragma unroll
    for (int nt = 0; nt < 4; nt++) {
      int col = n0 + wn + nt * 16 + lrow;
#pragma unroll
      for (int reg = 0; reg < 4; reg++) {
        int row = m0 + wm + mt * 16 + quad * 4 + reg;
        out[(size_t)row * 1024 + col] = acc1[mt][nt][reg] + kISC * acc2[mt][nt][reg];
      }
    }
}

// ============================ combine partials: bias+relu -> split-f16 ============================
__global__ __launch_bounds__(256) void combine_relu_split_kernel(
    const float* __restrict__ part, const float* __restrict__ bias,
    u16* __restrict__ hi, u16* __restrict__ lo) {
  int idx = blockIdx.x * 256 + threadIdx.x;
  int n = idx & 1023;
  float v = fmaxf(part[idx] + part[idx + kMPad * 1024] + bias[n], 0.f);
  u16 h, l;
  split_f16(v, h, l);
  hi[idx] = h; lo[idx] = l;
}

// ============================ combine partials: bias+relu -> f32 ============================
__global__ __launch_bounds__(256) void combine_relu_f32_kernel(
    const float* __restrict__ part, const float* __restrict__ bias,
    float* __restrict__ out) {
  int idx = blockIdx.x * 256 + threadIdx.x;
  int n = idx & 1023;
  out[idx] = fmaxf(part[idx] + part[idx + kMPad * 1024] + bias[n], 0.f);
}

// ============================ head linear (cls 2 + bbox 8 per roi) ============================
__global__ __launch_bounds__(64) void head_linear_kernel(
    const float* __restrict__ H2, const float* __restrict__ cw, const float* __restrict__ cb2,
    const float* __restrict__ bw, const float* __restrict__ bb2,
    const unsigned* __restrict__ Mc, float* __restrict__ out10) {
  int r = blockIdx.x;
  if (r >= (int)*Mc) return;
  __shared__ float x[1024];
  const float* h = H2 + (size_t)r * 1024;
  for (int i = threadIdx.x; i < 1024; i += 64) x[i] = h[i];
  __syncthreads();
  int t = threadIdx.x;
  if (t < 10) {
    const float* w = (t < 2) ? (cw + t * 1024) : (bw + (t - 2) * 1024);
    float bias = (t < 2) ? cb2[t] : bb2[t - 2];
    float dot = 0.f;
    for (int k = 0; k < 1024; k++) dot = fmaf(w[k], x[k], dot);
    out10[r * 10 + t] = dot + bias;
  }
}

// ============================ head decode ============================
__global__ __launch_bounds__(256) void head_decode_kernel(
    const float* __restrict__ out10, const float* __restrict__ rois,
    const unsigned* __restrict__ Mc, HeadCand* __restrict__ hc, int b) {
#pragma clang fp contract(off)
  int r = blockIdx.x * 256 + threadIdx.x;
  if (r >= (int)Mc[b]) return;
  const float* h = out10 + (size_t)r * 10;
  float l0 = h[0], l1 = h[1];
  float mx = fmaxf(l0, l1);
  float e0 = expf(l0 - mx), e1 = expf(l1 - mx);
  float sfg = e1 / (e0 + e1);
  const float* rr = rois + ((size_t)b * kPostNms + r) * 4;
  float4 bx = decode_clip(rr[0], rr[1], rr[2], rr[3], h[6], h[7], h[8], h[9],
                          10.f, 10.f, 5.f, 5.f);
  bool keep = (sfg > 0.05f) && (bx.z - bx.x >= 0.01f) && (bx.w - bx.y >= 0.01f);
  HeadCand c;
  c.x1 = bx.x; c.y1 = bx.y; c.x2 = bx.z; c.y2 = bx.w;
  c.score = sfg;
  c.key = keep ? keyOf(sfg) : 0u;
  c.pad0 = c.pad1 = 0;
  hc[r] = c;
}

// ============================ final output ============================
__global__ __launch_bounds__(256) void output_kernel(
    const float* __restrict__ detBox, const float* __restrict__ detSc,
    const unsigned* __restrict__ detCnt, float* __restrict__ out) {
  int t = threadIdx.x;
  if (t >= 200) return;
  int b = t / 100, q = t - b * 100;
  int cnt = (int)detCnt[b];
  float bx0 = 0.f, bx1 = 0.f, bx2 = 0.f, bx3 = 0.f, sc = 0.f, lb = 0.f;
  if (q < cnt) {
    const float* d = detBox + ((size_t)b * 100 + q) * 4;
    bx0 = d[0]; bx1 = d[1]; bx2 = d[2]; bx3 = d[3];
    sc = detSc[b * 100 + q];
    lb = 1.0f;
  }
  float* ob = out + ((size_t)b * 100 + q) * 4;
  ob[0] = bx0; ob[1] = bx1; ob[2] = bx2; ob[3] = bx3;
  out[800 + t] = sc;
  out[1000 + t] = lb;
}

// ============================ host launcher ============================
extern "C" void kernel_launch(void* const* d_in, const int* in_sizes, int n_in,
                              void* d_out, int out_size, void* d_ws, size_t ws_size,
                              hipStream_t stream) {
  (void)in_sizes; (void)n_in; (void)out_size; (void)ws_size;
  const float* feats[4] = {(const float*)d_in[0], (const float*)d_in[1],
                           (const float*)d_in[2], (const float*)d_in[3]};
  const float* w3 = (const float*)d_in[4];
  const float* b3 = (const float*)d_in[5];
  const float* wc = (const float*)d_in[6];
  const float* bcs = (const float*)d_in[7];
  const float* wb = (const float*)d_in[8];
  const float* bbx = (const float*)d_in[9];
  const float* fc6w = (const float*)d_in[10];
  const float* fc6b = (const float*)d_in[11];
  const float* fc7w = (const float*)d_in[12];
  const float* fc7b = (const float*)d_in[13];
  const float* clsw = (const float*)d_in[14];
  const float* clsb = (const float*)d_in[15];
  const float* bboxw = (const float*)d_in[16];
  const float* bboxb = (const float*)d_in[17];

  unsigned char* base = (unsigned char*)d_ws;
  size_t off = 0;
  auto alloc = [&](size_t bytes) -> void* {
    void* p = base + off;
    off += (bytes + 255) & ~(size_t)255;
    return p;
  };
  unsigned* keys = (unsigned*)alloc((size_t)2 * kAImg * 4);
  float* deltas = (float*)alloc((size_t)2 * kAImg * 16);
  unsigned* tkT = (unsigned*)alloc(32);
  unsigned* tkNeed = (unsigned*)alloc(32);
  unsigned* gtCnt = (unsigned*)alloc(316 * 4);
  unsigned* eqCnt = (unsigned*)alloc(316 * 4);
  unsigned* gtBase = (unsigned*)alloc(316 * 4);
  unsigned* eqBase = (unsigned*)alloc(316 * 4);
  Cand* cand = (Cand*)alloc((size_t)2 * kNCand * sizeof(Cand));
  unsigned* lvlKeys = (unsigned*)alloc((size_t)8 * 2048 * 4);
  unsigned* lvlSlot = (unsigned*)alloc((size_t)8 * 2048 * 4);
  unsigned* lvlCnt = (unsigned*)alloc(32);
  unsigned* gposOf = (unsigned*)alloc((size_t)8 * 2048 * 4);
  unsigned* validCnt = (unsigned*)alloc(8);
  float4* boxRaw = (float4*)alloc((size_t)2 * 8192 * 16);
  float4* boxLvl = (float4*)alloc((size_t)8 * 2048 * 16);
  unsigned long long* lvlMask = (unsigned long long*)alloc((size_t)8 * 2048 * 32 * 8);
  unsigned long long* lvlCol = (unsigned long long*)alloc((size_t)8 * 2048 * 8);
  unsigned* keptLoc = (unsigned*)alloc((size_t)8 * 2048 * 4);
  unsigned* lvlKeptCnt = (unsigned*)alloc(32);
  unsigned char* kflag = (unsigned char*)alloc((size_t)2 * 8192);
  unsigned* keptIdx = (unsigned*)alloc((size_t)2 * kPostNms * 4);
  float* rois = (float*)alloc((size_t)2 * kPostNms * 16);
  unsigned* Mc = (unsigned*)alloc(8);
  RoiParam* roiPar = (RoiParam*)alloc((size_t)2 * kPostNms * sizeof(RoiParam));
  // conv pipeline buffers
  u16* padHi = (u16*)alloc((size_t)204 * 202 * 128 * 2);
  u16* padLo = (u16*)alloc((size_t)204 * 202 * 128 * 2);
  u16* wTapHi = (u16*)alloc((size_t)9 * 128 * 128 * 2);
  u16* wTapLo = (u16*)alloc((size_t)9 * 128 * 128 * 2);
  float* tbuf = (float*)alloc((size_t)313 * 128 * 128 * 4);
  float* fhwc = (float*)alloc((size_t)2 * kHWCImg * 128 * 4);
  u16* pooledHi = (u16*)alloc((size_t)kMPad * 6272 * 2);
  u16* pooledLo = (u16*)alloc((size_t)kMPad * 6272 * 2);
  u16* fc6wHi = (u16*)alloc((size_t)1024 * 6272 * 2);
  u16* fc6wLo = (u16*)alloc((size_t)1024 * 6272 * 2);
  u16* fc7wHi = (u16*)alloc((size_t)1024 * 1024 * 2);
  u16* fc7wLo = (u16*)alloc((size_t)1024 * 1024 * 2);
  float* part = (float*)alloc((size_t)2 * kMPad * 1024 * 4);
  u16* H1hi = (u16*)alloc((size_t)kMPad * 1024 * 2);
  u16* H1lo = (u16*)alloc((size_t)kMPad * 1024 * 2);
  float* H2buf = (float*)alloc((size_t)kMPad * 1024 * 4);
  float* out10 = (float*)alloc((size_t)kPostNms * 10 * 4);
  HeadCand* hc = (HeadCand*)alloc((size_t)kPostNms * sizeof(HeadCand));
  unsigned* hsorted = (unsigned*)alloc((size_t)2048 * 4);
  unsigned* hvalid = (unsigned*)alloc(4);
  float4* hbox = (float4*)alloc((size_t)2048 * 16);
  float* hsc = (float*)alloc((size_t)2048 * 4);
  unsigned long long* hMask = (unsigned long long*)alloc((size_t)2048 * 32 * 8);
  unsigned long long* hCol = (unsigned long long*)alloc((size_t)2048 * 8);
  unsigned* hkept = (unsigned*)alloc((size_t)128 * 4);
  float* detBox = (float*)alloc((size_t)2 * 100 * 4 * 4);
  float* detSc = (float*)alloc((size_t)2 * 100 * 4);
  unsigned* detCnt = (unsigned*)alloc(8);

  // anchor base table, double precision, round-half-even (matches np.round)
  AnchTab tab;
  {
    const double aspects[3] = {0.5, 1.0, 2.0};
    const int sizes[4] = {32, 64, 128, 256};
    for (int l = 0; l < 4; l++)
      for (int a = 0; a < 3; a++) {
        double hr = sqrt(aspects[a]);
        double wr = 1.0 / hr;
        double wsz = wr * sizes[l], hsz = hr * sizes[l];
        tab.v[l][a][0] = (float)rint(-wsz / 2.0);
        tab.v[l][a][1] = (float)rint(-hsz / 2.0);
        tab.v[l][a][2] = (float)rint(wsz / 2.0);
        tab.v[l][a][3] = (float)rint(hsz / 2.0);
      }
  }

  const int LH[4] = {200, 100, 50, 25}, LW[4] = {200, 100, 50, 25};
  const int AOFF[4] = {0, 120000, 150000, 157500};
  const int POFF[4] = {0, 40000, 50000, 52500};

  // weight conversions (same work every call; graph-capture safe)
  convert_split_fc6_kernel<<<(1024 * 6272 + 255) / 256, 256, 0, stream>>>(fc6w, fc6wHi, fc6wLo);
  convert_split_kernel<<<1024, 256, 0, stream>>>(fc7w, fc7wHi, fc7wLo, 1024 * 1024);
  conv_w_repack_kernel<<<(9 * 128 * 128 + 255) / 256, 256, 0, stream>>>(w3, wTapHi, wTapLo);

  // RPN conv pipeline (MFMA implicit GEMM) per image per level; also emits fp32 HWC copy
  for (int b = 0; b < 2; b++) {
    for (int l = 0; l < 4; l++) {
      int H = LH[l], W = LW[l];
      int HW = H * W;
      int mtiles = (HW + 127) / 128;
      int n32 = (H + 4) * (W + 2) * 128 / 2;
      zero_u32_kernel<<<512, 256, 0, stream>>>((unsigned*)padHi, n32);
      zero_u32_kernel<<<512, 256, 0, stream>>>((unsigned*)padLo, n32);
      const float* fsrc = feats[l] + (size_t)b * 128 * HW;
      float* fdst = fhwc + ((size_t)b * kHWCImg + POFF[l]) * 128;
      dim3 tgrid((W + 63) / 64, H);
      switch (l) {
        case 0:
          transpose_pad_kernel<200, 200><<<tgrid, 256, 0, stream>>>(fsrc, padHi, padLo, fdst);
          conv_mfma_kernel<200, 200><<<mtiles, 256, 0, stream>>>(padHi, padLo, wTapHi, wTapLo, b3, tbuf);
          break;
        case 1:
          transpose_pad_kernel<100, 100><<<tgrid, 256, 0, stream>>>(fsrc, padHi, padLo, fdst);
          conv_mfma_kernel<100, 100><<<mtiles, 256, 0, stream>>>(padHi, padLo, wTapHi, wTapLo, b3, tbuf);
          break;
        case 2:
          transpose_pad_kernel<50, 50><<<tgrid, 256, 0, stream>>>(fsrc, padHi, padLo, fdst);
          conv_mfma_kernel<50, 50><<<mtiles, 256, 0, stream>>>(padHi, padLo, wTapHi, wTapLo, b3, tbuf);
          break;
        default:
          transpose_pad_kernel<25, 25><<<tgrid, 256, 0, stream>>>(fsrc, padHi, padLo, fdst);
          conv_mfma_kernel<25, 25><<<mtiles, 256, 0, stream>>>(padHi, padLo, wTapHi, wTapLo, b3, tbuf);
          break;
      }
      head_1x1_kernel<<<(HW + 255) / 256, 256, 0, stream>>>(
          tbuf, wc, bcs, wb, bbx, keys + (size_t)b * kAImg,
          deltas + (size_t)b * kAImg * 4, AOFF[l], HW);
    }
  }

  radix_select_kernel<<<6, 1024, 0, stream>>>(keys, tkT, tkNeed);
  cand_count_kernel<<<316, 1024, 0, stream>>>(keys, tkT, gtCnt, eqCnt);
  cand_prefix_kernel<<<1, 512, 0, stream>>>(gtCnt, eqCnt, gtBase, eqBase);
  cand_scatter_kernel<<<316, 1024, 0, stream>>>(
      keys, deltas, tkT, tkNeed, gtBase, eqBase, cand, tab);
  // per-level sort + global rank merge (replaces 8192-bitonic global sort)
  lvl_sort_kernel<<<8, 1024, 0, stream>>>(cand, lvlKeys, lvlSlot, lvlCnt);
  rank_box_kernel<<<dim3(8, 8), 256, 0, stream>>>(
      cand, lvlKeys, lvlSlot, lvlCnt, boxLvl, gposOf, boxRaw);
  total_valid_kernel<<<1, 64, 0, stream>>>(lvlCnt, validCnt);
  nms_mask_kernel<<<dim3(32, 32, 8), 64, 0, stream>>>(
      boxLvl, lvlCnt, lvlMask, 32, 2048, (long long)2048 * 32, 0.7f);
  nms_col_kernel<<<dim3(32, 8), 64, 0, stream>>>(
      boxLvl, lvlCnt, lvlCol, 2048, 2048, 0.7f);
  nms_reduce_frontier_kernel<2048><<<8, 64, 0, stream>>>(
      lvlMask, lvlCol, lvlCnt, keptLoc, lvlKeptCnt, (long long)2048 * 32, 2048);
  zero_u32_kernel<<<16, 256, 0, stream>>>((unsigned*)kflag, 4096);
  flag_scatter_kernel<<<dim3(8, 8), 256, 0, stream>>>(keptLoc, lvlKeptCnt, gposOf, kflag);
  merge_kept_kernel<<<2, 1024, 0, stream>>>(kflag, validCnt, keptIdx, Mc);
  rpn_roi_gather<<<dim3(8, 2), 256, 0, stream>>>(keptIdx, Mc, boxRaw, rois);
  roi_params_kernel<<<dim3(8, 2), 256, 0, stream>>>(rois, Mc, roiPar);

  for (int b = 0; b < 2; b++) {
    pad_pooled_kernel<<<512, 256, 0, stream>>>(pooledHi, pooledLo, Mc, b);
    roi_align_hwc_kernel<<<(kPostNms * 49 + 3) / 4, 256, 0, stream>>>(
        fhwc, roiPar + (size_t)b * kPostNms, Mc, pooledHi, pooledLo, b);
    // fc6: M=2048, N=1024, K=6272 (split 2 x 98 chunks of 32)
    gemm_f16x3_kernel<<<dim3(8, 16, 2), 256, 0, stream>>>(
        pooledHi, pooledLo, fc6wHi, fc6wLo, part, 6272, 98);
    combine_relu_split_kernel<<<8192, 256, 0, stream>>>(part, fc6b, H1hi, H1lo);
    // fc7: M=2048, N=1024, K=1024 (split 2 x 16 chunks of 32)
    gemm_f16x3_kernel<<<dim3(8, 16, 2), 256, 0, stream>>>(
        H1hi, H1lo, fc7wHi, fc7wLo, part, 1024, 16);
    combine_relu_f32_kernel<<<8192, 256, 0, stream>>>(part, fc7b, H2buf);
    head_linear_kernel<<<2000, 64, 0, stream>>>(H2buf, clsw, clsb, bboxw, bboxb, Mc + b, out10);
    head_decode_kernel<<<8, 256, 0, stream>>>(out10, rois, Mc, hc, b);
    sort_desc_kernel<2048><<<1, 1024, 0, stream>>>(
        ((const unsigned*)hc) + 5, 8, 2000, Mc + b, hsorted, hvalid, 0, 0);
    head_sort_gather<<<8, 256, 0, stream>>>(hc, hsorted, hvalid, hbox, hsc);
    nms_mask_kernel<<<dim3(32, 32, 1), 64, 0, stream>>>(
        hbox, hvalid, hMask, 32, 0, 0, 0.5f);
    nms_col_kernel<<<dim3(32, 1), 64, 0, stream>>>(
        hbox, hvalid, hCol, 0, 0, 0.5f);
    nms_reduce_frontier_kernel<100><<<1, 64, 0, stream>>>(
        hMask, hCol, hvalid, hkept, detCnt + b, (long long)2048 * 32, 0);
    head_det_gather<<<1, 128, 0, stream>>>(
        hkept, detCnt + b, hbox, hsc, detBox + (size_t)b * 400, detSc + (size_t)b * 100);
  }
  output_kernel<<<1, 256, 0, stream>>>(detBox, detSc, detCnt, (float*)d_out);
}